// Round 9
// baseline (6526.701 us; speedup 1.0000x reference)
//
#include <hip/hip_runtime.h>
#include <hip/hip_bf16.h>
#include <math.h>

#define LLEN 512
#define KNNK 16
#define DIM 1024
#define NHEAD 16
#define NLAYER 2
#define DFFN 4096
#define POSCLIP 32
#define NQ 4096
#define NTOK 65536

typedef __attribute__((ext_vector_type(8))) short short8v;
typedef __attribute__((ext_vector_type(4))) float f32x4;
typedef unsigned short ushort_t;

__device__ __forceinline__ float b2f(ushort_t u) {
  union { unsigned u; float f; } x; x.u = ((unsigned)u) << 16; return x.f;
}

// 2D XCD-blocked tile mapping: B-slice L2-resident, A fetched ~once/XCD.
__device__ __forceinline__ void xcd_map(int bid, int Mtiles, int Ntiles, int XN,
                                        int& mt, int& nt) {
  int nt_per = Ntiles / XN;
  int mt_per = (Mtiles * XN) >> 3;
  int xcd = bid & 7, i = bid >> 3;
  int xn = xcd % XN, xm = xcd / XN;
  int ntl = i % nt_per, mtl = i / nt_per;
  mt = xm * mt_per + mtl;
  nt = xn * nt_per + ntl;
}

#define GLD16(gp, lp)                                                          \
  __builtin_amdgcn_global_load_lds(                                            \
      (const __attribute__((address_space(1))) void*)(gp),                     \
      (__attribute__((address_space(3))) void*)(lp), 16, 0, 0)

// ---------------- KNN: one wave per query ----------------
__global__ __launch_bounds__(64) void knn_kernel(const float* __restrict__ coords,
                                                 int* __restrict__ edges) {
  int n = blockIdx.x;
  int b = n / LLEN, i = n % LLEN;
  int lane = threadIdx.x;
  const float* cb = coords + (size_t)b * LLEN * 9;
  float xi = cb[i * 9 + 3], yi = cb[i * 9 + 4], zi = cb[i * 9 + 5];
  float d[8];
#pragma unroll
  for (int r = 0; r < 8; ++r) {
    int j = r * 64 + lane;
    float dx = xi - cb[j * 9 + 3];
    float dy = yi - cb[j * 9 + 4];
    float dz = zi - cb[j * 9 + 5];
    d[r] = dx * dx + dy * dy + dz * dz;
  }
  for (int s = 0; s < KNNK; ++s) {
    float bv = INFINITY; int bi = 1 << 30;
#pragma unroll
    for (int r = 0; r < 8; ++r) {
      int j = r * 64 + lane;
      if (d[r] < bv || (d[r] == bv && j < bi)) { bv = d[r]; bi = j; }
    }
#pragma unroll
    for (int off = 32; off > 0; off >>= 1) {
      float ov = __shfl_xor(bv, off);
      int   oi = __shfl_xor(bi, off);
      if (ov < bv || (ov == bv && oi < bi)) { bv = ov; bi = oi; }
    }
    if (lane == 0) edges[n * KNNK + s] = bi;
    if ((bi & 63) == lane) d[bi >> 6] = INFINITY;
  }
}

// ---------------- dist: 16x16 per query ----------------
__global__ __launch_bounds__(256) void dist_kernel(const float* __restrict__ coords,
                                                   const int* __restrict__ edges,
                                                   float* __restrict__ dist) {
  int n = blockIdx.x; int b = n / LLEN;
  __shared__ float tx[16], ty[16], tz[16];
  int t = threadIdx.x;
  const float* cb = coords + (size_t)b * LLEN * 9;
  if (t < 16) {
    int j = edges[n * KNNK + t];
    tx[t] = cb[j * 9 + 3]; ty[t] = cb[j * 9 + 4]; tz[t] = cb[j * 9 + 5];
  }
  __syncthreads();
  int e = t >> 4, f = t & 15;
  float dx = tx[e] - tx[f], dy = ty[e] - ty[f], dz = tz[e] - tz[f];
  dist[(size_t)n * 256 + t] = sqrtf(dx * dx + dy * dy + dz * dz + 1e-8f);
}

// ---------------- z init (chunked) ----------------
__global__ __launch_bounds__(256) void zinit_kernel(const int* __restrict__ edges,
                                                    const float* __restrict__ emb,
                                                    float* __restrict__ zbuf, int tok0) {
  int tl = blockIdx.x;
  int tok = tok0 + tl;
  int n = tok >> 4;
  int diff = edges[tok] - edges[n << 4];
  int idx = min(max(diff, -POSCLIP), POSCLIP) + POSCLIP;
  ((float4*)(zbuf + (size_t)tl * DIM))[threadIdx.x] =
      ((const float4*)(emb + (size_t)idx * DIM))[threadIdx.x];
}

// ---------------- LayerNorm fp32 in -> bf16 out ----------------
__global__ __launch_bounds__(256) void ln_kernel(const float* __restrict__ X, int stride,
                                                 const float* __restrict__ g,
                                                 const float* __restrict__ bta,
                                                 __hip_bfloat16* __restrict__ Y) {
  int row = blockIdx.x; int t = threadIdx.x;
  const float4* xr = (const float4*)(X + (size_t)row * stride);
  float4 v = xr[t];
  float s = v.x + v.y + v.z + v.w;
  __shared__ float red[8];
  for (int off = 32; off; off >>= 1) s += __shfl_down(s, off);
  int wid = t >> 6;
  if ((t & 63) == 0) red[wid] = s;
  __syncthreads();
  if (t == 0) red[4] = (red[0] + red[1] + red[2] + red[3]) * (1.0f / DIM);
  __syncthreads();
  float mean = red[4];
  float d0 = v.x - mean, d1 = v.y - mean, d2 = v.z - mean, d3 = v.w - mean;
  float s2 = d0 * d0 + d1 * d1 + d2 * d2 + d3 * d3;
  for (int off = 32; off; off >>= 1) s2 += __shfl_down(s2, off);
  if ((t & 63) == 0) red[wid] = s2;
  __syncthreads();
  if (t == 0) red[5] = rsqrtf((red[0] + red[1] + red[2] + red[3]) * (1.0f / DIM) + 1e-5f);
  __syncthreads();
  float rstd = red[5];
  float4 gv = ((const float4*)g)[t], bv = ((const float4*)bta)[t];
  size_t o = (size_t)row * DIM + t * 4;
  Y[o + 0] = __float2bfloat16(d0 * rstd * gv.x + bv.x);
  Y[o + 1] = __float2bfloat16(d1 * rstd * gv.y + bv.y);
  Y[o + 2] = __float2bfloat16(d2 * rstd * gv.z + bv.z);
  Y[o + 3] = __float2bfloat16(d3 * rstd * gv.w + bv.w);
}

// ---------------- weight fp32 K x N -> bf16 N x K ----------------
__global__ __launch_bounds__(256) void wconv_kernel(const float* __restrict__ W,
                                                    __hip_bfloat16* __restrict__ Wt,
                                                    int K, int N) {
  __shared__ float tile[32][33];
  int n0 = blockIdx.x * 32, k0 = blockIdx.y * 32;
  int c = threadIdx.x & 31, r = threadIdx.x >> 5;
#pragma unroll
  for (int i = 0; i < 4; ++i)
    tile[r + i * 8][c] = W[(size_t)(k0 + r + i * 8) * N + n0 + c];
  __syncthreads();
#pragma unroll
  for (int i = 0; i < 4; ++i)
    Wt[(size_t)(n0 + r + i * 8) * K + k0 + c] = __float2bfloat16(tile[c][r + i * 8]);
}

// BK=32 swizzle (rows are 64B = 4x16B chunks): LDS chunk position c holds
// global k-chunk c ^ ((row>>1)&3); reads use kg ^ ((fr>>1)&3). <=2-way (free).

// ============ gemmT128: BM=128, BN=128, BK=32, 256 thr (4 waves 2x2),
// 3-slot ring (48KB LDS) -> 3 blocks/CU. MODE 0: bf16 C = x  MODE 1: fp32 C += x
template <int MODE>
__global__ __launch_bounds__(256, 3) void gemmT128_kernel(
    const ushort_t* __restrict__ A,
    const ushort_t* __restrict__ Wt,
    const float* __restrict__ bias,
    void* __restrict__ Cout,
    int K, int Mtiles, int Cstride, int Ntiles, int XN) {
  __shared__ ushort_t Alds[3][4096];   // 3 x 128 rows x 32 bf16
  __shared__ ushort_t Blds[3][4096];
  int t = threadIdx.x;
  int w = t >> 6, lane = t & 63;
  int wr = w >> 1, wc = w & 1;
  int fr = lane & 15, kg = lane >> 4;

  int mt, nt;
  xcd_map(blockIdx.x, Mtiles, Ntiles, XN, mt, nt);
  size_t m0 = (size_t)mt * 128, n0 = (size_t)nt * 128;

  // staging: 256 lanes x 16B = 64 rows per issue; issue j adds 64 rows.
  int stg_r = w * 16 + (lane >> 2);
  int stg_c = (((lane & 3) ^ ((lane >> 3) & 3)) << 3);  // elems, pre-swizzled
  const ushort_t* gAl = A + (m0 + stg_r) * (size_t)K + stg_c;
  const ushort_t* gBl = Wt + (n0 + stg_r) * (size_t)K + stg_c;
  int lds_w = w * 512;

#define SAt(slot, kcol, j) GLD16(gAl + (size_t)(j) * 64 * K + (kcol), Alds[slot] + (j) * 2048 + lds_w)
#define SBt(slot, kcol, j) GLD16(gBl + (size_t)(j) * 64 * K + (kcol), Blds[slot] + (j) * 2048 + lds_w)

  f32x4 acc[4][4];
#pragma unroll
  for (int i = 0; i < 4; ++i)
#pragma unroll
    for (int j = 0; j < 4; ++j) acc[i][j] = (f32x4){0.f, 0.f, 0.f, 0.f};

  int usw = ((kg ^ ((fr >> 1) & 3)) << 3);

  // prologue: T0 -> slot0, T1 -> slot1 (8 issues); wait T0 (T1's 4 in flight)
  SAt(0, 0, 0); SAt(0, 0, 1); SBt(0, 0, 0); SBt(0, 0, 1);
  SAt(1, 32, 0); SAt(1, 32, 1); SBt(1, 32, 0); SBt(1, 32, 1);
  asm volatile("s_waitcnt vmcnt(4)" ::: "memory");
  __builtin_amdgcn_s_barrier();

  short8v af[4], bf[4];
  int NT = K >> 5;
  int sl = 0, st = 2;
  for (int ti = 0; ti < NT; ++ti) {
    int kS = (ti + 2) << 5;
    int stg = (ti + 2) < NT;
    const ushort_t* sA = Alds[sl];
    const ushort_t* sB = Blds[sl];
#pragma unroll
    for (int mi = 0; mi < 4; ++mi)
      af[mi] = *(const short8v*)(sA + (wr * 64 + mi * 16 + fr) * 32 + usw);
#pragma unroll
    for (int ni = 0; ni < 4; ++ni)
      bf[ni] = *(const short8v*)(sB + (wc * 64 + ni * 16 + fr) * 32 + usw);
    if (stg) { SAt(st, kS, 0); SAt(st, kS, 1); SBt(st, kS, 0); SBt(st, kS, 1); }
    __builtin_amdgcn_s_barrier();
    asm volatile("s_waitcnt lgkmcnt(0)" ::: "memory");
    __builtin_amdgcn_s_setprio(1);
#pragma unroll
    for (int mi = 0; mi < 4; ++mi)
#pragma unroll
      for (int ni = 0; ni < 4; ++ni)
        acc[mi][ni] = __builtin_amdgcn_mfma_f32_16x16x32_bf16(af[mi], bf[ni], acc[mi][ni], 0, 0, 0);
    __builtin_amdgcn_s_setprio(0);
    if (stg) { asm volatile("s_waitcnt vmcnt(4)" ::: "memory"); }
    else if (ti + 1 < NT) { asm volatile("s_waitcnt vmcnt(0)" ::: "memory"); }
    __builtin_amdgcn_s_barrier();
    sl = (sl == 2) ? 0 : sl + 1;
    st = (st == 2) ? 0 : st + 1;
  }
#undef SAt
#undef SBt

  int er = wr * 64 + (lane >> 4) * 4;
  int ec = wc * 64 + fr;
#pragma unroll
  for (int mi = 0; mi < 4; ++mi) {
#pragma unroll
    for (int ni = 0; ni < 4; ++ni) {
      int col = (int)n0 + ec + ni * 16;
      float bs = bias[col];
#pragma unroll
      for (int j = 0; j < 4; ++j) {
        size_t row = m0 + er + mi * 16 + j;
        size_t cidx = row * (size_t)Cstride + col;
        float x = acc[mi][ni][j] + bs;
        if constexpr (MODE == 0) {
          ((__hip_bfloat16*)Cout)[cidx] = __float2bfloat16(x);
        } else {
          ((float*)Cout)[cidx] += x;
        }
      }
    }
  }
}

// ============ gemmG32: fused gated ff1, BM=128, BN=128 dual, BK=32 ==========
// 3-slot ring (72KB), 2 blocks/CU, counted vmcnt(3). (proven ~900 TF)
__global__ __launch_bounds__(512, 4) void gemmG32_kernel(
    const ushort_t* __restrict__ A,
    const ushort_t* __restrict__ Wt,
    const float* __restrict__ bias,
    __hip_bfloat16* __restrict__ Cout,
    int K, int Mtiles, int Cstride, int NhRows, int Ntiles, int XN) {
  __shared__ ushort_t Alds[3][4096];
  __shared__ ushort_t B1lds[3][4096];
  __shared__ ushort_t B2lds[3][4096];
  int t = threadIdx.x;
  int w = t >> 6, lane = t & 63;
  int wr = w >> 2, wc = w & 3;
  int fr = lane & 15, kg = lane >> 4;

  int mt, nt;
  xcd_map(blockIdx.x, Mtiles, Ntiles, XN, mt, nt);
  size_t m0 = (size_t)mt * 128, n0 = (size_t)nt * 128;

  int stg_r = w * 16 + (lane >> 2);
  int stg_c = (((lane & 3) ^ ((lane >> 3) & 3)) << 3);
  const ushort_t* gAl = A + (m0 + stg_r) * (size_t)K + stg_c;
  const ushort_t* gB1 = Wt + (n0 + stg_r) * (size_t)K + stg_c;
  const ushort_t* gB2 = Wt + ((size_t)NhRows + n0 + stg_r) * (size_t)K + stg_c;
  int lds_w = w * 512;

#define SAg(slot, kcol) GLD16(gAl + (kcol), Alds[slot] + lds_w)
#define SB1g(slot, kcol) GLD16(gB1 + (kcol), B1lds[slot] + lds_w)
#define SB2g(slot, kcol) GLD16(gB2 + (kcol), B2lds[slot] + lds_w)

  f32x4 acc1[4][2], acc2[4][2];
#pragma unroll
  for (int i = 0; i < 4; ++i)
#pragma unroll
    for (int j = 0; j < 2; ++j) {
      acc1[i][j] = (f32x4){0.f, 0.f, 0.f, 0.f};
      acc2[i][j] = (f32x4){0.f, 0.f, 0.f, 0.f};
    }

  int usw = ((kg ^ ((fr >> 1) & 3)) << 3);

  SAg(0, 0); SB1g(0, 0); SB2g(0, 0);
  SAg(1, 32); SB1g(1, 32); SB2g(1, 32);
  asm volatile("s_waitcnt vmcnt(3)" ::: "memory");
  __builtin_amdgcn_s_barrier();

  short8v af[4], bf1[2], bf2[2];
  int NT = K >> 5;
  int sl = 0, st = 2;
  for (int ti = 0; ti < NT; ++ti) {
    int kS = (ti + 2) << 5;
    int stg = (ti + 2) < NT;
    const ushort_t* sA = Alds[sl];
    const ushort_t* sB1 = B1lds[sl];
    const ushort_t* sB2 = B2lds[sl];
#pragma unroll
    for (int mi = 0; mi < 4; ++mi)
      af[mi] = *(const short8v*)(sA + (wr * 64 + mi * 16 + fr) * 32 + usw);
#pragma unroll
    for (int ni = 0; ni < 2; ++ni) {
      bf1[ni] = *(const short8v*)(sB1 + (wc * 32 + ni * 16 + fr) * 32 + usw);
      bf2[ni] = *(const short8v*)(sB2 + (wc * 32 + ni * 16 + fr) * 32 + usw);
    }
    if (stg) { SAg(st, kS); SB1g(st, kS); SB2g(st, kS); }
    __builtin_amdgcn_s_barrier();
    asm volatile("s_waitcnt lgkmcnt(0)" ::: "memory");
    __builtin_amdgcn_s_setprio(1);
#pragma unroll
    for (int mi = 0; mi < 4; ++mi)
#pragma unroll
      for (int ni = 0; ni < 2; ++ni) {
        acc1[mi][ni] = __builtin_amdgcn_mfma_f32_16x16x32_bf16(af[mi], bf1[ni], acc1[mi][ni], 0, 0, 0);
        acc2[mi][ni] = __builtin_amdgcn_mfma_f32_16x16x32_bf16(af[mi], bf2[ni], acc2[mi][ni], 0, 0, 0);
      }
    __builtin_amdgcn_s_setprio(0);
    if (stg) { asm volatile("s_waitcnt vmcnt(3)" ::: "memory"); }
    else if (ti + 1 < NT) { asm volatile("s_waitcnt vmcnt(0)" ::: "memory"); }
    __builtin_amdgcn_s_barrier();
    sl = (sl == 2) ? 0 : sl + 1;
    st = (st == 2) ? 0 : st + 1;
  }
#undef SAg
#undef SB1g
#undef SB2g

  int er = wr * 64 + (lane >> 4) * 4;
  int ec = wc * 32 + fr;
#pragma unroll
  for (int mi = 0; mi < 4; ++mi) {
#pragma unroll
    for (int ni = 0; ni < 2; ++ni) {
      int col = (int)n0 + ec + ni * 16;
      float b1v = bias[col];
      float b2v = bias[NhRows + col];
#pragma unroll
      for (int j = 0; j < 4; ++j) {
        size_t row = m0 + er + mi * 16 + j;
        float x1 = acc1[mi][ni][j] + b1v;
        float x2 = acc2[mi][ni][j] + b2v;
        float sg = x1 / (1.f + expf(-x1));
        Cout[row * (size_t)Cstride + col] = __float2bfloat16(sg * x2);
      }
    }
  }
}

// ---------------- small 128x128 GEMM (final head only) ----------------
template <int MODE>
__global__ __launch_bounds__(256) void mgemm_kernel(
    const __hip_bfloat16* __restrict__ A,
    const __hip_bfloat16* __restrict__ Wt,
    const float* __restrict__ bias,
    void* __restrict__ Cout,
    int K, int Nh, int Cstride) {
  __shared__ ushort_t As[4 * 128 * 8];
  __shared__ ushort_t Bs[4 * 128 * 8];
  __shared__ ushort_t Bs2[(MODE == 2) ? 4 * 128 * 8 : 8];
  int t = threadIdx.x;
  int w = t >> 6, lane = t & 63;
  int wr = w >> 1, wc = w & 1;
  size_t m0 = (size_t)blockIdx.y * 128;
  size_t n0 = (size_t)blockIdx.x * 128;
  int cell0 = w * 64 + lane;
  int cell1 = 256 + w * 64 + lane;
  int kg0 = cell0 >> 7, rw0 = cell0 & 127;
  int kg1 = cell1 >> 7, rw1 = cell1 & 127;
  const ushort_t* gA = (const ushort_t*)A;
  const ushort_t* gB = (const ushort_t*)Wt;
  const ushort_t* gB2 = (const ushort_t*)(Wt + (size_t)Nh * K);
  size_t a0 = (m0 + rw0) * (size_t)K + kg0 * 8;
  size_t a1 = (m0 + rw1) * (size_t)K + kg1 * 8;
  size_t b0 = (n0 + rw0) * (size_t)K + kg0 * 8;
  size_t b1 = (n0 + rw1) * (size_t)K + kg1 * 8;
  int ldso0 = w * 1024;
  int ldso1 = 4096 + w * 1024;
  f32x4 acc[4][4];
  f32x4 acc2[4][4];
#pragma unroll
  for (int i = 0; i < 4; ++i)
#pragma unroll
    for (int j = 0; j < 4; ++j) {
      acc[i][j] = (f32x4){0.f, 0.f, 0.f, 0.f};
      acc2[i][j] = (f32x4){0.f, 0.f, 0.f, 0.f};
    }
  int fr = lane & 15, kg = lane >> 4;
  int abase = (kg * 128 + wr * 64 + fr) * 16;
  int bbase = (kg * 128 + wc * 64 + fr) * 16;
  for (int k0 = 0; k0 < K; k0 += 32) {
    __syncthreads();
    GLD16(gA + a0 + k0, (char*)As + ldso0);
    GLD16(gA + a1 + k0, (char*)As + ldso1);
    GLD16(gB + b0 + k0, (char*)Bs + ldso0);
    GLD16(gB + b1 + k0, (char*)Bs + ldso1);
    if constexpr (MODE == 2) {
      GLD16(gB2 + b0 + k0, (char*)Bs2 + ldso0);
      GLD16(gB2 + b1 + k0, (char*)Bs2 + ldso1);
    }
    __syncthreads();
    short8v a[4], b[4];
#pragma unroll
    for (int mi = 0; mi < 4; ++mi)
      a[mi] = *(const short8v*)((const char*)As + abase + mi * 256);
#pragma unroll
    for (int ni = 0; ni < 4; ++ni)
      b[ni] = *(const short8v*)((const char*)Bs + bbase + ni * 256);
#pragma unroll
    for (int mi = 0; mi < 4; ++mi)
#pragma unroll
      for (int ni = 0; ni < 4; ++ni)
        acc[mi][ni] = __builtin_amdgcn_mfma_f32_16x16x32_bf16(a[mi], b[ni], acc[mi][ni], 0, 0, 0);
    if constexpr (MODE == 2) {
#pragma unroll
      for (int ni = 0; ni < 4; ++ni)
        b[ni] = *(const short8v*)((const char*)Bs2 + bbase + ni * 256);
#pragma unroll
      for (int mi = 0; mi < 4; ++mi)
#pragma unroll
        for (int ni = 0; ni < 4; ++ni)
          acc2[mi][ni] = __builtin_amdgcn_mfma_f32_16x16x32_bf16(a[mi], b[ni], acc2[mi][ni], 0, 0, 0);
    }
  }
  int er = wr * 64 + (lane >> 4) * 4;
  int ec = wc * 64 + fr;
#pragma unroll
  for (int mi = 0; mi < 4; ++mi) {
#pragma unroll
    for (int ni = 0; ni < 4; ++ni) {
      int col = (int)n0 + ec + ni * 16;
      float bs1 = bias[col];
#pragma unroll
      for (int j = 0; j < 4; ++j) {
        size_t row = m0 + er + mi * 16 + j;
        size_t cidx = row * (size_t)Cstride + col;
        float x = acc[mi][ni][j] + bs1;
        if constexpr (MODE == 3) {
          ((float*)Cout)[cidx] = x;
        } else {
          float x2 = acc2[mi][ni][j] + bias[Nh + col];
          float sig = 1.f / (1.f + expf(-x));
          ((__hip_bfloat16*)Cout)[cidx] = __float2bfloat16(x * sig * x2);
        }
      }
    }
  }
}

// ---------------- attention: one block per query, loop heads ----------------
__global__ __launch_bounds__(256) void attn_kernel(const __hip_bfloat16* __restrict__ qkv,
                                                   const float* __restrict__ dist,
                                                   const float* __restrict__ ds_l,
                                                   __hip_bfloat16* __restrict__ o) {
  int nq = blockIdx.x;
  int t = threadIdx.x;
  __shared__ float qs[16][65], ks[16][65], vs[16][65];
  __shared__ float sc[16][17], dl[16][17];
  __shared__ float sps_s[NHEAD];
  dl[t >> 4][t & 15] = dist[(size_t)nq * 256 + t];
  if (t < NHEAD) sps_s[t] = log1pf(expf(ds_l[t]));
  size_t base = (size_t)nq * 16 * 3072;
  int e = t >> 4, c4 = (t & 15) * 4;
  const ushort_t* qp = (const ushort_t*)qkv;
  for (int h = 0; h < NHEAD; ++h) {
    const ushort_t* p = qp + base + (size_t)e * 3072 + h * 64 + c4;
    ushort4 qv = *(const ushort4*)p;
    ushort4 kv = *(const ushort4*)(p + 1024);
    ushort4 vv = *(const ushort4*)(p + 2048);
    qs[e][c4] = b2f(qv.x); qs[e][c4 + 1] = b2f(qv.y); qs[e][c4 + 2] = b2f(qv.z); qs[e][c4 + 3] = b2f(qv.w);
    ks[e][c4] = b2f(kv.x); ks[e][c4 + 1] = b2f(kv.y); ks[e][c4 + 2] = b2f(kv.z); ks[e][c4 + 3] = b2f(kv.w);
    vs[e][c4] = b2f(vv.x); vs[e][c4 + 1] = b2f(vv.y); vs[e][c4 + 2] = b2f(vv.z); vs[e][c4 + 3] = b2f(vv.w);
    __syncthreads();
    int ee = t >> 4, ff = t & 15;
    float s = 0.f;
#pragma unroll
    for (int d = 0; d < 64; ++d) s = fmaf(qs[ee][d], ks[ff][d], s);
    sc[ee][ff] = s * 0.125f - sps_s[h] * dl[ee][ff];
    __syncthreads();
    if (t < 16) {
      float m = -1e30f;
      for (int f = 0; f < 16; ++f) m = fmaxf(m, sc[t][f]);
      float sum = 0.f;
      for (int f = 0; f < 16; ++f) { float pe = expf(sc[t][f] - m); sc[t][f] = pe; sum += pe; }
      float inv = 1.f / sum;
      for (int f = 0; f < 16; ++f) sc[t][f] *= inv;
    }
    __syncthreads();
#pragma unroll
    for (int r = 0; r < 4; ++r) {
      int idx = t + 256 * r;
      int oe = idx >> 6, od = idx & 63;
      float acc = 0.f;
#pragma unroll
      for (int f = 0; f < 16; ++f) acc = fmaf(sc[oe][f], vs[f][od], acc);
      o[(size_t)(nq * 16 + oe) * 1024 + h * 64 + od] = __float2bfloat16(acc);
    }
    __syncthreads();
  }
}

// ---------------- final VAE head elementwise ----------------
__global__ __launch_bounds__(64) void final_kernel(const float* __restrict__ tmp,
                                                   const float* __restrict__ eps,
                                                   float* __restrict__ out) {
  int r = blockIdx.x; int j = threadIdx.x;
  float mu = tmp[r * 128 + j];
  float lv = fminf(tmp[r * 128 + 64 + j], 5.0f);
  float zs = mu + eps[r * 64 + j] * expf(0.5f * lv);
  out[r * 64 + j] = zs;
  out[262144 + r * 64 + j] = mu;
  out[524288 + r * 64 + j] = lv;
}

extern "C" void kernel_launch(void* const* d_in, const int* in_sizes, int n_in,
                              void* d_out, int out_size, void* d_ws, size_t ws_size,
                              hipStream_t stream) {
  (void)in_sizes; (void)n_in; (void)out_size;
  const float* coords = (const float*)d_in[0];
  const float* eps    = (const float*)d_in[1];
  const float* emb    = (const float*)d_in[2];
  const float* ln1_g  = (const float*)d_in[3];
  const float* ln1_b  = (const float*)d_in[4];
  const float* Wqkv   = (const float*)d_in[5];
  const float* bqkv   = (const float*)d_in[6];
  const float* dist_scale = (const float*)d_in[7];
  const float* Wo     = (const float*)d_in[8];
  const float* bo     = (const float*)d_in[9];
  const float* ln2_g  = (const float*)d_in[10];
  const float* ln2_b  = (const float*)d_in[11];
  const float* Wf1    = (const float*)d_in[12];
  const float* bf1    = (const float*)d_in[13];
  const float* Wf2    = (const float*)d_in[14];
  const float* bf2    = (const float*)d_in[15];
  const float* lnf_g  = (const float*)d_in[16];
  const float* lnf_b  = (const float*)d_in[17];
  const float* We1    = (const float*)d_in[18];
  const float* be1    = (const float*)d_in[19];
  const float* We2    = (const float*)d_in[20];
  const float* be2    = (const float*)d_in[21];

  char* ws = (char*)d_ws;
  int*   edges = (int*)ws;                                        // 256 KB
  float* dist  = (float*)(ws + (4ull << 20));                     // 4 MB
  __hip_bfloat16* hfinal = (__hip_bfloat16*)(ws + (8ull << 20));  // 8 MB
  __hip_bfloat16* gated  = (__hip_bfloat16*)(ws + (16ull << 20)); // 4 MB
  float* tmp   = (float*)(ws + (20ull << 20));                    // 2 MB
  __hip_bfloat16* wbase = (__hip_bfloat16*)(ws + (24ull << 20));  // ~69.3 MB
  size_t woff = 0;
  __hip_bfloat16* wqkvT = wbase + woff; woff += 2ull * 3072 * 1024;
  __hip_bfloat16* woT   = wbase + woff; woff += 2ull * 1024 * 1024;
  __hip_bfloat16* wf1T  = wbase + woff; woff += 2ull * 8192 * 1024;
  __hip_bfloat16* wf2T  = wbase + woff; woff += 2ull * 1024 * 4096;
  __hip_bfloat16* we1T  = wbase + woff; woff += 1024ull * 1024;
  __hip_bfloat16* we2T  = wbase + woff; woff += 128ull * 512;

  const size_t FIXED = 96ull << 20;
  int CQ = 4096;
  while (CQ > 256 && FIXED + (size_t)CQ * 16 * 14336ull > ws_size) CQ >>= 1;
  if (FIXED + (size_t)CQ * 16 * 14336ull > ws_size) return;  // ws too small: leave poison
  size_t CT = (size_t)CQ * KNNK;
  char* creg = ws + FIXED;
  float* zbuf = (float*)creg;                                    // CT x 1024 fp32
  __hip_bfloat16* hbuf = (__hip_bfloat16*)(creg + CT * 4096);    // CT x 1024 bf16 (h / attn-out)
  __hip_bfloat16* sh8  = (__hip_bfloat16*)(creg + CT * 6144);    // CT x 4096 bf16 (qkv / gated)

  knn_kernel<<<NQ, 64, 0, stream>>>(coords, edges);
  dist_kernel<<<NQ, 256, 0, stream>>>(coords, edges, dist);
  for (int l = 0; l < NLAYER; ++l) {
    wconv_kernel<<<dim3(96, 32), 256, 0, stream>>>(Wqkv + (size_t)l * 1024 * 3072,
                                                   wqkvT + (size_t)l * 3072 * 1024, 1024, 3072);
    wconv_kernel<<<dim3(32, 32), 256, 0, stream>>>(Wo + (size_t)l * 1024 * 1024,
                                                   woT + (size_t)l * 1024 * 1024, 1024, 1024);
    wconv_kernel<<<dim3(256, 32), 256, 0, stream>>>(Wf1 + (size_t)l * 1024 * 8192,
                                                    wf1T + (size_t)l * 8192 * 1024, 1024, 8192);
    wconv_kernel<<<dim3(32, 128), 256, 0, stream>>>(Wf2 + (size_t)l * 4096 * 1024,
                                                    wf2T + (size_t)l * 1024 * 4096, 4096, 1024);
  }
  wconv_kernel<<<dim3(32, 32), 256, 0, stream>>>(We1, we1T, 1024, 1024);
  wconv_kernel<<<dim3(4, 16), 256, 0, stream>>>(We2, we2T, 512, 128);

  int NCH = NQ / CQ;
  int MT128 = (int)(CT / 128);   // T128/G32 M-tiles
  for (int c = 0; c < NCH; ++c) {
    zinit_kernel<<<(int)CT, 256, 0, stream>>>(edges, emb, zbuf, (int)(c * CT));
    for (int l = 0; l < NLAYER; ++l) {
      ln_kernel<<<(int)CT, 256, 0, stream>>>(zbuf, DIM, ln1_g + l * DIM, ln1_b + l * DIM, hbuf);
      gemmT128_kernel<0><<<MT128 * 24, 256, 0, stream>>>(
          (const ushort_t*)hbuf, (const ushort_t*)(wqkvT + (size_t)l * 3072 * 1024),
          bqkv + l * 3072, sh8, 1024, MT128, 3072, 24, 4);
      attn_kernel<<<CQ, 256, 0, stream>>>(sh8, dist + (size_t)c * CQ * 256,
                                          dist_scale + l * NHEAD, hbuf);
      gemmT128_kernel<1><<<MT128 * 8, 256, 0, stream>>>(
          (const ushort_t*)hbuf, (const ushort_t*)(woT + (size_t)l * 1024 * 1024),
          bo + l * DIM, zbuf, 1024, MT128, 1024, 8, 2);
      ln_kernel<<<(int)CT, 256, 0, stream>>>(zbuf, DIM, ln2_g + l * DIM, ln2_b + l * DIM, hbuf);
      gemmG32_kernel<<<MT128 * 32, 512, 0, stream>>>(
          (const ushort_t*)hbuf, (const ushort_t*)(wf1T + (size_t)l * 8192 * 1024),
          bf1 + l * 2 * DFFN, sh8, 1024, MT128, 4096, 4096, 32, 4);
      gemmT128_kernel<1><<<MT128 * 8, 256, 0, stream>>>(
          (const ushort_t*)sh8, (const ushort_t*)(wf2T + (size_t)l * 1024 * 4096),
          bf2 + l * DIM, zbuf, 4096, MT128, 1024, 8, 2);
    }
    ln_kernel<<<CQ, 256, 0, stream>>>(zbuf, KNNK * DIM, lnf_g, lnf_b,
                                      hfinal + (size_t)c * CQ * DIM);
  }

  mgemm_kernel<2><<<dim3(4, 32), 256, 0, stream>>>(hfinal, we1T, be1, gated, 1024, 512, 512);
  mgemm_kernel<3><<<dim3(1, 32), 256, 0, stream>>>(gated, we2T, be2, tmp, 512, 0, 128);
  final_kernel<<<NQ, 64, 0, stream>>>(tmp, eps, (float*)d_out);
}

// Round 10
// 6514.819 us; speedup vs baseline: 1.0018x; 1.0018x over previous
//
#include <hip/hip_runtime.h>
#include <hip/hip_bf16.h>
#include <math.h>

#define LLEN 512
#define KNNK 16
#define DIM 1024
#define NHEAD 16
#define NLAYER 2
#define DFFN 4096
#define POSCLIP 32
#define NQ 4096
#define NTOK 65536

typedef __attribute__((ext_vector_type(8))) short short8v;
typedef __attribute__((ext_vector_type(4))) float f32x4;
typedef unsigned short ushort_t;

__device__ __forceinline__ float b2f(ushort_t u) {
  union { unsigned u; float f; } x; x.u = ((unsigned)u) << 16; return x.f;
}

// 2D XCD-blocked tile mapping: B-slice L2-resident, A fetched ~once/XCD.
__device__ __forceinline__ void xcd_map(int bid, int Mtiles, int Ntiles, int XN,
                                        int& mt, int& nt) {
  int nt_per = Ntiles / XN;
  int mt_per = (Mtiles * XN) >> 3;
  int xcd = bid & 7, i = bid >> 3;
  int xn = xcd % XN, xm = xcd / XN;
  int ntl = i % nt_per, mtl = i / nt_per;
  mt = xm * mt_per + mtl;
  nt = xn * nt_per + ntl;
}

#define GLD16(gp, lp)                                                          \
  __builtin_amdgcn_global_load_lds(                                            \
      (const __attribute__((address_space(1))) void*)(gp),                     \
      (__attribute__((address_space(3))) void*)(lp), 16, 0, 0)

// ---------------- KNN: one wave per query ----------------
__global__ __launch_bounds__(64) void knn_kernel(const float* __restrict__ coords,
                                                 int* __restrict__ edges) {
  int n = blockIdx.x;
  int b = n / LLEN, i = n % LLEN;
  int lane = threadIdx.x;
  const float* cb = coords + (size_t)b * LLEN * 9;
  float xi = cb[i * 9 + 3], yi = cb[i * 9 + 4], zi = cb[i * 9 + 5];
  float d[8];
#pragma unroll
  for (int r = 0; r < 8; ++r) {
    int j = r * 64 + lane;
    float dx = xi - cb[j * 9 + 3];
    float dy = yi - cb[j * 9 + 4];
    float dz = zi - cb[j * 9 + 5];
    d[r] = dx * dx + dy * dy + dz * dz;
  }
  for (int s = 0; s < KNNK; ++s) {
    float bv = INFINITY; int bi = 1 << 30;
#pragma unroll
    for (int r = 0; r < 8; ++r) {
      int j = r * 64 + lane;
      if (d[r] < bv || (d[r] == bv && j < bi)) { bv = d[r]; bi = j; }
    }
#pragma unroll
    for (int off = 32; off > 0; off >>= 1) {
      float ov = __shfl_xor(bv, off);
      int   oi = __shfl_xor(bi, off);
      if (ov < bv || (ov == bv && oi < bi)) { bv = ov; bi = oi; }
    }
    if (lane == 0) edges[n * KNNK + s] = bi;
    if ((bi & 63) == lane) d[bi >> 6] = INFINITY;
  }
}

// ---------------- dist: 16x16 per query ----------------
__global__ __launch_bounds__(256) void dist_kernel(const float* __restrict__ coords,
                                                   const int* __restrict__ edges,
                                                   float* __restrict__ dist) {
  int n = blockIdx.x; int b = n / LLEN;
  __shared__ float tx[16], ty[16], tz[16];
  int t = threadIdx.x;
  const float* cb = coords + (size_t)b * LLEN * 9;
  if (t < 16) {
    int j = edges[n * KNNK + t];
    tx[t] = cb[j * 9 + 3]; ty[t] = cb[j * 9 + 4]; tz[t] = cb[j * 9 + 5];
  }
  __syncthreads();
  int e = t >> 4, f = t & 15;
  float dx = tx[e] - tx[f], dy = ty[e] - ty[f], dz = tz[e] - tz[f];
  dist[(size_t)n * 256 + t] = sqrtf(dx * dx + dy * dy + dz * dz + 1e-8f);
}

// ---------------- z init (chunked) ----------------
__global__ __launch_bounds__(256) void zinit_kernel(const int* __restrict__ edges,
                                                    const float* __restrict__ emb,
                                                    float* __restrict__ zbuf, int tok0) {
  int tl = blockIdx.x;
  int tok = tok0 + tl;
  int n = tok >> 4;
  int diff = edges[tok] - edges[n << 4];
  int idx = min(max(diff, -POSCLIP), POSCLIP) + POSCLIP;
  ((float4*)(zbuf + (size_t)tl * DIM))[threadIdx.x] =
      ((const float4*)(emb + (size_t)idx * DIM))[threadIdx.x];
}

// ---------------- LayerNorm fp32 in -> bf16 out ----------------
__global__ __launch_bounds__(256) void ln_kernel(const float* __restrict__ X, int stride,
                                                 const float* __restrict__ g,
                                                 const float* __restrict__ bta,
                                                 __hip_bfloat16* __restrict__ Y) {
  int row = blockIdx.x; int t = threadIdx.x;
  const float4* xr = (const float4*)(X + (size_t)row * stride);
  float4 v = xr[t];
  float s = v.x + v.y + v.z + v.w;
  __shared__ float red[8];
  for (int off = 32; off; off >>= 1) s += __shfl_down(s, off);
  int wid = t >> 6;
  if ((t & 63) == 0) red[wid] = s;
  __syncthreads();
  if (t == 0) red[4] = (red[0] + red[1] + red[2] + red[3]) * (1.0f / DIM);
  __syncthreads();
  float mean = red[4];
  float d0 = v.x - mean, d1 = v.y - mean, d2 = v.z - mean, d3 = v.w - mean;
  float s2 = d0 * d0 + d1 * d1 + d2 * d2 + d3 * d3;
  for (int off = 32; off; off >>= 1) s2 += __shfl_down(s2, off);
  if ((t & 63) == 0) red[wid] = s2;
  __syncthreads();
  if (t == 0) red[5] = rsqrtf((red[0] + red[1] + red[2] + red[3]) * (1.0f / DIM) + 1e-5f);
  __syncthreads();
  float rstd = red[5];
  float4 gv = ((const float4*)g)[t], bv = ((const float4*)bta)[t];
  size_t o = (size_t)row * DIM + t * 4;
  Y[o + 0] = __float2bfloat16(d0 * rstd * gv.x + bv.x);
  Y[o + 1] = __float2bfloat16(d1 * rstd * gv.y + bv.y);
  Y[o + 2] = __float2bfloat16(d2 * rstd * gv.z + bv.z);
  Y[o + 3] = __float2bfloat16(d3 * rstd * gv.w + bv.w);
}

// ---------------- weight fp32 K x N -> bf16 N x K ----------------
__global__ __launch_bounds__(256) void wconv_kernel(const float* __restrict__ W,
                                                    __hip_bfloat16* __restrict__ Wt,
                                                    int K, int N) {
  __shared__ float tile[32][33];
  int n0 = blockIdx.x * 32, k0 = blockIdx.y * 32;
  int c = threadIdx.x & 31, r = threadIdx.x >> 5;
#pragma unroll
  for (int i = 0; i < 4; ++i)
    tile[r + i * 8][c] = W[(size_t)(k0 + r + i * 8) * N + n0 + c];
  __syncthreads();
#pragma unroll
  for (int i = 0; i < 4; ++i)
    Wt[(size_t)(n0 + r + i * 8) * K + k0 + c] = __float2bfloat16(tile[c][r + i * 8]);
}

// BK=32 swizzle (rows are 64B = 4x16B chunks): LDS chunk position c holds
// global k-chunk c ^ ((row>>1)&3); reads use kg ^ ((fr>>1)&3). <=2-way (free).

// ============ gemmT128: BM=128, BN=128, BK=32, 256 thr (4 waves 2x2),
// 3-slot ring (48KB LDS). MODE 0: bf16 C = x  MODE 1: fp32 C += x
template <int MODE>
__global__ __launch_bounds__(256, 3) void gemmT128_kernel(
    const ushort_t* __restrict__ A,
    const ushort_t* __restrict__ Wt,
    const float* __restrict__ bias,
    void* __restrict__ Cout,
    int K, int Mtiles, int Cstride, int Ntiles, int XN) {
  __shared__ ushort_t Alds[3][4096];   // 3 x 128 rows x 32 bf16
  __shared__ ushort_t Blds[3][4096];
  int t = threadIdx.x;
  int w = t >> 6, lane = t & 63;
  int wr = w >> 1, wc = w & 1;
  int fr = lane & 15, kg = lane >> 4;

  int mt, nt;
  xcd_map(blockIdx.x, Mtiles, Ntiles, XN, mt, nt);
  size_t m0 = (size_t)mt * 128, n0 = (size_t)nt * 128;

  int stg_r = w * 16 + (lane >> 2);
  int stg_c = (((lane & 3) ^ ((lane >> 3) & 3)) << 3);  // elems, pre-swizzled
  const ushort_t* gAl = A + (m0 + stg_r) * (size_t)K + stg_c;
  const ushort_t* gBl = Wt + (n0 + stg_r) * (size_t)K + stg_c;
  int lds_w = w * 512;

#define SAt(slot, kcol, j) GLD16(gAl + (size_t)(j) * 64 * K + (kcol), Alds[slot] + (j) * 2048 + lds_w)
#define SBt(slot, kcol, j) GLD16(gBl + (size_t)(j) * 64 * K + (kcol), Blds[slot] + (j) * 2048 + lds_w)

  f32x4 acc[4][4];
#pragma unroll
  for (int i = 0; i < 4; ++i)
#pragma unroll
    for (int j = 0; j < 4; ++j) acc[i][j] = (f32x4){0.f, 0.f, 0.f, 0.f};

  int usw = ((kg ^ ((fr >> 1) & 3)) << 3);

  SAt(0, 0, 0); SAt(0, 0, 1); SBt(0, 0, 0); SBt(0, 0, 1);
  SAt(1, 32, 0); SAt(1, 32, 1); SBt(1, 32, 0); SBt(1, 32, 1);
  asm volatile("s_waitcnt vmcnt(4)" ::: "memory");
  __builtin_amdgcn_s_barrier();

  short8v af[4], bf[4];
  int NT = K >> 5;
  int sl = 0, st = 2;
  for (int ti = 0; ti < NT; ++ti) {
    int kS = (ti + 2) << 5;
    int stg = (ti + 2) < NT;
    const ushort_t* sA = Alds[sl];
    const ushort_t* sB = Blds[sl];
#pragma unroll
    for (int mi = 0; mi < 4; ++mi)
      af[mi] = *(const short8v*)(sA + (wr * 64 + mi * 16 + fr) * 32 + usw);
#pragma unroll
    for (int ni = 0; ni < 4; ++ni)
      bf[ni] = *(const short8v*)(sB + (wc * 64 + ni * 16 + fr) * 32 + usw);
    if (stg) { SAt(st, kS, 0); SAt(st, kS, 1); SBt(st, kS, 0); SBt(st, kS, 1); }
    __builtin_amdgcn_s_barrier();
    asm volatile("s_waitcnt lgkmcnt(0)" ::: "memory");
    __builtin_amdgcn_s_setprio(1);
#pragma unroll
    for (int mi = 0; mi < 4; ++mi)
#pragma unroll
      for (int ni = 0; ni < 4; ++ni)
        acc[mi][ni] = __builtin_amdgcn_mfma_f32_16x16x32_bf16(af[mi], bf[ni], acc[mi][ni], 0, 0, 0);
    __builtin_amdgcn_s_setprio(0);
    if (stg) { asm volatile("s_waitcnt vmcnt(4)" ::: "memory"); }
    else if (ti + 1 < NT) { asm volatile("s_waitcnt vmcnt(0)" ::: "memory"); }
    __builtin_amdgcn_s_barrier();
    sl = (sl == 2) ? 0 : sl + 1;
    st = (st == 2) ? 0 : st + 1;
  }
#undef SAt
#undef SBt

  int er = wr * 64 + (lane >> 4) * 4;
  int ec = wc * 64 + fr;
#pragma unroll
  for (int mi = 0; mi < 4; ++mi) {
#pragma unroll
    for (int ni = 0; ni < 4; ++ni) {
      int col = (int)n0 + ec + ni * 16;
      float bs = bias[col];
#pragma unroll
      for (int j = 0; j < 4; ++j) {
        size_t row = m0 + er + mi * 16 + j;
        size_t cidx = row * (size_t)Cstride + col;
        float x = acc[mi][ni][j] + bs;
        if constexpr (MODE == 0) {
          ((__hip_bfloat16*)Cout)[cidx] = __float2bfloat16(x);
        } else {
          ((float*)Cout)[cidx] += x;
        }
      }
    }
  }
}

// ============ gemmGW: fused gated ff1, 4 waves (2Mx2N), per-wave 64x64 of
// BOTH gated outputs -> 32 MFMA : 12 ds_read per K-tile (0.375 vs 0.5).
// BM=128, BN=128 dual, BK=32, 3-slot ring 72KB -> 2 blocks/CU.
__global__ __launch_bounds__(256, 2) void gemmGW_kernel(
    const ushort_t* __restrict__ A,
    const ushort_t* __restrict__ Wt,
    const float* __restrict__ bias,
    __hip_bfloat16* __restrict__ Cout,
    int K, int Mtiles, int Cstride, int NhRows, int Ntiles, int XN) {
  __shared__ ushort_t Alds[3][4096];   // 3 x 128 x 32
  __shared__ ushort_t B1lds[3][4096];
  __shared__ ushort_t B2lds[3][4096];
  int t = threadIdx.x;
  int w = t >> 6, lane = t & 63;
  int wr = w >> 1, wc = w & 1;
  int fr = lane & 15, kg = lane >> 4;

  int mt, nt;
  xcd_map(blockIdx.x, Mtiles, Ntiles, XN, mt, nt);
  size_t m0 = (size_t)mt * 128, n0 = (size_t)nt * 128;

  int stg_r = w * 16 + (lane >> 2);
  int stg_c = (((lane & 3) ^ ((lane >> 3) & 3)) << 3);
  const ushort_t* gAl = A + (m0 + stg_r) * (size_t)K + stg_c;
  const ushort_t* gB1 = Wt + (n0 + stg_r) * (size_t)K + stg_c;
  const ushort_t* gB2 = Wt + ((size_t)NhRows + n0 + stg_r) * (size_t)K + stg_c;
  int lds_w = w * 512;

#define SAg(slot, kcol, j) GLD16(gAl + (size_t)(j) * 64 * K + (kcol), Alds[slot] + (j) * 2048 + lds_w)
#define SB1g(slot, kcol, j) GLD16(gB1 + (size_t)(j) * 64 * K + (kcol), B1lds[slot] + (j) * 2048 + lds_w)
#define SB2g(slot, kcol, j) GLD16(gB2 + (size_t)(j) * 64 * K + (kcol), B2lds[slot] + (j) * 2048 + lds_w)

  f32x4 acc1[4][4], acc2[4][4];
#pragma unroll
  for (int i = 0; i < 4; ++i)
#pragma unroll
    for (int j = 0; j < 4; ++j) {
      acc1[i][j] = (f32x4){0.f, 0.f, 0.f, 0.f};
      acc2[i][j] = (f32x4){0.f, 0.f, 0.f, 0.f};
    }

  int usw = ((kg ^ ((fr >> 1) & 3)) << 3);

  // prologue: T0 -> slot0, T1 -> slot1 (12 issues); wait T0 (T1's 6 in flight)
  SAg(0, 0, 0); SAg(0, 0, 1); SB1g(0, 0, 0); SB1g(0, 0, 1); SB2g(0, 0, 0); SB2g(0, 0, 1);
  SAg(1, 32, 0); SAg(1, 32, 1); SB1g(1, 32, 0); SB1g(1, 32, 1); SB2g(1, 32, 0); SB2g(1, 32, 1);
  asm volatile("s_waitcnt vmcnt(6)" ::: "memory");
  __builtin_amdgcn_s_barrier();

  short8v af[4], bf1[4], bf2[4];
  int NT = K >> 5;
  int sl = 0, st = 2;
  for (int ti = 0; ti < NT; ++ti) {
    int kS = (ti + 2) << 5;
    int stg = (ti + 2) < NT;
    const ushort_t* sA = Alds[sl];
    const ushort_t* sB1 = B1lds[sl];
    const ushort_t* sB2 = B2lds[sl];
#pragma unroll
    for (int mi = 0; mi < 4; ++mi)
      af[mi] = *(const short8v*)(sA + (wr * 64 + mi * 16 + fr) * 32 + usw);
#pragma unroll
    for (int ni = 0; ni < 4; ++ni) {
      bf1[ni] = *(const short8v*)(sB1 + (wc * 64 + ni * 16 + fr) * 32 + usw);
      bf2[ni] = *(const short8v*)(sB2 + (wc * 64 + ni * 16 + fr) * 32 + usw);
    }
    if (stg) {
      SAg(st, kS, 0); SAg(st, kS, 1);
      SB1g(st, kS, 0); SB1g(st, kS, 1);
      SB2g(st, kS, 0); SB2g(st, kS, 1);
    }
    __builtin_amdgcn_s_barrier();
    asm volatile("s_waitcnt lgkmcnt(0)" ::: "memory");
    __builtin_amdgcn_s_setprio(1);
#pragma unroll
    for (int mi = 0; mi < 4; ++mi)
#pragma unroll
      for (int ni = 0; ni < 4; ++ni) {
        acc1[mi][ni] = __builtin_amdgcn_mfma_f32_16x16x32_bf16(af[mi], bf1[ni], acc1[mi][ni], 0, 0, 0);
        acc2[mi][ni] = __builtin_amdgcn_mfma_f32_16x16x32_bf16(af[mi], bf2[ni], acc2[mi][ni], 0, 0, 0);
      }
    __builtin_amdgcn_s_setprio(0);
    if (stg) { asm volatile("s_waitcnt vmcnt(6)" ::: "memory"); }
    else if (ti + 1 < NT) { asm volatile("s_waitcnt vmcnt(0)" ::: "memory"); }
    __builtin_amdgcn_s_barrier();
    sl = (sl == 2) ? 0 : sl + 1;
    st = (st == 2) ? 0 : st + 1;
  }
#undef SAg
#undef SB1g
#undef SB2g

  int er = wr * 64 + (lane >> 4) * 4;
  int ec = wc * 64 + fr;
#pragma unroll
  for (int mi = 0; mi < 4; ++mi) {
#pragma unroll
    for (int ni = 0; ni < 4; ++ni) {
      int col = (int)n0 + ec + ni * 16;
      float b1v = bias[col];
      float b2v = bias[NhRows + col];
#pragma unroll
      for (int j = 0; j < 4; ++j) {
        size_t row = m0 + er + mi * 16 + j;
        float x1 = acc1[mi][ni][j] + b1v;
        float x2 = acc2[mi][ni][j] + b2v;
        float sg = x1 / (1.f + expf(-x1));
        Cout[row * (size_t)Cstride + col] = __float2bfloat16(sg * x2);
      }
    }
  }
}

// ---------------- small 128x128 GEMM (final head only) ----------------
template <int MODE>
__global__ __launch_bounds__(256) void mgemm_kernel(
    const __hip_bfloat16* __restrict__ A,
    const __hip_bfloat16* __restrict__ Wt,
    const float* __restrict__ bias,
    void* __restrict__ Cout,
    int K, int Nh, int Cstride) {
  __shared__ ushort_t As[4 * 128 * 8];
  __shared__ ushort_t Bs[4 * 128 * 8];
  __shared__ ushort_t Bs2[(MODE == 2) ? 4 * 128 * 8 : 8];
  int t = threadIdx.x;
  int w = t >> 6, lane = t & 63;
  int wr = w >> 1, wc = w & 1;
  size_t m0 = (size_t)blockIdx.y * 128;
  size_t n0 = (size_t)blockIdx.x * 128;
  int cell0 = w * 64 + lane;
  int cell1 = 256 + w * 64 + lane;
  int kg0 = cell0 >> 7, rw0 = cell0 & 127;
  int kg1 = cell1 >> 7, rw1 = cell1 & 127;
  const ushort_t* gA = (const ushort_t*)A;
  const ushort_t* gB = (const ushort_t*)Wt;
  const ushort_t* gB2 = (const ushort_t*)(Wt + (size_t)Nh * K);
  size_t a0 = (m0 + rw0) * (size_t)K + kg0 * 8;
  size_t a1 = (m0 + rw1) * (size_t)K + kg1 * 8;
  size_t b0 = (n0 + rw0) * (size_t)K + kg0 * 8;
  size_t b1 = (n0 + rw1) * (size_t)K + kg1 * 8;
  int ldso0 = w * 1024;
  int ldso1 = 4096 + w * 1024;
  f32x4 acc[4][4];
  f32x4 acc2[4][4];
#pragma unroll
  for (int i = 0; i < 4; ++i)
#pragma unroll
    for (int j = 0; j < 4; ++j) {
      acc[i][j] = (f32x4){0.f, 0.f, 0.f, 0.f};
      acc2[i][j] = (f32x4){0.f, 0.f, 0.f, 0.f};
    }
  int fr = lane & 15, kg = lane >> 4;
  int abase = (kg * 128 + wr * 64 + fr) * 16;
  int bbase = (kg * 128 + wc * 64 + fr) * 16;
  for (int k0 = 0; k0 < K; k0 += 32) {
    __syncthreads();
    GLD16(gA + a0 + k0, (char*)As + ldso0);
    GLD16(gA + a1 + k0, (char*)As + ldso1);
    GLD16(gB + b0 + k0, (char*)Bs + ldso0);
    GLD16(gB + b1 + k0, (char*)Bs + ldso1);
    if constexpr (MODE == 2) {
      GLD16(gB2 + b0 + k0, (char*)Bs2 + ldso0);
      GLD16(gB2 + b1 + k0, (char*)Bs2 + ldso1);
    }
    __syncthreads();
    short8v a[4], b[4];
#pragma unroll
    for (int mi = 0; mi < 4; ++mi)
      a[mi] = *(const short8v*)((const char*)As + abase + mi * 256);
#pragma unroll
    for (int ni = 0; ni < 4; ++ni)
      b[ni] = *(const short8v*)((const char*)Bs + bbase + ni * 256);
#pragma unroll
    for (int mi = 0; mi < 4; ++mi)
#pragma unroll
      for (int ni = 0; ni < 4; ++ni)
        acc[mi][ni] = __builtin_amdgcn_mfma_f32_16x16x32_bf16(a[mi], b[ni], acc[mi][ni], 0, 0, 0);
    if constexpr (MODE == 2) {
#pragma unroll
      for (int ni = 0; ni < 4; ++ni)
        b[ni] = *(const short8v*)((const char*)Bs2 + bbase + ni * 256);
#pragma unroll
      for (int mi = 0; mi < 4; ++mi)
#pragma unroll
        for (int ni = 0; ni < 4; ++ni)
          acc2[mi][ni] = __builtin_amdgcn_mfma_f32_16x16x32_bf16(a[mi], b[ni], acc2[mi][ni], 0, 0, 0);
    }
  }
  int er = wr * 64 + (lane >> 4) * 4;
  int ec = wc * 64 + fr;
#pragma unroll
  for (int mi = 0; mi < 4; ++mi) {
#pragma unroll
    for (int ni = 0; ni < 4; ++ni) {
      int col = (int)n0 + ec + ni * 16;
      float bs1 = bias[col];
#pragma unroll
      for (int j = 0; j < 4; ++j) {
        size_t row = m0 + er + mi * 16 + j;
        size_t cidx = row * (size_t)Cstride + col;
        float x = acc[mi][ni][j] + bs1;
        if constexpr (MODE == 3) {
          ((float*)Cout)[cidx] = x;
        } else {
          float x2 = acc2[mi][ni][j] + bias[Nh + col];
          float sig = 1.f / (1.f + expf(-x));
          ((__hip_bfloat16*)Cout)[cidx] = __float2bfloat16(x * sig * x2);
        }
      }
    }
  }
}

// ---------------- attention: one block per query, loop heads ----------------
__global__ __launch_bounds__(256) void attn_kernel(const __hip_bfloat16* __restrict__ qkv,
                                                   const float* __restrict__ dist,
                                                   const float* __restrict__ ds_l,
                                                   __hip_bfloat16* __restrict__ o) {
  int nq = blockIdx.x;
  int t = threadIdx.x;
  __shared__ float qs[16][65], ks[16][65], vs[16][65];
  __shared__ float sc[16][17], dl[16][17];
  __shared__ float sps_s[NHEAD];
  dl[t >> 4][t & 15] = dist[(size_t)nq * 256 + t];
  if (t < NHEAD) sps_s[t] = log1pf(expf(ds_l[t]));
  size_t base = (size_t)nq * 16 * 3072;
  int e = t >> 4, c4 = (t & 15) * 4;
  const ushort_t* qp = (const ushort_t*)qkv;
  for (int h = 0; h < NHEAD; ++h) {
    const ushort_t* p = qp + base + (size_t)e * 3072 + h * 64 + c4;
    ushort4 qv = *(const ushort4*)p;
    ushort4 kv = *(const ushort4*)(p + 1024);
    ushort4 vv = *(const ushort4*)(p + 2048);
    qs[e][c4] = b2f(qv.x); qs[e][c4 + 1] = b2f(qv.y); qs[e][c4 + 2] = b2f(qv.z); qs[e][c4 + 3] = b2f(qv.w);
    ks[e][c4] = b2f(kv.x); ks[e][c4 + 1] = b2f(kv.y); ks[e][c4 + 2] = b2f(kv.z); ks[e][c4 + 3] = b2f(kv.w);
    vs[e][c4] = b2f(vv.x); vs[e][c4 + 1] = b2f(vv.y); vs[e][c4 + 2] = b2f(vv.z); vs[e][c4 + 3] = b2f(vv.w);
    __syncthreads();
    int ee = t >> 4, ff = t & 15;
    float s = 0.f;
#pragma unroll
    for (int d = 0; d < 64; ++d) s = fmaf(qs[ee][d], ks[ff][d], s);
    sc[ee][ff] = s * 0.125f - sps_s[h] * dl[ee][ff];
    __syncthreads();
    if (t < 16) {
      float m = -1e30f;
      for (int f = 0; f < 16; ++f) m = fmaxf(m, sc[t][f]);
      float sum = 0.f;
      for (int f = 0; f < 16; ++f) { float pe = expf(sc[t][f] - m); sc[t][f] = pe; sum += pe; }
      float inv = 1.f / sum;
      for (int f = 0; f < 16; ++f) sc[t][f] *= inv;
    }
    __syncthreads();
#pragma unroll
    for (int r = 0; r < 4; ++r) {
      int idx = t + 256 * r;
      int oe = idx >> 6, od = idx & 63;
      float acc = 0.f;
#pragma unroll
      for (int f = 0; f < 16; ++f) acc = fmaf(sc[oe][f], vs[f][od], acc);
      o[(size_t)(nq * 16 + oe) * 1024 + h * 64 + od] = __float2bfloat16(acc);
    }
    __syncthreads();
  }
}

// ---------------- final VAE head elementwise ----------------
__global__ __launch_bounds__(64) void final_kernel(const float* __restrict__ tmp,
                                                   const float* __restrict__ eps,
                                                   float* __restrict__ out) {
  int r = blockIdx.x; int j = threadIdx.x;
  float mu = tmp[r * 128 + j];
  float lv = fminf(tmp[r * 128 + 64 + j], 5.0f);
  float zs = mu + eps[r * 64 + j] * expf(0.5f * lv);
  out[r * 64 + j] = zs;
  out[262144 + r * 64 + j] = mu;
  out[524288 + r * 64 + j] = lv;
}

extern "C" void kernel_launch(void* const* d_in, const int* in_sizes, int n_in,
                              void* d_out, int out_size, void* d_ws, size_t ws_size,
                              hipStream_t stream) {
  (void)in_sizes; (void)n_in; (void)out_size;
  const float* coords = (const float*)d_in[0];
  const float* eps    = (const float*)d_in[1];
  const float* emb    = (const float*)d_in[2];
  const float* ln1_g  = (const float*)d_in[3];
  const float* ln1_b  = (const float*)d_in[4];
  const float* Wqkv   = (const float*)d_in[5];
  const float* bqkv   = (const float*)d_in[6];
  const float* dist_scale = (const float*)d_in[7];
  const float* Wo     = (const float*)d_in[8];
  const float* bo     = (const float*)d_in[9];
  const float* ln2_g  = (const float*)d_in[10];
  const float* ln2_b  = (const float*)d_in[11];
  const float* Wf1    = (const float*)d_in[12];
  const float* bf1    = (const float*)d_in[13];
  const float* Wf2    = (const float*)d_in[14];
  const float* bf2    = (const float*)d_in[15];
  const float* lnf_g  = (const float*)d_in[16];
  const float* lnf_b  = (const float*)d_in[17];
  const float* We1    = (const float*)d_in[18];
  const float* be1    = (const float*)d_in[19];
  const float* We2    = (const float*)d_in[20];
  const float* be2    = (const float*)d_in[21];

  char* ws = (char*)d_ws;
  int*   edges = (int*)ws;                                        // 256 KB
  float* dist  = (float*)(ws + (4ull << 20));                     // 4 MB
  __hip_bfloat16* hfinal = (__hip_bfloat16*)(ws + (8ull << 20));  // 8 MB
  __hip_bfloat16* gated  = (__hip_bfloat16*)(ws + (16ull << 20)); // 4 MB
  float* tmp   = (float*)(ws + (20ull << 20));                    // 2 MB
  __hip_bfloat16* wbase = (__hip_bfloat16*)(ws + (24ull << 20));  // ~69.3 MB
  size_t woff = 0;
  __hip_bfloat16* wqkvT = wbase + woff; woff += 2ull * 3072 * 1024;
  __hip_bfloat16* woT   = wbase + woff; woff += 2ull * 1024 * 1024;
  __hip_bfloat16* wf1T  = wbase + woff; woff += 2ull * 8192 * 1024;
  __hip_bfloat16* wf2T  = wbase + woff; woff += 2ull * 1024 * 4096;
  __hip_bfloat16* we1T  = wbase + woff; woff += 1024ull * 1024;
  __hip_bfloat16* we2T  = wbase + woff; woff += 128ull * 512;

  const size_t FIXED = 96ull << 20;
  int CQ = 4096;
  while (CQ > 256 && FIXED + (size_t)CQ * 16 * 14336ull > ws_size) CQ >>= 1;
  if (FIXED + (size_t)CQ * 16 * 14336ull > ws_size) return;  // ws too small: leave poison
  size_t CT = (size_t)CQ * KNNK;
  char* creg = ws + FIXED;
  float* zbuf = (float*)creg;                                    // CT x 1024 fp32
  __hip_bfloat16* hbuf = (__hip_bfloat16*)(creg + CT * 4096);    // CT x 1024 bf16 (h / attn-out)
  __hip_bfloat16* sh8  = (__hip_bfloat16*)(creg + CT * 6144);    // CT x 4096 bf16 (qkv / gated)

  knn_kernel<<<NQ, 64, 0, stream>>>(coords, edges);
  dist_kernel<<<NQ, 256, 0, stream>>>(coords, edges, dist);
  for (int l = 0; l < NLAYER; ++l) {
    wconv_kernel<<<dim3(96, 32), 256, 0, stream>>>(Wqkv + (size_t)l * 1024 * 3072,
                                                   wqkvT + (size_t)l * 3072 * 1024, 1024, 3072);
    wconv_kernel<<<dim3(32, 32), 256, 0, stream>>>(Wo + (size_t)l * 1024 * 1024,
                                                   woT + (size_t)l * 1024 * 1024, 1024, 1024);
    wconv_kernel<<<dim3(256, 32), 256, 0, stream>>>(Wf1 + (size_t)l * 1024 * 8192,
                                                    wf1T + (size_t)l * 8192 * 1024, 1024, 8192);
    wconv_kernel<<<dim3(32, 128), 256, 0, stream>>>(Wf2 + (size_t)l * 4096 * 1024,
                                                    wf2T + (size_t)l * 1024 * 4096, 4096, 1024);
  }
  wconv_kernel<<<dim3(32, 32), 256, 0, stream>>>(We1, we1T, 1024, 1024);
  wconv_kernel<<<dim3(4, 16), 256, 0, stream>>>(We2, we2T, 512, 128);

  int NCH = NQ / CQ;
  int MT128 = (int)(CT / 128);
  for (int c = 0; c < NCH; ++c) {
    zinit_kernel<<<(int)CT, 256, 0, stream>>>(edges, emb, zbuf, (int)(c * CT));
    for (int l = 0; l < NLAYER; ++l) {
      ln_kernel<<<(int)CT, 256, 0, stream>>>(zbuf, DIM, ln1_g + l * DIM, ln1_b + l * DIM, hbuf);
      gemmT128_kernel<0><<<MT128 * 24, 256, 0, stream>>>(
          (const ushort_t*)hbuf, (const ushort_t*)(wqkvT + (size_t)l * 3072 * 1024),
          bqkv + l * 3072, sh8, 1024, MT128, 3072, 24, 4);
      attn_kernel<<<CQ, 256, 0, stream>>>(sh8, dist + (size_t)c * CQ * 256,
                                          dist_scale + l * NHEAD, hbuf);
      gemmT128_kernel<1><<<MT128 * 8, 256, 0, stream>>>(
          (const ushort_t*)hbuf, (const ushort_t*)(woT + (size_t)l * 1024 * 1024),
          bo + l * DIM, zbuf, 1024, MT128, 1024, 8, 2);
      ln_kernel<<<(int)CT, 256, 0, stream>>>(zbuf, DIM, ln2_g + l * DIM, ln2_b + l * DIM, hbuf);
      gemmGW_kernel<<<MT128 * 32, 256, 0, stream>>>(
          (const ushort_t*)hbuf, (const ushort_t*)(wf1T + (size_t)l * 8192 * 1024),
          bf1 + l * 2 * DFFN, sh8, 1024, MT128, 4096, 4096, 32, 4);
      gemmT128_kernel<1><<<MT128 * 8, 256, 0, stream>>>(
          (const ushort_t*)sh8, (const ushort_t*)(wf2T + (size_t)l * 1024 * 4096),
          bf2 + l * DIM, zbuf, 4096, MT128, 1024, 8, 2);
    }
    ln_kernel<<<CQ, 256, 0, stream>>>(zbuf, KNNK * DIM, lnf_g, lnf_b,
                                      hfinal + (size_t)c * CQ * DIM);
  }

  mgemm_kernel<2><<<dim3(4, 32), 256, 0, stream>>>(hfinal, we1T, be1, gated, 1024, 512, 512);
  mgemm_kernel<3><<<dim3(1, 32), 256, 0, stream>>>(gated, we2T, be2, tmp, 512, 0, 128);
  final_kernel<<<NQ, 64, 0, stream>>>(tmp, eps, (float*)d_out);
}

// Round 11
// 6356.441 us; speedup vs baseline: 1.0268x; 1.0249x over previous
//
#include <hip/hip_runtime.h>
#include <hip/hip_bf16.h>
#include <math.h>

#define LLEN 512
#define KNNK 16
#define DIM 1024
#define NHEAD 16
#define NLAYER 2
#define DFFN 4096
#define POSCLIP 32
#define NQ 4096
#define NTOK 65536
#define HSPLIT 4

typedef __attribute__((ext_vector_type(8))) short short8v;
typedef __attribute__((ext_vector_type(4))) float f32x4;
typedef unsigned short ushort_t;

__device__ __forceinline__ float b2f(ushort_t u) {
  union { unsigned u; float f; } x; x.u = ((unsigned)u) << 16; return x.f;
}

// 2D XCD-blocked tile mapping: B-slice L2-resident, A fetched ~once/XCD.
__device__ __forceinline__ void xcd_map(int bid, int Mtiles, int Ntiles, int XN,
                                        int& mt, int& nt) {
  int nt_per = Ntiles / XN;
  int mt_per = (Mtiles * XN) >> 3;
  int xcd = bid & 7, i = bid >> 3;
  int xn = xcd % XN, xm = xcd / XN;
  int ntl = i % nt_per, mtl = i / nt_per;
  mt = xm * mt_per + mtl;
  nt = xn * nt_per + ntl;
}

#define GLD16(gp, lp)                                                          \
  __builtin_amdgcn_global_load_lds(                                            \
      (const __attribute__((address_space(1))) void*)(gp),                     \
      (__attribute__((address_space(3))) void*)(lp), 16, 0, 0)

// ---------------- KNN: one wave per query ----------------
__global__ __launch_bounds__(64) void knn_kernel(const float* __restrict__ coords,
                                                 int* __restrict__ edges) {
  int n = blockIdx.x;
  int b = n / LLEN, i = n % LLEN;
  int lane = threadIdx.x;
  const float* cb = coords + (size_t)b * LLEN * 9;
  float xi = cb[i * 9 + 3], yi = cb[i * 9 + 4], zi = cb[i * 9 + 5];
  float d[8];
#pragma unroll
  for (int r = 0; r < 8; ++r) {
    int j = r * 64 + lane;
    float dx = xi - cb[j * 9 + 3];
    float dy = yi - cb[j * 9 + 4];
    float dz = zi - cb[j * 9 + 5];
    d[r] = dx * dx + dy * dy + dz * dz;
  }
  for (int s = 0; s < KNNK; ++s) {
    float bv = INFINITY; int bi = 1 << 30;
#pragma unroll
    for (int r = 0; r < 8; ++r) {
      int j = r * 64 + lane;
      if (d[r] < bv || (d[r] == bv && j < bi)) { bv = d[r]; bi = j; }
    }
#pragma unroll
    for (int off = 32; off > 0; off >>= 1) {
      float ov = __shfl_xor(bv, off);
      int   oi = __shfl_xor(bi, off);
      if (ov < bv || (ov == bv && oi < bi)) { bv = ov; bi = oi; }
    }
    if (lane == 0) edges[n * KNNK + s] = bi;
    if ((bi & 63) == lane) d[bi >> 6] = INFINITY;
  }
}

// ---------------- dist: 16x16 per query ----------------
__global__ __launch_bounds__(256) void dist_kernel(const float* __restrict__ coords,
                                                   const int* __restrict__ edges,
                                                   float* __restrict__ dist) {
  int n = blockIdx.x; int b = n / LLEN;
  __shared__ float tx[16], ty[16], tz[16];
  int t = threadIdx.x;
  const float* cb = coords + (size_t)b * LLEN * 9;
  if (t < 16) {
    int j = edges[n * KNNK + t];
    tx[t] = cb[j * 9 + 3]; ty[t] = cb[j * 9 + 4]; tz[t] = cb[j * 9 + 5];
  }
  __syncthreads();
  int e = t >> 4, f = t & 15;
  float dx = tx[e] - tx[f], dy = ty[e] - ty[f], dz = tz[e] - tz[f];
  dist[(size_t)n * 256 + t] = sqrtf(dx * dx + dy * dy + dz * dz + 1e-8f);
}

// ---------------- z init (chunked) ----------------
__global__ __launch_bounds__(256) void zinit_kernel(const int* __restrict__ edges,
                                                    const float* __restrict__ emb,
                                                    float* __restrict__ zbuf, int tok0) {
  int tl = blockIdx.x;
  int tok = tok0 + tl;
  int n = tok >> 4;
  int diff = edges[tok] - edges[n << 4];
  int idx = min(max(diff, -POSCLIP), POSCLIP) + POSCLIP;
  ((float4*)(zbuf + (size_t)tl * DIM))[threadIdx.x] =
      ((const float4*)(emb + (size_t)idx * DIM))[threadIdx.x];
}

// ---------------- LayerNorm fp32 in -> bf16 out ----------------
__global__ __launch_bounds__(256) void ln_kernel(const float* __restrict__ X, int stride,
                                                 const float* __restrict__ g,
                                                 const float* __restrict__ bta,
                                                 __hip_bfloat16* __restrict__ Y) {
  int row = blockIdx.x; int t = threadIdx.x;
  const float4* xr = (const float4*)(X + (size_t)row * stride);
  float4 v = xr[t];
  float s = v.x + v.y + v.z + v.w;
  __shared__ float red[8];
  for (int off = 32; off; off >>= 1) s += __shfl_down(s, off);
  int wid = t >> 6;
  if ((t & 63) == 0) red[wid] = s;
  __syncthreads();
  if (t == 0) red[4] = (red[0] + red[1] + red[2] + red[3]) * (1.0f / DIM);
  __syncthreads();
  float mean = red[4];
  float d0 = v.x - mean, d1 = v.y - mean, d2 = v.z - mean, d3 = v.w - mean;
  float s2 = d0 * d0 + d1 * d1 + d2 * d2 + d3 * d3;
  for (int off = 32; off; off >>= 1) s2 += __shfl_down(s2, off);
  if ((t & 63) == 0) red[wid] = s2;
  __syncthreads();
  if (t == 0) red[5] = rsqrtf((red[0] + red[1] + red[2] + red[3]) * (1.0f / DIM) + 1e-5f);
  __syncthreads();
  float rstd = red[5];
  float4 gv = ((const float4*)g)[t], bv = ((const float4*)bta)[t];
  size_t o = (size_t)row * DIM + t * 4;
  Y[o + 0] = __float2bfloat16(d0 * rstd * gv.x + bv.x);
  Y[o + 1] = __float2bfloat16(d1 * rstd * gv.y + bv.y);
  Y[o + 2] = __float2bfloat16(d2 * rstd * gv.z + bv.z);
  Y[o + 3] = __float2bfloat16(d3 * rstd * gv.w + bv.w);
}

// ---------------- weight fp32 K x N -> bf16 N x K ----------------
__global__ __launch_bounds__(256) void wconv_kernel(const float* __restrict__ W,
                                                    __hip_bfloat16* __restrict__ Wt,
                                                    int K, int N) {
  __shared__ float tile[32][33];
  int n0 = blockIdx.x * 32, k0 = blockIdx.y * 32;
  int c = threadIdx.x & 31, r = threadIdx.x >> 5;
#pragma unroll
  for (int i = 0; i < 4; ++i)
    tile[r + i * 8][c] = W[(size_t)(k0 + r + i * 8) * N + n0 + c];
  __syncthreads();
#pragma unroll
  for (int i = 0; i < 4; ++i)
    Wt[(size_t)(n0 + r + i * 8) * K + k0 + c] = __float2bfloat16(tile[c][r + i * 8]);
}

// BK=32 swizzle (rows are 64B = 4x16B chunks): LDS chunk position c holds
// global k-chunk c ^ ((row>>1)&3); reads use kg ^ ((fr>>1)&3). <=2-way (free).
//
// SINGLE-BARRIER RING (r11): per K-tile: {ds_read(sl); stage(st); lgkmcnt(0);
// sched_barrier; MFMA; vmcnt(N); barrier}. Race ledger: gload->ds_read of slot
// X protected by per-wave vmcnt (tile t+1 complete at end-barrier of iter t) +
// end barrier; ds_read->gload overwrite protected because each wave's
// lgkmcnt(0) precedes its end barrier and the overwrite is issued after it.

// ============ gemmT128: BM=128, BN=128, BK=32, 256 thr (4 waves 2x2),
// 3-slot ring (48KB LDS). MODE 0: bf16 C = x  MODE 1: fp32 C += x
template <int MODE>
__global__ __launch_bounds__(256, 3) void gemmT128_kernel(
    const ushort_t* __restrict__ A,
    const ushort_t* __restrict__ Wt,
    const float* __restrict__ bias,
    void* __restrict__ Cout,
    int K, int Mtiles, int Cstride, int Ntiles, int XN) {
  __shared__ ushort_t Alds[3][4096];   // 3 x 128 rows x 32 bf16
  __shared__ ushort_t Blds[3][4096];
  int t = threadIdx.x;
  int w = t >> 6, lane = t & 63;
  int wr = w >> 1, wc = w & 1;
  int fr = lane & 15, kg = lane >> 4;

  int mt, nt;
  xcd_map(blockIdx.x, Mtiles, Ntiles, XN, mt, nt);
  size_t m0 = (size_t)mt * 128, n0 = (size_t)nt * 128;

  int stg_r = w * 16 + (lane >> 2);
  int stg_c = (((lane & 3) ^ ((lane >> 3) & 3)) << 3);  // elems, pre-swizzled
  const ushort_t* gAl = A + (m0 + stg_r) * (size_t)K + stg_c;
  const ushort_t* gBl = Wt + (n0 + stg_r) * (size_t)K + stg_c;
  int lds_w = w * 512;

#define SAt(slot, kcol, j) GLD16(gAl + (size_t)(j) * 64 * K + (kcol), Alds[slot] + (j) * 2048 + lds_w)
#define SBt(slot, kcol, j) GLD16(gBl + (size_t)(j) * 64 * K + (kcol), Blds[slot] + (j) * 2048 + lds_w)

  f32x4 acc[4][4];
#pragma unroll
  for (int i = 0; i < 4; ++i)
#pragma unroll
    for (int j = 0; j < 4; ++j) acc[i][j] = (f32x4){0.f, 0.f, 0.f, 0.f};

  int usw = ((kg ^ ((fr >> 1) & 3)) << 3);

  SAt(0, 0, 0); SAt(0, 0, 1); SBt(0, 0, 0); SBt(0, 0, 1);
  SAt(1, 32, 0); SAt(1, 32, 1); SBt(1, 32, 0); SBt(1, 32, 1);
  asm volatile("s_waitcnt vmcnt(4)" ::: "memory");
  __builtin_amdgcn_s_barrier();

  short8v af[4], bf[4];
  int NT = K >> 5;
  int sl = 0, st = 2;
  for (int ti = 0; ti < NT; ++ti) {
    int kS = (ti + 2) << 5;
    int stg = (ti + 2) < NT;
    const ushort_t* sA = Alds[sl];
    const ushort_t* sB = Blds[sl];
#pragma unroll
    for (int mi = 0; mi < 4; ++mi)
      af[mi] = *(const short8v*)(sA + (wr * 64 + mi * 16 + fr) * 32 + usw);
#pragma unroll
    for (int ni = 0; ni < 4; ++ni)
      bf[ni] = *(const short8v*)(sB + (wc * 64 + ni * 16 + fr) * 32 + usw);
    if (stg) { SAt(st, kS, 0); SAt(st, kS, 1); SBt(st, kS, 0); SBt(st, kS, 1); }
    asm volatile("s_waitcnt lgkmcnt(0)" ::: "memory");
    __builtin_amdgcn_sched_barrier(0);
    __builtin_amdgcn_s_setprio(1);
#pragma unroll
    for (int mi = 0; mi < 4; ++mi)
#pragma unroll
      for (int ni = 0; ni < 4; ++ni)
        acc[mi][ni] = __builtin_amdgcn_mfma_f32_16x16x32_bf16(af[mi], bf[ni], acc[mi][ni], 0, 0, 0);
    __builtin_amdgcn_s_setprio(0);
    if (stg) { asm volatile("s_waitcnt vmcnt(4)" ::: "memory"); }
    else if (ti + 1 < NT) { asm volatile("s_waitcnt vmcnt(0)" ::: "memory"); }
    __builtin_amdgcn_s_barrier();
    sl = (sl == 2) ? 0 : sl + 1;
    st = (st == 2) ? 0 : st + 1;
  }
#undef SAt
#undef SBt

  int er = wr * 64 + (lane >> 4) * 4;
  int ec = wc * 64 + fr;
#pragma unroll
  for (int mi = 0; mi < 4; ++mi) {
#pragma unroll
    for (int ni = 0; ni < 4; ++ni) {
      int col = (int)n0 + ec + ni * 16;
      float bs = bias[col];
#pragma unroll
      for (int j = 0; j < 4; ++j) {
        size_t row = m0 + er + mi * 16 + j;
        size_t cidx = row * (size_t)Cstride + col;
        float x = acc[mi][ni][j] + bs;
        if constexpr (MODE == 0) {
          ((__hip_bfloat16*)Cout)[cidx] = __float2bfloat16(x);
        } else {
          ((float*)Cout)[cidx] += x;
        }
      }
    }
  }
}

// ============ gemmGW: fused gated ff1, 4 waves (2Mx2N), per-wave 64x64 of
// BOTH gated outputs. BM=128, BN=128 dual, BK=32, 3-slot ring 72KB, 2 blk/CU.
__global__ __launch_bounds__(256, 2) void gemmGW_kernel(
    const ushort_t* __restrict__ A,
    const ushort_t* __restrict__ Wt,
    const float* __restrict__ bias,
    __hip_bfloat16* __restrict__ Cout,
    int K, int Mtiles, int Cstride, int NhRows, int Ntiles, int XN) {
  __shared__ ushort_t Alds[3][4096];   // 3 x 128 x 32
  __shared__ ushort_t B1lds[3][4096];
  __shared__ ushort_t B2lds[3][4096];
  int t = threadIdx.x;
  int w = t >> 6, lane = t & 63;
  int wr = w >> 1, wc = w & 1;
  int fr = lane & 15, kg = lane >> 4;

  int mt, nt;
  xcd_map(blockIdx.x, Mtiles, Ntiles, XN, mt, nt);
  size_t m0 = (size_t)mt * 128, n0 = (size_t)nt * 128;

  int stg_r = w * 16 + (lane >> 2);
  int stg_c = (((lane & 3) ^ ((lane >> 3) & 3)) << 3);
  const ushort_t* gAl = A + (m0 + stg_r) * (size_t)K + stg_c;
  const ushort_t* gB1 = Wt + (n0 + stg_r) * (size_t)K + stg_c;
  const ushort_t* gB2 = Wt + ((size_t)NhRows + n0 + stg_r) * (size_t)K + stg_c;
  int lds_w = w * 512;

#define SAg(slot, kcol, j) GLD16(gAl + (size_t)(j) * 64 * K + (kcol), Alds[slot] + (j) * 2048 + lds_w)
#define SB1g(slot, kcol, j) GLD16(gB1 + (size_t)(j) * 64 * K + (kcol), B1lds[slot] + (j) * 2048 + lds_w)
#define SB2g(slot, kcol, j) GLD16(gB2 + (size_t)(j) * 64 * K + (kcol), B2lds[slot] + (j) * 2048 + lds_w)

  f32x4 acc1[4][4], acc2[4][4];
#pragma unroll
  for (int i = 0; i < 4; ++i)
#pragma unroll
    for (int j = 0; j < 4; ++j) {
      acc1[i][j] = (f32x4){0.f, 0.f, 0.f, 0.f};
      acc2[i][j] = (f32x4){0.f, 0.f, 0.f, 0.f};
    }

  int usw = ((kg ^ ((fr >> 1) & 3)) << 3);

  SAg(0, 0, 0); SAg(0, 0, 1); SB1g(0, 0, 0); SB1g(0, 0, 1); SB2g(0, 0, 0); SB2g(0, 0, 1);
  SAg(1, 32, 0); SAg(1, 32, 1); SB1g(1, 32, 0); SB1g(1, 32, 1); SB2g(1, 32, 0); SB2g(1, 32, 1);
  asm volatile("s_waitcnt vmcnt(6)" ::: "memory");
  __builtin_amdgcn_s_barrier();

  short8v af[4], bf1[4], bf2[4];
  int NT = K >> 5;
  int sl = 0, st = 2;
  for (int ti = 0; ti < NT; ++ti) {
    int kS = (ti + 2) << 5;
    int stg = (ti + 2) < NT;
    const ushort_t* sA = Alds[sl];
    const ushort_t* sB1 = B1lds[sl];
    const ushort_t* sB2 = B2lds[sl];
#pragma unroll
    for (int mi = 0; mi < 4; ++mi)
      af[mi] = *(const short8v*)(sA + (wr * 64 + mi * 16 + fr) * 32 + usw);
#pragma unroll
    for (int ni = 0; ni < 4; ++ni) {
      bf1[ni] = *(const short8v*)(sB1 + (wc * 64 + ni * 16 + fr) * 32 + usw);
      bf2[ni] = *(const short8v*)(sB2 + (wc * 64 + ni * 16 + fr) * 32 + usw);
    }
    if (stg) {
      SAg(st, kS, 0); SAg(st, kS, 1);
      SB1g(st, kS, 0); SB1g(st, kS, 1);
      SB2g(st, kS, 0); SB2g(st, kS, 1);
    }
    asm volatile("s_waitcnt lgkmcnt(0)" ::: "memory");
    __builtin_amdgcn_sched_barrier(0);
    __builtin_amdgcn_s_setprio(1);
#pragma unroll
    for (int mi = 0; mi < 4; ++mi)
#pragma unroll
      for (int ni = 0; ni < 4; ++ni) {
        acc1[mi][ni] = __builtin_amdgcn_mfma_f32_16x16x32_bf16(af[mi], bf1[ni], acc1[mi][ni], 0, 0, 0);
        acc2[mi][ni] = __builtin_amdgcn_mfma_f32_16x16x32_bf16(af[mi], bf2[ni], acc2[mi][ni], 0, 0, 0);
      }
    __builtin_amdgcn_s_setprio(0);
    if (stg) { asm volatile("s_waitcnt vmcnt(6)" ::: "memory"); }
    else if (ti + 1 < NT) { asm volatile("s_waitcnt vmcnt(0)" ::: "memory"); }
    __builtin_amdgcn_s_barrier();
    sl = (sl == 2) ? 0 : sl + 1;
    st = (st == 2) ? 0 : st + 1;
  }
#undef SAg
#undef SB1g
#undef SB2g

  int er = wr * 64 + (lane >> 4) * 4;
  int ec = wc * 64 + fr;
#pragma unroll
  for (int mi = 0; mi < 4; ++mi) {
#pragma unroll
    for (int ni = 0; ni < 4; ++ni) {
      int col = (int)n0 + ec + ni * 16;
      float b1v = bias[col];
      float b2v = bias[NhRows + col];
#pragma unroll
      for (int j = 0; j < 4; ++j) {
        size_t row = m0 + er + mi * 16 + j;
        float x1 = acc1[mi][ni][j] + b1v;
        float x2 = acc2[mi][ni][j] + b2v;
        float sg = x1 / (1.f + expf(-x1));
        Cout[row * (size_t)Cstride + col] = __float2bfloat16(sg * x2);
      }
    }
  }
}

// ---------------- small 128x128 GEMM (final head only) ----------------
template <int MODE>
__global__ __launch_bounds__(256) void mgemm_kernel(
    const __hip_bfloat16* __restrict__ A,
    const __hip_bfloat16* __restrict__ Wt,
    const float* __restrict__ bias,
    void* __restrict__ Cout,
    int K, int Nh, int Cstride) {
  __shared__ ushort_t As[4 * 128 * 8];
  __shared__ ushort_t Bs[4 * 128 * 8];
  __shared__ ushort_t Bs2[(MODE == 2) ? 4 * 128 * 8 : 8];
  int t = threadIdx.x;
  int w = t >> 6, lane = t & 63;
  int wr = w >> 1, wc = w & 1;
  size_t m0 = (size_t)blockIdx.y * 128;
  size_t n0 = (size_t)blockIdx.x * 128;
  int cell0 = w * 64 + lane;
  int cell1 = 256 + w * 64 + lane;
  int kg0 = cell0 >> 7, rw0 = cell0 & 127;
  int kg1 = cell1 >> 7, rw1 = cell1 & 127;
  const ushort_t* gA = (const ushort_t*)A;
  const ushort_t* gB = (const ushort_t*)Wt;
  const ushort_t* gB2 = (const ushort_t*)(Wt + (size_t)Nh * K);
  size_t a0 = (m0 + rw0) * (size_t)K + kg0 * 8;
  size_t a1 = (m0 + rw1) * (size_t)K + kg1 * 8;
  size_t b0 = (n0 + rw0) * (size_t)K + kg0 * 8;
  size_t b1 = (n0 + rw1) * (size_t)K + kg1 * 8;
  int ldso0 = w * 1024;
  int ldso1 = 4096 + w * 1024;
  f32x4 acc[4][4];
  f32x4 acc2[4][4];
#pragma unroll
  for (int i = 0; i < 4; ++i)
#pragma unroll
    for (int j = 0; j < 4; ++j) {
      acc[i][j] = (f32x4){0.f, 0.f, 0.f, 0.f};
      acc2[i][j] = (f32x4){0.f, 0.f, 0.f, 0.f};
    }
  int fr = lane & 15, kg = lane >> 4;
  int abase = (kg * 128 + wr * 64 + fr) * 16;
  int bbase = (kg * 128 + wc * 64 + fr) * 16;
  for (int k0 = 0; k0 < K; k0 += 32) {
    __syncthreads();
    GLD16(gA + a0 + k0, (char*)As + ldso0);
    GLD16(gA + a1 + k0, (char*)As + ldso1);
    GLD16(gB + b0 + k0, (char*)Bs + ldso0);
    GLD16(gB + b1 + k0, (char*)Bs + ldso1);
    if constexpr (MODE == 2) {
      GLD16(gB2 + b0 + k0, (char*)Bs2 + ldso0);
      GLD16(gB2 + b1 + k0, (char*)Bs2 + ldso1);
    }
    __syncthreads();
    short8v a[4], b[4];
#pragma unroll
    for (int mi = 0; mi < 4; ++mi)
      a[mi] = *(const short8v*)((const char*)As + abase + mi * 256);
#pragma unroll
    for (int ni = 0; ni < 4; ++ni)
      b[ni] = *(const short8v*)((const char*)Bs + bbase + ni * 256);
#pragma unroll
    for (int mi = 0; mi < 4; ++mi)
#pragma unroll
      for (int ni = 0; ni < 4; ++ni)
        acc[mi][ni] = __builtin_amdgcn_mfma_f32_16x16x32_bf16(a[mi], b[ni], acc[mi][ni], 0, 0, 0);
    if constexpr (MODE == 2) {
#pragma unroll
      for (int ni = 0; ni < 4; ++ni)
        b[ni] = *(const short8v*)((const char*)Bs2 + bbase + ni * 256);
#pragma unroll
      for (int mi = 0; mi < 4; ++mi)
#pragma unroll
        for (int ni = 0; ni < 4; ++ni)
          acc2[mi][ni] = __builtin_amdgcn_mfma_f32_16x16x32_bf16(a[mi], b[ni], acc2[mi][ni], 0, 0, 0);
    }
  }
  int er = wr * 64 + (lane >> 4) * 4;
  int ec = wc * 64 + fr;
#pragma unroll
  for (int mi = 0; mi < 4; ++mi) {
#pragma unroll
    for (int ni = 0; ni < 4; ++ni) {
      int col = (int)n0 + ec + ni * 16;
      float bs1 = bias[col];
#pragma unroll
      for (int j = 0; j < 4; ++j) {
        size_t row = m0 + er + mi * 16 + j;
        size_t cidx = row * (size_t)Cstride + col;
        float x = acc[mi][ni][j] + bs1;
        if constexpr (MODE == 3) {
          ((float*)Cout)[cidx] = x;
        } else {
          float x2 = acc2[mi][ni][j] + bias[Nh + col];
          float sig = 1.f / (1.f + expf(-x));
          ((__hip_bfloat16*)Cout)[cidx] = __float2bfloat16(x * sig * x2);
        }
      }
    }
  }
}

// ---------------- attention: 4 heads per block (HSPLIT=4) ----------------
__global__ __launch_bounds__(256) void attn_kernel(const __hip_bfloat16* __restrict__ qkv,
                                                   const float* __restrict__ dist,
                                                   const float* __restrict__ ds_l,
                                                   __hip_bfloat16* __restrict__ o) {
  int nq = blockIdx.x >> 2;
  int h0 = (blockIdx.x & 3) * (NHEAD / HSPLIT);
  int t = threadIdx.x;
  __shared__ float qs[16][65], ks[16][65], vs[16][65];
  __shared__ float sc[16][17], dl[16][17];
  __shared__ float sps_s[NHEAD];
  dl[t >> 4][t & 15] = dist[(size_t)nq * 256 + t];
  if (t < NHEAD) sps_s[t] = log1pf(expf(ds_l[t]));
  size_t base = (size_t)nq * 16 * 3072;
  int e = t >> 4, c4 = (t & 15) * 4;
  const ushort_t* qp = (const ushort_t*)qkv;
  for (int h = h0; h < h0 + NHEAD / HSPLIT; ++h) {
    const ushort_t* p = qp + base + (size_t)e * 3072 + h * 64 + c4;
    ushort4 qv = *(const ushort4*)p;
    ushort4 kv = *(const ushort4*)(p + 1024);
    ushort4 vv = *(const ushort4*)(p + 2048);
    qs[e][c4] = b2f(qv.x); qs[e][c4 + 1] = b2f(qv.y); qs[e][c4 + 2] = b2f(qv.z); qs[e][c4 + 3] = b2f(qv.w);
    ks[e][c4] = b2f(kv.x); ks[e][c4 + 1] = b2f(kv.y); ks[e][c4 + 2] = b2f(kv.z); ks[e][c4 + 3] = b2f(kv.w);
    vs[e][c4] = b2f(vv.x); vs[e][c4 + 1] = b2f(vv.y); vs[e][c4 + 2] = b2f(vv.z); vs[e][c4 + 3] = b2f(vv.w);
    __syncthreads();
    int ee = t >> 4, ff = t & 15;
    float s = 0.f;
#pragma unroll
    for (int d = 0; d < 64; ++d) s = fmaf(qs[ee][d], ks[ff][d], s);
    sc[ee][ff] = s * 0.125f - sps_s[h] * dl[ee][ff];
    __syncthreads();
    if (t < 16) {
      float m = -1e30f;
      for (int f = 0; f < 16; ++f) m = fmaxf(m, sc[t][f]);
      float sum = 0.f;
      for (int f = 0; f < 16; ++f) { float pe = expf(sc[t][f] - m); sc[t][f] = pe; sum += pe; }
      float inv = 1.f / sum;
      for (int f = 0; f < 16; ++f) sc[t][f] *= inv;
    }
    __syncthreads();
#pragma unroll
    for (int r = 0; r < 4; ++r) {
      int idx = t + 256 * r;
      int oe = idx >> 6, od = idx & 63;
      float acc = 0.f;
#pragma unroll
      for (int f = 0; f < 16; ++f) acc = fmaf(sc[oe][f], vs[f][od], acc);
      o[(size_t)(nq * 16 + oe) * 1024 + h * 64 + od] = __float2bfloat16(acc);
    }
    __syncthreads();
  }
}

// ---------------- final VAE head elementwise ----------------
__global__ __launch_bounds__(64) void final_kernel(const float* __restrict__ tmp,
                                                   const float* __restrict__ eps,
                                                   float* __restrict__ out) {
  int r = blockIdx.x; int j = threadIdx.x;
  float mu = tmp[r * 128 + j];
  float lv = fminf(tmp[r * 128 + 64 + j], 5.0f);
  float zs = mu + eps[r * 64 + j] * expf(0.5f * lv);
  out[r * 64 + j] = zs;
  out[262144 + r * 64 + j] = mu;
  out[524288 + r * 64 + j] = lv;
}

extern "C" void kernel_launch(void* const* d_in, const int* in_sizes, int n_in,
                              void* d_out, int out_size, void* d_ws, size_t ws_size,
                              hipStream_t stream) {
  (void)in_sizes; (void)n_in; (void)out_size;
  const float* coords = (const float*)d_in[0];
  const float* eps    = (const float*)d_in[1];
  const float* emb    = (const float*)d_in[2];
  const float* ln1_g  = (const float*)d_in[3];
  const float* ln1_b  = (const float*)d_in[4];
  const float* Wqkv   = (const float*)d_in[5];
  const float* bqkv   = (const float*)d_in[6];
  const float* dist_scale = (const float*)d_in[7];
  const float* Wo     = (const float*)d_in[8];
  const float* bo     = (const float*)d_in[9];
  const float* ln2_g  = (const float*)d_in[10];
  const float* ln2_b  = (const float*)d_in[11];
  const float* Wf1    = (const float*)d_in[12];
  const float* bf1    = (const float*)d_in[13];
  const float* Wf2    = (const float*)d_in[14];
  const float* bf2    = (const float*)d_in[15];
  const float* lnf_g  = (const float*)d_in[16];
  const float* lnf_b  = (const float*)d_in[17];
  const float* We1    = (const float*)d_in[18];
  const float* be1    = (const float*)d_in[19];
  const float* We2    = (const float*)d_in[20];
  const float* be2    = (const float*)d_in[21];

  char* ws = (char*)d_ws;
  int*   edges = (int*)ws;                                        // 256 KB
  float* dist  = (float*)(ws + (4ull << 20));                     // 4 MB
  __hip_bfloat16* hfinal = (__hip_bfloat16*)(ws + (8ull << 20));  // 8 MB
  __hip_bfloat16* gated  = (__hip_bfloat16*)(ws + (16ull << 20)); // 4 MB
  float* tmp   = (float*)(ws + (20ull << 20));                    // 2 MB
  __hip_bfloat16* wbase = (__hip_bfloat16*)(ws + (24ull << 20));  // ~69.3 MB
  size_t woff = 0;
  __hip_bfloat16* wqkvT = wbase + woff; woff += 2ull * 3072 * 1024;
  __hip_bfloat16* woT   = wbase + woff; woff += 2ull * 1024 * 1024;
  __hip_bfloat16* wf1T  = wbase + woff; woff += 2ull * 8192 * 1024;
  __hip_bfloat16* wf2T  = wbase + woff; woff += 2ull * 1024 * 4096;
  __hip_bfloat16* we1T  = wbase + woff; woff += 1024ull * 1024;
  __hip_bfloat16* we2T  = wbase + woff; woff += 128ull * 512;

  const size_t FIXED = 96ull << 20;
  int CQ = 4096;
  while (CQ > 256 && FIXED + (size_t)CQ * 16 * 14336ull > ws_size) CQ >>= 1;
  if (FIXED + (size_t)CQ * 16 * 14336ull > ws_size) return;  // ws too small: leave poison
  size_t CT = (size_t)CQ * KNNK;
  char* creg = ws + FIXED;
  float* zbuf = (float*)creg;                                    // CT x 1024 fp32
  __hip_bfloat16* hbuf = (__hip_bfloat16*)(creg + CT * 4096);    // CT x 1024 bf16 (h / attn-out)
  __hip_bfloat16* sh8  = (__hip_bfloat16*)(creg + CT * 6144);    // CT x 4096 bf16 (qkv / gated)

  knn_kernel<<<NQ, 64, 0, stream>>>(coords, edges);
  dist_kernel<<<NQ, 256, 0, stream>>>(coords, edges, dist);
  for (int l = 0; l < NLAYER; ++l) {
    wconv_kernel<<<dim3(96, 32), 256, 0, stream>>>(Wqkv + (size_t)l * 1024 * 3072,
                                                   wqkvT + (size_t)l * 3072 * 1024, 1024, 3072);
    wconv_kernel<<<dim3(32, 32), 256, 0, stream>>>(Wo + (size_t)l * 1024 * 1024,
                                                   woT + (size_t)l * 1024 * 1024, 1024, 1024);
    wconv_kernel<<<dim3(256, 32), 256, 0, stream>>>(Wf1 + (size_t)l * 1024 * 8192,
                                                    wf1T + (size_t)l * 8192 * 1024, 1024, 8192);
    wconv_kernel<<<dim3(32, 128), 256, 0, stream>>>(Wf2 + (size_t)l * 4096 * 1024,
                                                    wf2T + (size_t)l * 1024 * 4096, 4096, 1024);
  }
  wconv_kernel<<<dim3(32, 32), 256, 0, stream>>>(We1, we1T, 1024, 1024);
  wconv_kernel<<<dim3(4, 16), 256, 0, stream>>>(We2, we2T, 512, 128);

  int NCH = NQ / CQ;
  int MT128 = (int)(CT / 128);
  for (int c = 0; c < NCH; ++c) {
    zinit_kernel<<<(int)CT, 256, 0, stream>>>(edges, emb, zbuf, (int)(c * CT));
    for (int l = 0; l < NLAYER; ++l) {
      ln_kernel<<<(int)CT, 256, 0, stream>>>(zbuf, DIM, ln1_g + l * DIM, ln1_b + l * DIM, hbuf);
      gemmT128_kernel<0><<<MT128 * 24, 256, 0, stream>>>(
          (const ushort_t*)hbuf, (const ushort_t*)(wqkvT + (size_t)l * 3072 * 1024),
          bqkv + l * 3072, sh8, 1024, MT128, 3072, 24, 4);
      attn_kernel<<<CQ * HSPLIT, 256, 0, stream>>>(sh8, dist + (size_t)c * CQ * 256,
                                                   dist_scale + l * NHEAD, hbuf);
      gemmT128_kernel<1><<<MT128 * 8, 256, 0, stream>>>(
          (const ushort_t*)hbuf, (const ushort_t*)(woT + (size_t)l * 1024 * 1024),
          bo + l * DIM, zbuf, 1024, MT128, 1024, 8, 2);
      ln_kernel<<<(int)CT, 256, 0, stream>>>(zbuf, DIM, ln2_g + l * DIM, ln2_b + l * DIM, hbuf);
      gemmGW_kernel<<<MT128 * 32, 256, 0, stream>>>(
          (const ushort_t*)hbuf, (const ushort_t*)(wf1T + (size_t)l * 8192 * 1024),
          bf1 + l * 2 * DFFN, sh8, 1024, MT128, 4096, 4096, 32, 4);
      gemmT128_kernel<1><<<MT128 * 8, 256, 0, stream>>>(
          (const ushort_t*)sh8, (const ushort_t*)(wf2T + (size_t)l * 1024 * 4096),
          bf2 + l * DIM, zbuf, 4096, MT128, 1024, 8, 2);
    }
    ln_kernel<<<CQ, 256, 0, stream>>>(zbuf, KNNK * DIM, lnf_g, lnf_b,
                                      hfinal + (size_t)c * CQ * DIM);
  }

  mgemm_kernel<2><<<dim3(4, 32), 256, 0, stream>>>(hfinal, we1T, be1, gated, 1024, 512, 512);
  mgemm_kernel<3><<<dim3(1, 32), 256, 0, stream>>>(gated, we2T, be2, tmp, 512, 0, 128);
  final_kernel<<<NQ, 64, 0, stream>>>(tmp, eps, (float*)d_out);
}

// Round 12
// 4065.415 us; speedup vs baseline: 1.6054x; 1.5635x over previous
//
#include <hip/hip_runtime.h>
#include <hip/hip_bf16.h>
#include <math.h>

#define LLEN 512
#define KNNK 16
#define DIM 1024
#define NHEAD 16
#define NLAYER 2
#define DFFN 4096
#define POSCLIP 32
#define NQ 4096
#define NTOK 65536
#define HSPLIT 4

typedef __attribute__((ext_vector_type(8))) short short8v;
typedef __attribute__((ext_vector_type(4))) float f32x4;
typedef unsigned short ushort_t;

__device__ __forceinline__ float b2f(ushort_t u) {
  union { unsigned u; float f; } x; x.u = ((unsigned)u) << 16; return x.f;
}

// 2D XCD-blocked tile mapping: B-slice L2-resident, A fetched ~once/XCD.
__device__ __forceinline__ void xcd_map(int bid, int Mtiles, int Ntiles, int XN,
                                        int& mt, int& nt) {
  int nt_per = Ntiles / XN;
  int mt_per = (Mtiles * XN) >> 3;
  int xcd = bid & 7, i = bid >> 3;
  int xn = xcd % XN, xm = xcd / XN;
  int ntl = i % nt_per, mtl = i / nt_per;
  mt = xm * mt_per + mtl;
  nt = xn * nt_per + ntl;
}

#define GLD16(gp, lp)                                                          \
  __builtin_amdgcn_global_load_lds(                                            \
      (const __attribute__((address_space(1))) void*)(gp),                     \
      (__attribute__((address_space(3))) void*)(lp), 16, 0, 0)

// ---------------- KNN: one wave per query ----------------
__global__ __launch_bounds__(64) void knn_kernel(const float* __restrict__ coords,
                                                 int* __restrict__ edges) {
  int n = blockIdx.x;
  int b = n / LLEN, i = n % LLEN;
  int lane = threadIdx.x;
  const float* cb = coords + (size_t)b * LLEN * 9;
  float xi = cb[i * 9 + 3], yi = cb[i * 9 + 4], zi = cb[i * 9 + 5];
  float d[8];
#pragma unroll
  for (int r = 0; r < 8; ++r) {
    int j = r * 64 + lane;
    float dx = xi - cb[j * 9 + 3];
    float dy = yi - cb[j * 9 + 4];
    float dz = zi - cb[j * 9 + 5];
    d[r] = dx * dx + dy * dy + dz * dz;
  }
  for (int s = 0; s < KNNK; ++s) {
    float bv = INFINITY; int bi = 1 << 30;
#pragma unroll
    for (int r = 0; r < 8; ++r) {
      int j = r * 64 + lane;
      if (d[r] < bv || (d[r] == bv && j < bi)) { bv = d[r]; bi = j; }
    }
#pragma unroll
    for (int off = 32; off > 0; off >>= 1) {
      float ov = __shfl_xor(bv, off);
      int   oi = __shfl_xor(bi, off);
      if (ov < bv || (ov == bv && oi < bi)) { bv = ov; bi = oi; }
    }
    if (lane == 0) edges[n * KNNK + s] = bi;
    if ((bi & 63) == lane) d[bi >> 6] = INFINITY;
  }
}

// ---------------- dist: 16x16 per query ----------------
__global__ __launch_bounds__(256) void dist_kernel(const float* __restrict__ coords,
                                                   const int* __restrict__ edges,
                                                   float* __restrict__ dist) {
  int n = blockIdx.x; int b = n / LLEN;
  __shared__ float tx[16], ty[16], tz[16];
  int t = threadIdx.x;
  const float* cb = coords + (size_t)b * LLEN * 9;
  if (t < 16) {
    int j = edges[n * KNNK + t];
    tx[t] = cb[j * 9 + 3]; ty[t] = cb[j * 9 + 4]; tz[t] = cb[j * 9 + 5];
  }
  __syncthreads();
  int e = t >> 4, f = t & 15;
  float dx = tx[e] - tx[f], dy = ty[e] - ty[f], dz = tz[e] - tz[f];
  dist[(size_t)n * 256 + t] = sqrtf(dx * dx + dy * dy + dz * dz + 1e-8f);
}

// ---------------- z init (chunked) ----------------
__global__ __launch_bounds__(256) void zinit_kernel(const int* __restrict__ edges,
                                                    const float* __restrict__ emb,
                                                    float* __restrict__ zbuf, int tok0) {
  int tl = blockIdx.x;
  int tok = tok0 + tl;
  int n = tok >> 4;
  int diff = edges[tok] - edges[n << 4];
  int idx = min(max(diff, -POSCLIP), POSCLIP) + POSCLIP;
  ((float4*)(zbuf + (size_t)tl * DIM))[threadIdx.x] =
      ((const float4*)(emb + (size_t)idx * DIM))[threadIdx.x];
}

// ---------------- LayerNorm fp32 in -> bf16 out ----------------
__global__ __launch_bounds__(256) void ln_kernel(const float* __restrict__ X, int stride,
                                                 const float* __restrict__ g,
                                                 const float* __restrict__ bta,
                                                 __hip_bfloat16* __restrict__ Y) {
  int row = blockIdx.x; int t = threadIdx.x;
  const float4* xr = (const float4*)(X + (size_t)row * stride);
  float4 v = xr[t];
  float s = v.x + v.y + v.z + v.w;
  __shared__ float red[8];
  for (int off = 32; off; off >>= 1) s += __shfl_down(s, off);
  int wid = t >> 6;
  if ((t & 63) == 0) red[wid] = s;
  __syncthreads();
  if (t == 0) red[4] = (red[0] + red[1] + red[2] + red[3]) * (1.0f / DIM);
  __syncthreads();
  float mean = red[4];
  float d0 = v.x - mean, d1 = v.y - mean, d2 = v.z - mean, d3 = v.w - mean;
  float s2 = d0 * d0 + d1 * d1 + d2 * d2 + d3 * d3;
  for (int off = 32; off; off >>= 1) s2 += __shfl_down(s2, off);
  if ((t & 63) == 0) red[wid] = s2;
  __syncthreads();
  if (t == 0) red[5] = rsqrtf((red[0] + red[1] + red[2] + red[3]) * (1.0f / DIM) + 1e-5f);
  __syncthreads();
  float rstd = red[5];
  float4 gv = ((const float4*)g)[t], bv = ((const float4*)bta)[t];
  size_t o = (size_t)row * DIM + t * 4;
  Y[o + 0] = __float2bfloat16(d0 * rstd * gv.x + bv.x);
  Y[o + 1] = __float2bfloat16(d1 * rstd * gv.y + bv.y);
  Y[o + 2] = __float2bfloat16(d2 * rstd * gv.z + bv.z);
  Y[o + 3] = __float2bfloat16(d3 * rstd * gv.w + bv.w);
}

// ---------------- weight fp32 K x N -> bf16 N x K ----------------
__global__ __launch_bounds__(256) void wconv_kernel(const float* __restrict__ W,
                                                    __hip_bfloat16* __restrict__ Wt,
                                                    int K, int N) {
  __shared__ float tile[32][33];
  int n0 = blockIdx.x * 32, k0 = blockIdx.y * 32;
  int c = threadIdx.x & 31, r = threadIdx.x >> 5;
#pragma unroll
  for (int i = 0; i < 4; ++i)
    tile[r + i * 8][c] = W[(size_t)(k0 + r + i * 8) * N + n0 + c];
  __syncthreads();
#pragma unroll
  for (int i = 0; i < 4; ++i)
    Wt[(size_t)(n0 + r + i * 8) * K + k0 + c] = __float2bfloat16(tile[c][r + i * 8]);
}

// BK=32 swizzle: LDS chunk c holds global k-chunk c ^ ((row>>1)&3);
// reads use kg ^ ((fr>>1)&3). <=2-way (free).

// ============ gemmT128: BM=128, BN=128, BK=32, 256 thr (4 waves 2x2),
// 3-slot ring (48KB LDS). MODE 0: bf16 C = x  MODE 1: fp32 C += x
template <int MODE>
__global__ __launch_bounds__(256, 3) void gemmT128_kernel(
    const ushort_t* __restrict__ A,
    const ushort_t* __restrict__ Wt,
    const float* __restrict__ bias,
    void* __restrict__ Cout,
    int K, int Mtiles, int Cstride, int Ntiles, int XN) {
  __shared__ ushort_t Alds[3][4096];
  __shared__ ushort_t Blds[3][4096];
  int t = threadIdx.x;
  int w = t >> 6, lane = t & 63;
  int wr = w >> 1, wc = w & 1;
  int fr = lane & 15, kg = lane >> 4;

  int mt, nt;
  xcd_map(blockIdx.x, Mtiles, Ntiles, XN, mt, nt);
  size_t m0 = (size_t)mt * 128, n0 = (size_t)nt * 128;

  int stg_r = w * 16 + (lane >> 2);
  int stg_c = (((lane & 3) ^ ((lane >> 3) & 3)) << 3);
  const ushort_t* gAl = A + (m0 + stg_r) * (size_t)K + stg_c;
  const ushort_t* gBl = Wt + (n0 + stg_r) * (size_t)K + stg_c;
  int lds_w = w * 512;

#define SAt(slot, kcol, j) GLD16(gAl + (size_t)(j) * 64 * K + (kcol), Alds[slot] + (j) * 2048 + lds_w)
#define SBt(slot, kcol, j) GLD16(gBl + (size_t)(j) * 64 * K + (kcol), Blds[slot] + (j) * 2048 + lds_w)

  f32x4 acc[4][4];
#pragma unroll
  for (int i = 0; i < 4; ++i)
#pragma unroll
    for (int j = 0; j < 4; ++j) acc[i][j] = (f32x4){0.f, 0.f, 0.f, 0.f};

  int usw = ((kg ^ ((fr >> 1) & 3)) << 3);

  SAt(0, 0, 0); SAt(0, 0, 1); SBt(0, 0, 0); SBt(0, 0, 1);
  SAt(1, 32, 0); SAt(1, 32, 1); SBt(1, 32, 0); SBt(1, 32, 1);
  asm volatile("s_waitcnt vmcnt(4)" ::: "memory");
  __builtin_amdgcn_s_barrier();

  short8v af[4], bf[4];
  int NT = K >> 5;
  int sl = 0, st = 2;
  for (int ti = 0; ti < NT; ++ti) {
    int kS = (ti + 2) << 5;
    int stg = (ti + 2) < NT;
    const ushort_t* sA = Alds[sl];
    const ushort_t* sB = Blds[sl];
#pragma unroll
    for (int mi = 0; mi < 4; ++mi)
      af[mi] = *(const short8v*)(sA + (wr * 64 + mi * 16 + fr) * 32 + usw);
#pragma unroll
    for (int ni = 0; ni < 4; ++ni)
      bf[ni] = *(const short8v*)(sB + (wc * 64 + ni * 16 + fr) * 32 + usw);
    if (stg) { SAt(st, kS, 0); SAt(st, kS, 1); SBt(st, kS, 0); SBt(st, kS, 1); }
    asm volatile("s_waitcnt lgkmcnt(0)" ::: "memory");
    __builtin_amdgcn_sched_barrier(0);
    __builtin_amdgcn_s_setprio(1);
#pragma unroll
    for (int mi = 0; mi < 4; ++mi)
#pragma unroll
      for (int ni = 0; ni < 4; ++ni)
        acc[mi][ni] = __builtin_amdgcn_mfma_f32_16x16x32_bf16(af[mi], bf[ni], acc[mi][ni], 0, 0, 0);
    __builtin_amdgcn_s_setprio(0);
    if (stg) { asm volatile("s_waitcnt vmcnt(4)" ::: "memory"); }
    else if (ti + 1 < NT) { asm volatile("s_waitcnt vmcnt(0)" ::: "memory"); }
    __builtin_amdgcn_s_barrier();
    sl = (sl == 2) ? 0 : sl + 1;
    st = (st == 2) ? 0 : st + 1;
  }
#undef SAt
#undef SBt

  int er = wr * 64 + (lane >> 4) * 4;
  int ec = wc * 64 + fr;
#pragma unroll
  for (int mi = 0; mi < 4; ++mi) {
#pragma unroll
    for (int ni = 0; ni < 4; ++ni) {
      int col = (int)n0 + ec + ni * 16;
      float bs = bias[col];
#pragma unroll
      for (int j = 0; j < 4; ++j) {
        size_t row = m0 + er + mi * 16 + j;
        size_t cidx = row * (size_t)Cstride + col;
        float x = acc[mi][ni][j] + bs;
        if constexpr (MODE == 0) {
          ((__hip_bfloat16*)Cout)[cidx] = __float2bfloat16(x);
        } else {
          ((float*)Cout)[cidx] += x;
        }
      }
    }
  }
}

// ============ gemmGW: fused gated ff1, 4 waves (2Mx2N), per-wave 64x64 of
// BOTH gated outputs. BM=128, BN=128 dual, BK=32, 3-slot ring 72KB, 2 blk/CU.
__global__ __launch_bounds__(256, 2) void gemmGW_kernel(
    const ushort_t* __restrict__ A,
    const ushort_t* __restrict__ Wt,
    const float* __restrict__ bias,
    __hip_bfloat16* __restrict__ Cout,
    int K, int Mtiles, int Cstride, int NhRows, int Ntiles, int XN) {
  __shared__ ushort_t Alds[3][4096];
  __shared__ ushort_t B1lds[3][4096];
  __shared__ ushort_t B2lds[3][4096];
  int t = threadIdx.x;
  int w = t >> 6, lane = t & 63;
  int wr = w >> 1, wc = w & 1;
  int fr = lane & 15, kg = lane >> 4;

  int mt, nt;
  xcd_map(blockIdx.x, Mtiles, Ntiles, XN, mt, nt);
  size_t m0 = (size_t)mt * 128, n0 = (size_t)nt * 128;

  int stg_r = w * 16 + (lane >> 2);
  int stg_c = (((lane & 3) ^ ((lane >> 3) & 3)) << 3);
  const ushort_t* gAl = A + (m0 + stg_r) * (size_t)K + stg_c;
  const ushort_t* gB1 = Wt + (n0 + stg_r) * (size_t)K + stg_c;
  const ushort_t* gB2 = Wt + ((size_t)NhRows + n0 + stg_r) * (size_t)K + stg_c;
  int lds_w = w * 512;

#define SAg(slot, kcol, j) GLD16(gAl + (size_t)(j) * 64 * K + (kcol), Alds[slot] + (j) * 2048 + lds_w)
#define SB1g(slot, kcol, j) GLD16(gB1 + (size_t)(j) * 64 * K + (kcol), B1lds[slot] + (j) * 2048 + lds_w)
#define SB2g(slot, kcol, j) GLD16(gB2 + (size_t)(j) * 64 * K + (kcol), B2lds[slot] + (j) * 2048 + lds_w)

  f32x4 acc1[4][4], acc2[4][4];
#pragma unroll
  for (int i = 0; i < 4; ++i)
#pragma unroll
    for (int j = 0; j < 4; ++j) {
      acc1[i][j] = (f32x4){0.f, 0.f, 0.f, 0.f};
      acc2[i][j] = (f32x4){0.f, 0.f, 0.f, 0.f};
    }

  int usw = ((kg ^ ((fr >> 1) & 3)) << 3);

  SAg(0, 0, 0); SAg(0, 0, 1); SB1g(0, 0, 0); SB1g(0, 0, 1); SB2g(0, 0, 0); SB2g(0, 0, 1);
  SAg(1, 32, 0); SAg(1, 32, 1); SB1g(1, 32, 0); SB1g(1, 32, 1); SB2g(1, 32, 0); SB2g(1, 32, 1);
  asm volatile("s_waitcnt vmcnt(6)" ::: "memory");
  __builtin_amdgcn_s_barrier();

  short8v af[4], bf1[4], bf2[4];
  int NT = K >> 5;
  int sl = 0, st = 2;
  for (int ti = 0; ti < NT; ++ti) {
    int kS = (ti + 2) << 5;
    int stg = (ti + 2) < NT;
    const ushort_t* sA = Alds[sl];
    const ushort_t* sB1 = B1lds[sl];
    const ushort_t* sB2 = B2lds[sl];
#pragma unroll
    for (int mi = 0; mi < 4; ++mi)
      af[mi] = *(const short8v*)(sA + (wr * 64 + mi * 16 + fr) * 32 + usw);
#pragma unroll
    for (int ni = 0; ni < 4; ++ni) {
      bf1[ni] = *(const short8v*)(sB1 + (wc * 64 + ni * 16 + fr) * 32 + usw);
      bf2[ni] = *(const short8v*)(sB2 + (wc * 64 + ni * 16 + fr) * 32 + usw);
    }
    if (stg) {
      SAg(st, kS, 0); SAg(st, kS, 1);
      SB1g(st, kS, 0); SB1g(st, kS, 1);
      SB2g(st, kS, 0); SB2g(st, kS, 1);
    }
    asm volatile("s_waitcnt lgkmcnt(0)" ::: "memory");
    __builtin_amdgcn_sched_barrier(0);
    __builtin_amdgcn_s_setprio(1);
#pragma unroll
    for (int mi = 0; mi < 4; ++mi)
#pragma unroll
      for (int ni = 0; ni < 4; ++ni) {
        acc1[mi][ni] = __builtin_amdgcn_mfma_f32_16x16x32_bf16(af[mi], bf1[ni], acc1[mi][ni], 0, 0, 0);
        acc2[mi][ni] = __builtin_amdgcn_mfma_f32_16x16x32_bf16(af[mi], bf2[ni], acc2[mi][ni], 0, 0, 0);
      }
    __builtin_amdgcn_s_setprio(0);
    if (stg) { asm volatile("s_waitcnt vmcnt(6)" ::: "memory"); }
    else if (ti + 1 < NT) { asm volatile("s_waitcnt vmcnt(0)" ::: "memory"); }
    __builtin_amdgcn_s_barrier();
    sl = (sl == 2) ? 0 : sl + 1;
    st = (st == 2) ? 0 : st + 1;
  }
#undef SAg
#undef SB1g
#undef SB2g

  int er = wr * 64 + (lane >> 4) * 4;
  int ec = wc * 64 + fr;
#pragma unroll
  for (int mi = 0; mi < 4; ++mi) {
#pragma unroll
    for (int ni = 0; ni < 4; ++ni) {
      int col = (int)n0 + ec + ni * 16;
      float b1v = bias[col];
      float b2v = bias[NhRows + col];
#pragma unroll
      for (int j = 0; j < 4; ++j) {
        size_t row = m0 + er + mi * 16 + j;
        float x1 = acc1[mi][ni][j] + b1v;
        float x2 = acc2[mi][ni][j] + b2v;
        float sg = x1 / (1.f + expf(-x1));
        Cout[row * (size_t)Cstride + col] = __float2bfloat16(sg * x2);
      }
    }
  }
}

// ---------------- small 128x128 GEMM (final head only) ----------------
template <int MODE>
__global__ __launch_bounds__(256) void mgemm_kernel(
    const __hip_bfloat16* __restrict__ A,
    const __hip_bfloat16* __restrict__ Wt,
    const float* __restrict__ bias,
    void* __restrict__ Cout,
    int K, int Nh, int Cstride) {
  __shared__ ushort_t As[4 * 128 * 8];
  __shared__ ushort_t Bs[4 * 128 * 8];
  __shared__ ushort_t Bs2[(MODE == 2) ? 4 * 128 * 8 : 8];
  int t = threadIdx.x;
  int w = t >> 6, lane = t & 63;
  int wr = w >> 1, wc = w & 1;
  size_t m0 = (size_t)blockIdx.y * 128;
  size_t n0 = (size_t)blockIdx.x * 128;
  int cell0 = w * 64 + lane;
  int cell1 = 256 + w * 64 + lane;
  int kg0 = cell0 >> 7, rw0 = cell0 & 127;
  int kg1 = cell1 >> 7, rw1 = cell1 & 127;
  const ushort_t* gA = (const ushort_t*)A;
  const ushort_t* gB = (const ushort_t*)Wt;
  const ushort_t* gB2 = (const ushort_t*)(Wt + (size_t)Nh * K);
  size_t a0 = (m0 + rw0) * (size_t)K + kg0 * 8;
  size_t a1 = (m0 + rw1) * (size_t)K + kg1 * 8;
  size_t b0 = (n0 + rw0) * (size_t)K + kg0 * 8;
  size_t b1 = (n0 + rw1) * (size_t)K + kg1 * 8;
  int ldso0 = w * 1024;
  int ldso1 = 4096 + w * 1024;
  f32x4 acc[4][4];
  f32x4 acc2[4][4];
#pragma unroll
  for (int i = 0; i < 4; ++i)
#pragma unroll
    for (int j = 0; j < 4; ++j) {
      acc[i][j] = (f32x4){0.f, 0.f, 0.f, 0.f};
      acc2[i][j] = (f32x4){0.f, 0.f, 0.f, 0.f};
    }
  int fr = lane & 15, kg = lane >> 4;
  int abase = (kg * 128 + wr * 64 + fr) * 16;
  int bbase = (kg * 128 + wc * 64 + fr) * 16;
  for (int k0 = 0; k0 < K; k0 += 32) {
    __syncthreads();
    GLD16(gA + a0 + k0, (char*)As + ldso0);
    GLD16(gA + a1 + k0, (char*)As + ldso1);
    GLD16(gB + b0 + k0, (char*)Bs + ldso0);
    GLD16(gB + b1 + k0, (char*)Bs + ldso1);
    if constexpr (MODE == 2) {
      GLD16(gB2 + b0 + k0, (char*)Bs2 + ldso0);
      GLD16(gB2 + b1 + k0, (char*)Bs2 + ldso1);
    }
    __syncthreads();
    short8v a[4], b[4];
#pragma unroll
    for (int mi = 0; mi < 4; ++mi)
      a[mi] = *(const short8v*)((const char*)As + abase + mi * 256);
#pragma unroll
    for (int ni = 0; ni < 4; ++ni)
      b[ni] = *(const short8v*)((const char*)Bs + bbase + ni * 256);
#pragma unroll
    for (int mi = 0; mi < 4; ++mi)
#pragma unroll
      for (int ni = 0; ni < 4; ++ni)
        acc[mi][ni] = __builtin_amdgcn_mfma_f32_16x16x32_bf16(a[mi], b[ni], acc[mi][ni], 0, 0, 0);
    if constexpr (MODE == 2) {
#pragma unroll
      for (int ni = 0; ni < 4; ++ni)
        b[ni] = *(const short8v*)((const char*)Bs2 + bbase + ni * 256);
#pragma unroll
      for (int mi = 0; mi < 4; ++mi)
#pragma unroll
        for (int ni = 0; ni < 4; ++ni)
          acc2[mi][ni] = __builtin_amdgcn_mfma_f32_16x16x32_bf16(a[mi], b[ni], acc2[mi][ni], 0, 0, 0);
    }
  }
  int er = wr * 64 + (lane >> 4) * 4;
  int ec = wc * 64 + fr;
#pragma unroll
  for (int mi = 0; mi < 4; ++mi) {
#pragma unroll
    for (int ni = 0; ni < 4; ++ni) {
      int col = (int)n0 + ec + ni * 16;
      float bs1 = bias[col];
#pragma unroll
      for (int j = 0; j < 4; ++j) {
        size_t row = m0 + er + mi * 16 + j;
        size_t cidx = row * (size_t)Cstride + col;
        float x = acc[mi][ni][j] + bs1;
        if constexpr (MODE == 3) {
          ((float*)Cout)[cidx] = x;
        } else {
          float x2 = acc2[mi][ni][j] + bias[Nh + col];
          float sig = 1.f / (1.f + expf(-x));
          ((__hip_bfloat16*)Cout)[cidx] = __float2bfloat16(x * sig * x2);
        }
      }
    }
  }
}

// ---------------- attention layer-0: 4 heads per block ----------------
__global__ __launch_bounds__(256) void attn_kernel(const __hip_bfloat16* __restrict__ qkv,
                                                   const float* __restrict__ dist,
                                                   const float* __restrict__ ds_l,
                                                   __hip_bfloat16* __restrict__ o) {
  int nq = blockIdx.x >> 2;
  int h0 = (blockIdx.x & 3) * (NHEAD / HSPLIT);
  int t = threadIdx.x;
  __shared__ float qs[16][65], ks[16][65], vs[16][65];
  __shared__ float sc[16][17], dl[16][17];
  __shared__ float sps_s[NHEAD];
  dl[t >> 4][t & 15] = dist[(size_t)nq * 256 + t];
  if (t < NHEAD) sps_s[t] = log1pf(expf(ds_l[t]));
  size_t base = (size_t)nq * 16 * 3072;
  int e = t >> 4, c4 = (t & 15) * 4;
  const ushort_t* qp = (const ushort_t*)qkv;
  for (int h = h0; h < h0 + NHEAD / HSPLIT; ++h) {
    const ushort_t* p = qp + base + (size_t)e * 3072 + h * 64 + c4;
    ushort4 qv = *(const ushort4*)p;
    ushort4 kv = *(const ushort4*)(p + 1024);
    ushort4 vv = *(const ushort4*)(p + 2048);
    qs[e][c4] = b2f(qv.x); qs[e][c4 + 1] = b2f(qv.y); qs[e][c4 + 2] = b2f(qv.z); qs[e][c4 + 3] = b2f(qv.w);
    ks[e][c4] = b2f(kv.x); ks[e][c4 + 1] = b2f(kv.y); ks[e][c4 + 2] = b2f(kv.z); ks[e][c4 + 3] = b2f(kv.w);
    vs[e][c4] = b2f(vv.x); vs[e][c4 + 1] = b2f(vv.y); vs[e][c4 + 2] = b2f(vv.z); vs[e][c4 + 3] = b2f(vv.w);
    __syncthreads();
    int ee = t >> 4, ff = t & 15;
    float s = 0.f;
#pragma unroll
    for (int d = 0; d < 64; ++d) s = fmaf(qs[ee][d], ks[ff][d], s);
    sc[ee][ff] = s * 0.125f - sps_s[h] * dl[ee][ff];
    __syncthreads();
    if (t < 16) {
      float m = -1e30f;
      for (int f = 0; f < 16; ++f) m = fmaxf(m, sc[t][f]);
      float sum = 0.f;
      for (int f = 0; f < 16; ++f) { float pe = expf(sc[t][f] - m); sc[t][f] = pe; sum += pe; }
      float inv = 1.f / sum;
      for (int f = 0; f < 16; ++f) sc[t][f] *= inv;
    }
    __syncthreads();
#pragma unroll
    for (int r = 0; r < 4; ++r) {
      int idx = t + 256 * r;
      int oe = idx >> 6, od = idx & 63;
      float acc = 0.f;
#pragma unroll
      for (int f = 0; f < 16; ++f) acc = fmaf(sc[oe][f], vs[f][od], acc);
      o[(size_t)(nq * 16 + oe) * 1024 + h * 64 + od] = __float2bfloat16(acc);
    }
    __syncthreads();
  }
}

// ---------------- attention layer-2: token-0 output only ----------------
// One block per query; all 16 heads; writes compact o[nq*1024 + h*64 + d].
__global__ __launch_bounds__(256) void attn2_kernel(const __hip_bfloat16* __restrict__ qkv,
                                                    const float* __restrict__ dist,
                                                    const float* __restrict__ ds_l,
                                                    __hip_bfloat16* __restrict__ o) {
  int nq = blockIdx.x;
  int t = threadIdx.x;
  __shared__ ushort_t ks[16 * 1032];
  __shared__ ushort_t vs[16 * 1032];
  __shared__ float qsf[1024];
  __shared__ float sc[16][17];
  __shared__ float pm[16], pi[16], sps_s[16], dl[16];
  const ushort_t* qp = (const ushort_t*)qkv;
  size_t base = (size_t)nq * 16 * 3072;
#pragma unroll
  for (int i = 0; i < 8; ++i) {
    int flat8 = (i * 256 + t) * 8;
    int e = flat8 >> 10, cc = flat8 & 1023;
    *(short8v*)(ks + e * 1032 + cc) = *(const short8v*)(qp + base + (size_t)e * 3072 + 1024 + cc);
    *(short8v*)(vs + e * 1032 + cc) = *(const short8v*)(qp + base + (size_t)e * 3072 + 2048 + cc);
  }
  {
    ushort4 qv = *(const ushort4*)(qp + base + t * 4);
    qsf[t * 4 + 0] = b2f(qv.x); qsf[t * 4 + 1] = b2f(qv.y);
    qsf[t * 4 + 2] = b2f(qv.z); qsf[t * 4 + 3] = b2f(qv.w);
  }
  if (t < 16) {
    sps_s[t] = log1pf(expf(ds_l[t]));
    dl[t] = dist[(size_t)nq * 256 + t];
  }
  __syncthreads();
  int h = t >> 4, f = t & 15;
  float s = 0.f;
#pragma unroll
  for (int dc = 0; dc < 8; ++dc) {
    short8v k8 = *(const short8v*)(ks + f * 1032 + h * 64 + dc * 8);
#pragma unroll
    for (int j = 0; j < 8; ++j)
      s = fmaf(qsf[h * 64 + dc * 8 + j], b2f((ushort_t)k8[j]), s);
  }
  sc[h][f] = s * 0.125f - sps_s[h] * dl[f];
  __syncthreads();
  if (t < 16) {
    float m = -1e30f;
    for (int ff = 0; ff < 16; ++ff) m = fmaxf(m, sc[t][ff]);
    float sum = 0.f;
    for (int ff = 0; ff < 16; ++ff) sum += expf(sc[t][ff] - m);
    pm[t] = m; pi[t] = 1.f / sum;
  }
  __syncthreads();
  float p = expf(sc[h][f] - pm[h]) * pi[h];
  __syncthreads();
  sc[h][f] = p;
  __syncthreads();
#pragma unroll
  for (int r = 0; r < 4; ++r) {
    int idx = t + 256 * r;
    int oh = idx >> 6, od = idx & 63;
    float acc = 0.f;
#pragma unroll
    for (int f2 = 0; f2 < 16; ++f2)
      acc = fmaf(sc[oh][f2], b2f(vs[f2 * 1032 + oh * 64 + od]), acc);
    o[(size_t)nq * 1024 + idx] = __float2bfloat16(acc);
  }
}

// ---------------- z0 gather: token-0 rows -> compact fp32 ----------------
__global__ __launch_bounds__(256) void z0copy_kernel(const float* __restrict__ z,
                                                     float* __restrict__ z0) {
  ((float4*)(z0 + (size_t)blockIdx.x * 1024))[threadIdx.x] =
      ((const float4*)(z + (size_t)blockIdx.x * 16384))[threadIdx.x];
}

// ---------------- final VAE head elementwise ----------------
__global__ __launch_bounds__(64) void final_kernel(const float* __restrict__ tmp,
                                                   const float* __restrict__ eps,
                                                   float* __restrict__ out) {
  int r = blockIdx.x; int j = threadIdx.x;
  float mu = tmp[r * 128 + j];
  float lv = fminf(tmp[r * 128 + 64 + j], 5.0f);
  float zs = mu + eps[r * 64 + j] * expf(0.5f * lv);
  out[r * 64 + j] = zs;
  out[262144 + r * 64 + j] = mu;
  out[524288 + r * 64 + j] = lv;
}

extern "C" void kernel_launch(void* const* d_in, const int* in_sizes, int n_in,
                              void* d_out, int out_size, void* d_ws, size_t ws_size,
                              hipStream_t stream) {
  (void)in_sizes; (void)n_in; (void)out_size;
  const float* coords = (const float*)d_in[0];
  const float* eps    = (const float*)d_in[1];
  const float* emb    = (const float*)d_in[2];
  const float* ln1_g  = (const float*)d_in[3];
  const float* ln1_b  = (const float*)d_in[4];
  const float* Wqkv   = (const float*)d_in[5];
  const float* bqkv   = (const float*)d_in[6];
  const float* dist_scale = (const float*)d_in[7];
  const float* Wo     = (const float*)d_in[8];
  const float* bo     = (const float*)d_in[9];
  const float* ln2_g  = (const float*)d_in[10];
  const float* ln2_b  = (const float*)d_in[11];
  const float* Wf1    = (const float*)d_in[12];
  const float* bf1    = (const float*)d_in[13];
  const float* Wf2    = (const float*)d_in[14];
  const float* bf2    = (const float*)d_in[15];
  const float* lnf_g  = (const float*)d_in[16];
  const float* lnf_b  = (const float*)d_in[17];
  const float* We1    = (const float*)d_in[18];
  const float* be1    = (const float*)d_in[19];
  const float* We2    = (const float*)d_in[20];
  const float* be2    = (const float*)d_in[21];

  char* ws = (char*)d_ws;
  int*   edges = (int*)ws;                                        // 256 KB
  float* dist  = (float*)(ws + (4ull << 20));                     // 4 MB
  __hip_bfloat16* hfinal = (__hip_bfloat16*)(ws + (8ull << 20));  // 8 MB
  __hip_bfloat16* gated  = (__hip_bfloat16*)(ws + (16ull << 20)); // 4 MB
  float* tmp   = (float*)(ws + (20ull << 20));                    // 2 MB
  __hip_bfloat16* o_all  = (__hip_bfloat16*)(ws + (22ull << 20)); // 8 MB (NQ x 1024 bf16)
  float* z0_all = (float*)(ws + (30ull << 20));                   // 16 MB (NQ x 1024 fp32)
  __hip_bfloat16* wbase = (__hip_bfloat16*)(ws + (46ull << 20));  // ~69.3 MB
  size_t woff = 0;
  __hip_bfloat16* wqkvT = wbase + woff; woff += 2ull * 3072 * 1024;
  __hip_bfloat16* woT   = wbase + woff; woff += 2ull * 1024 * 1024;
  __hip_bfloat16* wf1T  = wbase + woff; woff += 2ull * 8192 * 1024;
  __hip_bfloat16* wf2T  = wbase + woff; woff += 2ull * 1024 * 4096;
  __hip_bfloat16* we1T  = wbase + woff; woff += 1024ull * 1024;
  __hip_bfloat16* we2T  = wbase + woff; woff += 128ull * 512;

  const size_t FIXED = 116ull << 20;
  int CQ = 4096;
  while (CQ > 256 && FIXED + (size_t)CQ * 16 * 14336ull > ws_size) CQ >>= 1;
  if (FIXED + (size_t)CQ * 16 * 14336ull > ws_size) return;  // ws too small: leave poison
  size_t CT = (size_t)CQ * KNNK;
  char* creg = ws + FIXED;
  float* zbuf = (float*)creg;                                    // CT x 1024 fp32
  __hip_bfloat16* hbuf = (__hip_bfloat16*)(creg + CT * 4096);    // CT x 1024 bf16
  __hip_bfloat16* sh8  = (__hip_bfloat16*)(creg + CT * 6144);    // CT x 4096 bf16
  // post-loop aliases (chunk buffers dead after loop; CT>=4096 guarantees fit)
  __hip_bfloat16* h2        = hbuf;   // NQ x 1024 bf16 (8 MB)
  __hip_bfloat16* gated_all = sh8;    // NQ x 4096 bf16 (32 MB)

  knn_kernel<<<NQ, 64, 0, stream>>>(coords, edges);
  dist_kernel<<<NQ, 256, 0, stream>>>(coords, edges, dist);
  for (int l = 0; l < NLAYER; ++l) {
    wconv_kernel<<<dim3(96, 32), 256, 0, stream>>>(Wqkv + (size_t)l * 1024 * 3072,
                                                   wqkvT + (size_t)l * 3072 * 1024, 1024, 3072);
    wconv_kernel<<<dim3(32, 32), 256, 0, stream>>>(Wo + (size_t)l * 1024 * 1024,
                                                   woT + (size_t)l * 1024 * 1024, 1024, 1024);
    wconv_kernel<<<dim3(256, 32), 256, 0, stream>>>(Wf1 + (size_t)l * 1024 * 8192,
                                                    wf1T + (size_t)l * 8192 * 1024, 1024, 8192);
    wconv_kernel<<<dim3(32, 128), 256, 0, stream>>>(Wf2 + (size_t)l * 4096 * 1024,
                                                    wf2T + (size_t)l * 1024 * 4096, 4096, 1024);
  }
  wconv_kernel<<<dim3(32, 32), 256, 0, stream>>>(We1, we1T, 1024, 1024);
  wconv_kernel<<<dim3(4, 16), 256, 0, stream>>>(We2, we2T, 512, 128);

  int NCH = NQ / CQ;
  int MT128 = (int)(CT / 128);
  for (int c = 0; c < NCH; ++c) {
    zinit_kernel<<<(int)CT, 256, 0, stream>>>(edges, emb, zbuf, (int)(c * CT));
    // ---- layer 0: full (all tokens feed layer-1 K/V) ----
    ln_kernel<<<(int)CT, 256, 0, stream>>>(zbuf, DIM, ln1_g, ln1_b, hbuf);
    gemmT128_kernel<0><<<MT128 * 24, 256, 0, stream>>>(
        (const ushort_t*)hbuf, (const ushort_t*)wqkvT, bqkv, sh8, 1024, MT128, 3072, 24, 4);
    attn_kernel<<<CQ * HSPLIT, 256, 0, stream>>>(sh8, dist + (size_t)c * CQ * 256,
                                                 dist_scale, hbuf);
    gemmT128_kernel<1><<<MT128 * 8, 256, 0, stream>>>(
        (const ushort_t*)hbuf, (const ushort_t*)woT, bo, zbuf, 1024, MT128, 1024, 8, 2);
    ln_kernel<<<(int)CT, 256, 0, stream>>>(zbuf, DIM, ln2_g, ln2_b, hbuf);
    gemmGW_kernel<<<MT128 * 32, 256, 0, stream>>>(
        (const ushort_t*)hbuf, (const ushort_t*)wf1T, bf1, sh8, 1024, MT128, 4096, 4096, 32, 4);
    gemmT128_kernel<1><<<MT128 * 8, 256, 0, stream>>>(
        (const ushort_t*)sh8, (const ushort_t*)wf2T, bf2, zbuf, 4096, MT128, 1024, 8, 2);
    // ---- layer 1 front: full ln1+qkv (K/V need all tokens); token-0 attn ----
    ln_kernel<<<(int)CT, 256, 0, stream>>>(zbuf, DIM, ln1_g + DIM, ln1_b + DIM, hbuf);
    gemmT128_kernel<0><<<MT128 * 24, 256, 0, stream>>>(
        (const ushort_t*)hbuf, (const ushort_t*)(wqkvT + 3072ull * 1024),
        bqkv + 3072, sh8, 1024, MT128, 3072, 24, 4);
    attn2_kernel<<<CQ, 256, 0, stream>>>(sh8, dist + (size_t)c * CQ * 256,
                                         dist_scale + NHEAD, o_all + (size_t)c * CQ * 1024);
    z0copy_kernel<<<CQ, 256, 0, stream>>>(zbuf, z0_all + (size_t)c * CQ * 1024);
  }

  // ---- layer 1 tail on compact token-0 rows: M = NQ = 4096 ----
  int MTQ = NQ / 128;  // 32
  gemmT128_kernel<1><<<MTQ * 8, 256, 0, stream>>>(
      (const ushort_t*)o_all, (const ushort_t*)(woT + 1024ull * 1024),
      bo + DIM, z0_all, 1024, MTQ, 1024, 8, 2);
  ln_kernel<<<NQ, 256, 0, stream>>>(z0_all, DIM, ln2_g + DIM, ln2_b + DIM, h2);
  gemmGW_kernel<<<MTQ * 32, 256, 0, stream>>>(
      (const ushort_t*)h2, (const ushort_t*)(wf1T + 8192ull * 1024),
      bf1 + 2 * DFFN, gated_all, 1024, MTQ, 4096, 4096, 32, 4);
  gemmT128_kernel<1><<<MTQ * 8, 256, 0, stream>>>(
      (const ushort_t*)gated_all, (const ushort_t*)(wf2T + 1024ull * 4096),
      bf2 + DIM, z0_all, 4096, MTQ, 1024, 8, 2);
  ln_kernel<<<NQ, 256, 0, stream>>>(z0_all, DIM, lnf_g, lnf_b, hfinal);

  mgemm_kernel<2><<<dim3(4, 32), 256, 0, stream>>>(hfinal, we1T, be1, gated, 1024, 512, 512);
  mgemm_kernel<3><<<dim3(1, 32), 256, 0, stream>>>(gated, we2T, be2, tmp, 512, 0, 128);
  final_kernel<<<NQ, 64, 0, stream>>>(tmp, eps, (float*)d_out);
}

// Round 13
// 3727.312 us; speedup vs baseline: 1.7510x; 1.0907x over previous
//
#include <hip/hip_runtime.h>
#include <hip/hip_bf16.h>
#include <math.h>

#define LLEN 512
#define KNNK 16
#define DIM 1024
#define NHEAD 16
#define NLAYER 2
#define DFFN 4096
#define POSCLIP 32
#define NQ 4096
#define NTOK 65536
#define HSPLIT 4

typedef __attribute__((ext_vector_type(8))) short short8v;
typedef __attribute__((ext_vector_type(4))) float f32x4;
typedef unsigned short ushort_t;

__device__ __forceinline__ float b2f(ushort_t u) {
  union { unsigned u; float f; } x; x.u = ((unsigned)u) << 16; return x.f;
}

// 2D XCD-blocked tile mapping: B-slice L2-resident, A fetched ~once/XCD.
__device__ __forceinline__ void xcd_map(int bid, int Mtiles, int Ntiles, int XN,
                                        int& mt, int& nt) {
  int nt_per = Ntiles / XN;
  int mt_per = (Mtiles * XN) >> 3;
  int xcd = bid & 7, i = bid >> 3;
  int xn = xcd % XN, xm = xcd / XN;
  int ntl = i % nt_per, mtl = i / nt_per;
  mt = xm * mt_per + mtl;
  nt = xn * nt_per + ntl;
}

#define GLD16(gp, lp)                                                          \
  __builtin_amdgcn_global_load_lds(                                            \
      (const __attribute__((address_space(1))) void*)(gp),                     \
      (__attribute__((address_space(3))) void*)(lp), 16, 0, 0)

// ---------------- KNN: one wave per query ----------------
__global__ __launch_bounds__(64) void knn_kernel(const float* __restrict__ coords,
                                                 int* __restrict__ edges) {
  int n = blockIdx.x;
  int b = n / LLEN, i = n % LLEN;
  int lane = threadIdx.x;
  const float* cb = coords + (size_t)b * LLEN * 9;
  float xi = cb[i * 9 + 3], yi = cb[i * 9 + 4], zi = cb[i * 9 + 5];
  float d[8];
#pragma unroll
  for (int r = 0; r < 8; ++r) {
    int j = r * 64 + lane;
    float dx = xi - cb[j * 9 + 3];
    float dy = yi - cb[j * 9 + 4];
    float dz = zi - cb[j * 9 + 5];
    d[r] = dx * dx + dy * dy + dz * dz;
  }
  for (int s = 0; s < KNNK; ++s) {
    float bv = INFINITY; int bi = 1 << 30;
#pragma unroll
    for (int r = 0; r < 8; ++r) {
      int j = r * 64 + lane;
      if (d[r] < bv || (d[r] == bv && j < bi)) { bv = d[r]; bi = j; }
    }
#pragma unroll
    for (int off = 32; off > 0; off >>= 1) {
      float ov = __shfl_xor(bv, off);
      int   oi = __shfl_xor(bi, off);
      if (ov < bv || (ov == bv && oi < bi)) { bv = ov; bi = oi; }
    }
    if (lane == 0) edges[n * KNNK + s] = bi;
    if ((bi & 63) == lane) d[bi >> 6] = INFINITY;
  }
}

// ---------------- dist: 16x16 per query ----------------
__global__ __launch_bounds__(256) void dist_kernel(const float* __restrict__ coords,
                                                   const int* __restrict__ edges,
                                                   float* __restrict__ dist) {
  int n = blockIdx.x; int b = n / LLEN;
  __shared__ float tx[16], ty[16], tz[16];
  int t = threadIdx.x;
  const float* cb = coords + (size_t)b * LLEN * 9;
  if (t < 16) {
    int j = edges[n * KNNK + t];
    tx[t] = cb[j * 9 + 3]; ty[t] = cb[j * 9 + 4]; tz[t] = cb[j * 9 + 5];
  }
  __syncthreads();
  int e = t >> 4, f = t & 15;
  float dx = tx[e] - tx[f], dy = ty[e] - ty[f], dz = tz[e] - tz[f];
  dist[(size_t)n * 256 + t] = sqrtf(dx * dx + dy * dy + dz * dz + 1e-8f);
}

// ---------------- z init (chunked) ----------------
__global__ __launch_bounds__(256) void zinit_kernel(const int* __restrict__ edges,
                                                    const float* __restrict__ emb,
                                                    float* __restrict__ zbuf, int tok0) {
  int tl = blockIdx.x;
  int tok = tok0 + tl;
  int n = tok >> 4;
  int diff = edges[tok] - edges[n << 4];
  int idx = min(max(diff, -POSCLIP), POSCLIP) + POSCLIP;
  ((float4*)(zbuf + (size_t)tl * DIM))[threadIdx.x] =
      ((const float4*)(emb + (size_t)idx * DIM))[threadIdx.x];
}

// ---------------- LayerNorm fp32 in -> bf16 out ----------------
__global__ __launch_bounds__(256) void ln_kernel(const float* __restrict__ X, int stride,
                                                 const float* __restrict__ g,
                                                 const float* __restrict__ bta,
                                                 __hip_bfloat16* __restrict__ Y) {
  int row = blockIdx.x; int t = threadIdx.x;
  const float4* xr = (const float4*)(X + (size_t)row * stride);
  float4 v = xr[t];
  float s = v.x + v.y + v.z + v.w;
  __shared__ float red[8];
  for (int off = 32; off; off >>= 1) s += __shfl_down(s, off);
  int wid = t >> 6;
  if ((t & 63) == 0) red[wid] = s;
  __syncthreads();
  if (t == 0) red[4] = (red[0] + red[1] + red[2] + red[3]) * (1.0f / DIM);
  __syncthreads();
  float mean = red[4];
  float d0 = v.x - mean, d1 = v.y - mean, d2 = v.z - mean, d3 = v.w - mean;
  float s2 = d0 * d0 + d1 * d1 + d2 * d2 + d3 * d3;
  for (int off = 32; off; off >>= 1) s2 += __shfl_down(s2, off);
  if ((t & 63) == 0) red[wid] = s2;
  __syncthreads();
  if (t == 0) red[5] = rsqrtf((red[0] + red[1] + red[2] + red[3]) * (1.0f / DIM) + 1e-5f);
  __syncthreads();
  float rstd = red[5];
  float4 gv = ((const float4*)g)[t], bv = ((const float4*)bta)[t];
  size_t o = (size_t)row * DIM + t * 4;
  Y[o + 0] = __float2bfloat16(d0 * rstd * gv.x + bv.x);
  Y[o + 1] = __float2bfloat16(d1 * rstd * gv.y + bv.y);
  Y[o + 2] = __float2bfloat16(d2 * rstd * gv.z + bv.z);
  Y[o + 3] = __float2bfloat16(d3 * rstd * gv.w + bv.w);
}

// ---------------- weight fp32 K x N -> bf16 N x K ----------------
__global__ __launch_bounds__(256) void wconv_kernel(const float* __restrict__ W,
                                                    __hip_bfloat16* __restrict__ Wt,
                                                    int K, int N) {
  __shared__ float tile[32][33];
  int n0 = blockIdx.x * 32, k0 = blockIdx.y * 32;
  int c = threadIdx.x & 31, r = threadIdx.x >> 5;
#pragma unroll
  for (int i = 0; i < 4; ++i)
    tile[r + i * 8][c] = W[(size_t)(k0 + r + i * 8) * N + n0 + c];
  __syncthreads();
#pragma unroll
  for (int i = 0; i < 4; ++i)
    Wt[(size_t)(n0 + r + i * 8) * K + k0 + c] = __float2bfloat16(tile[c][r + i * 8]);
}

// ---------------- qkv for the 65 distinct layer-0 rows ----------------
// out[r, c] = dot(h65[r], wqkvT[c]) + b[c];  one block per row r.
__global__ __launch_bounds__(256) void qkv65_kernel(const __hip_bfloat16* __restrict__ h65,
                                                    const __hip_bfloat16* __restrict__ wqkvT,
                                                    const float* __restrict__ bqkv,
                                                    __hip_bfloat16* __restrict__ out) {
  int r = blockIdx.x;
  int t = threadIdx.x;
  __shared__ float a[1024];
  {
    ushort4 v = *(const ushort4*)((const ushort_t*)h65 + (size_t)r * 1024 + t * 4);
    a[t * 4 + 0] = b2f(v.x); a[t * 4 + 1] = b2f(v.y);
    a[t * 4 + 2] = b2f(v.z); a[t * 4 + 3] = b2f(v.w);
  }
  __syncthreads();
  for (int c = t; c < 3072; c += 256) {
    const ushort_t* wrow = (const ushort_t*)wqkvT + (size_t)c * 1024;
    float s = 0.f;
    for (int k = 0; k < 1024; k += 8) {
      short8v w8 = *(const short8v*)(wrow + k);
#pragma unroll
      for (int j = 0; j < 8; ++j) s = fmaf(a[k + j], b2f((ushort_t)w8[j]), s);
    }
    out[(size_t)r * 3072 + c] = __float2bfloat16(s + bqkv[c]);
  }
}

// BK=32 swizzle: LDS chunk c holds global k-chunk c ^ ((row>>1)&3);
// reads use kg ^ ((fr>>1)&3). <=2-way (free).

// ============ gemmT128: BM=128, BN=128, BK=32, 256 thr (4 waves 2x2),
// 3-slot ring (48KB LDS). MODE 0: bf16 C = x  MODE 1: fp32 C += x
template <int MODE>
__global__ __launch_bounds__(256, 3) void gemmT128_kernel(
    const ushort_t* __restrict__ A,
    const ushort_t* __restrict__ Wt,
    const float* __restrict__ bias,
    void* __restrict__ Cout,
    int K, int Mtiles, int Cstride, int Ntiles, int XN) {
  __shared__ ushort_t Alds[3][4096];
  __shared__ ushort_t Blds[3][4096];
  int t = threadIdx.x;
  int w = t >> 6, lane = t & 63;
  int wr = w >> 1, wc = w & 1;
  int fr = lane & 15, kg = lane >> 4;

  int mt, nt;
  xcd_map(blockIdx.x, Mtiles, Ntiles, XN, mt, nt);
  size_t m0 = (size_t)mt * 128, n0 = (size_t)nt * 128;

  int stg_r = w * 16 + (lane >> 2);
  int stg_c = (((lane & 3) ^ ((lane >> 3) & 3)) << 3);
  const ushort_t* gAl = A + (m0 + stg_r) * (size_t)K + stg_c;
  const ushort_t* gBl = Wt + (n0 + stg_r) * (size_t)K + stg_c;
  int lds_w = w * 512;

#define SAt(slot, kcol, j) GLD16(gAl + (size_t)(j) * 64 * K + (kcol), Alds[slot] + (j) * 2048 + lds_w)
#define SBt(slot, kcol, j) GLD16(gBl + (size_t)(j) * 64 * K + (kcol), Blds[slot] + (j) * 2048 + lds_w)

  f32x4 acc[4][4];
#pragma unroll
  for (int i = 0; i < 4; ++i)
#pragma unroll
    for (int j = 0; j < 4; ++j) acc[i][j] = (f32x4){0.f, 0.f, 0.f, 0.f};

  int usw = ((kg ^ ((fr >> 1) & 3)) << 3);

  SAt(0, 0, 0); SAt(0, 0, 1); SBt(0, 0, 0); SBt(0, 0, 1);
  SAt(1, 32, 0); SAt(1, 32, 1); SBt(1, 32, 0); SBt(1, 32, 1);
  asm volatile("s_waitcnt vmcnt(4)" ::: "memory");
  __builtin_amdgcn_s_barrier();

  short8v af[4], bf[4];
  int NT = K >> 5;
  int sl = 0, st = 2;
  for (int ti = 0; ti < NT; ++ti) {
    int kS = (ti + 2) << 5;
    int stg = (ti + 2) < NT;
    const ushort_t* sA = Alds[sl];
    const ushort_t* sB = Blds[sl];
#pragma unroll
    for (int mi = 0; mi < 4; ++mi)
      af[mi] = *(const short8v*)(sA + (wr * 64 + mi * 16 + fr) * 32 + usw);
#pragma unroll
    for (int ni = 0; ni < 4; ++ni)
      bf[ni] = *(const short8v*)(sB + (wc * 64 + ni * 16 + fr) * 32 + usw);
    if (stg) { SAt(st, kS, 0); SAt(st, kS, 1); SBt(st, kS, 0); SBt(st, kS, 1); }
    asm volatile("s_waitcnt lgkmcnt(0)" ::: "memory");
    __builtin_amdgcn_sched_barrier(0);
    __builtin_amdgcn_s_setprio(1);
#pragma unroll
    for (int mi = 0; mi < 4; ++mi)
#pragma unroll
      for (int ni = 0; ni < 4; ++ni)
        acc[mi][ni] = __builtin_amdgcn_mfma_f32_16x16x32_bf16(af[mi], bf[ni], acc[mi][ni], 0, 0, 0);
    __builtin_amdgcn_s_setprio(0);
    if (stg) { asm volatile("s_waitcnt vmcnt(4)" ::: "memory"); }
    else if (ti + 1 < NT) { asm volatile("s_waitcnt vmcnt(0)" ::: "memory"); }
    __builtin_amdgcn_s_barrier();
    sl = (sl == 2) ? 0 : sl + 1;
    st = (st == 2) ? 0 : st + 1;
  }
#undef SAt
#undef SBt

  int er = wr * 64 + (lane >> 4) * 4;
  int ec = wc * 64 + fr;
#pragma unroll
  for (int mi = 0; mi < 4; ++mi) {
#pragma unroll
    for (int ni = 0; ni < 4; ++ni) {
      int col = (int)n0 + ec + ni * 16;
      float bs = bias[col];
#pragma unroll
      for (int j = 0; j < 4; ++j) {
        size_t row = m0 + er + mi * 16 + j;
        size_t cidx = row * (size_t)Cstride + col;
        float x = acc[mi][ni][j] + bs;
        if constexpr (MODE == 0) {
          ((__hip_bfloat16*)Cout)[cidx] = __float2bfloat16(x);
        } else {
          ((float*)Cout)[cidx] += x;
        }
      }
    }
  }
}

// ============ gemmGW: fused gated ff1, 4 waves (2Mx2N), per-wave 64x64 of
// BOTH gated outputs. BM=128, BN=128 dual, BK=32, 3-slot ring 72KB, 2 blk/CU.
__global__ __launch_bounds__(256, 2) void gemmGW_kernel(
    const ushort_t* __restrict__ A,
    const ushort_t* __restrict__ Wt,
    const float* __restrict__ bias,
    __hip_bfloat16* __restrict__ Cout,
    int K, int Mtiles, int Cstride, int NhRows, int Ntiles, int XN) {
  __shared__ ushort_t Alds[3][4096];
  __shared__ ushort_t B1lds[3][4096];
  __shared__ ushort_t B2lds[3][4096];
  int t = threadIdx.x;
  int w = t >> 6, lane = t & 63;
  int wr = w >> 1, wc = w & 1;
  int fr = lane & 15, kg = lane >> 4;

  int mt, nt;
  xcd_map(blockIdx.x, Mtiles, Ntiles, XN, mt, nt);
  size_t m0 = (size_t)mt * 128, n0 = (size_t)nt * 128;

  int stg_r = w * 16 + (lane >> 2);
  int stg_c = (((lane & 3) ^ ((lane >> 3) & 3)) << 3);
  const ushort_t* gAl = A + (m0 + stg_r) * (size_t)K + stg_c;
  const ushort_t* gB1 = Wt + (n0 + stg_r) * (size_t)K + stg_c;
  const ushort_t* gB2 = Wt + ((size_t)NhRows + n0 + stg_r) * (size_t)K + stg_c;
  int lds_w = w * 512;

#define SAg(slot, kcol, j) GLD16(gAl + (size_t)(j) * 64 * K + (kcol), Alds[slot] + (j) * 2048 + lds_w)
#define SB1g(slot, kcol, j) GLD16(gB1 + (size_t)(j) * 64 * K + (kcol), B1lds[slot] + (j) * 2048 + lds_w)
#define SB2g(slot, kcol, j) GLD16(gB2 + (size_t)(j) * 64 * K + (kcol), B2lds[slot] + (j) * 2048 + lds_w)

  f32x4 acc1[4][4], acc2[4][4];
#pragma unroll
  for (int i = 0; i < 4; ++i)
#pragma unroll
    for (int j = 0; j < 4; ++j) {
      acc1[i][j] = (f32x4){0.f, 0.f, 0.f, 0.f};
      acc2[i][j] = (f32x4){0.f, 0.f, 0.f, 0.f};
    }

  int usw = ((kg ^ ((fr >> 1) & 3)) << 3);

  SAg(0, 0, 0); SAg(0, 0, 1); SB1g(0, 0, 0); SB1g(0, 0, 1); SB2g(0, 0, 0); SB2g(0, 0, 1);
  SAg(1, 32, 0); SAg(1, 32, 1); SB1g(1, 32, 0); SB1g(1, 32, 1); SB2g(1, 32, 0); SB2g(1, 32, 1);
  asm volatile("s_waitcnt vmcnt(6)" ::: "memory");
  __builtin_amdgcn_s_barrier();

  short8v af[4], bf1[4], bf2[4];
  int NT = K >> 5;
  int sl = 0, st = 2;
  for (int ti = 0; ti < NT; ++ti) {
    int kS = (ti + 2) << 5;
    int stg = (ti + 2) < NT;
    const ushort_t* sA = Alds[sl];
    const ushort_t* sB1 = B1lds[sl];
    const ushort_t* sB2 = B2lds[sl];
#pragma unroll
    for (int mi = 0; mi < 4; ++mi)
      af[mi] = *(const short8v*)(sA + (wr * 64 + mi * 16 + fr) * 32 + usw);
#pragma unroll
    for (int ni = 0; ni < 4; ++ni) {
      bf1[ni] = *(const short8v*)(sB1 + (wc * 64 + ni * 16 + fr) * 32 + usw);
      bf2[ni] = *(const short8v*)(sB2 + (wc * 64 + ni * 16 + fr) * 32 + usw);
    }
    if (stg) {
      SAg(st, kS, 0); SAg(st, kS, 1);
      SB1g(st, kS, 0); SB1g(st, kS, 1);
      SB2g(st, kS, 0); SB2g(st, kS, 1);
    }
    asm volatile("s_waitcnt lgkmcnt(0)" ::: "memory");
    __builtin_amdgcn_sched_barrier(0);
    __builtin_amdgcn_s_setprio(1);
#pragma unroll
    for (int mi = 0; mi < 4; ++mi)
#pragma unroll
      for (int ni = 0; ni < 4; ++ni) {
        acc1[mi][ni] = __builtin_amdgcn_mfma_f32_16x16x32_bf16(af[mi], bf1[ni], acc1[mi][ni], 0, 0, 0);
        acc2[mi][ni] = __builtin_amdgcn_mfma_f32_16x16x32_bf16(af[mi], bf2[ni], acc2[mi][ni], 0, 0, 0);
      }
    __builtin_amdgcn_s_setprio(0);
    if (stg) { asm volatile("s_waitcnt vmcnt(6)" ::: "memory"); }
    else if (ti + 1 < NT) { asm volatile("s_waitcnt vmcnt(0)" ::: "memory"); }
    __builtin_amdgcn_s_barrier();
    sl = (sl == 2) ? 0 : sl + 1;
    st = (st == 2) ? 0 : st + 1;
  }
#undef SAg
#undef SB1g
#undef SB2g

  int er = wr * 64 + (lane >> 4) * 4;
  int ec = wc * 64 + fr;
#pragma unroll
  for (int mi = 0; mi < 4; ++mi) {
#pragma unroll
    for (int ni = 0; ni < 4; ++ni) {
      int col = (int)n0 + ec + ni * 16;
      float b1v = bias[col];
      float b2v = bias[NhRows + col];
#pragma unroll
      for (int j = 0; j < 4; ++j) {
        size_t row = m0 + er + mi * 16 + j;
        float x1 = acc1[mi][ni][j] + b1v;
        float x2 = acc2[mi][ni][j] + b2v;
        float sg = x1 / (1.f + expf(-x1));
        Cout[row * (size_t)Cstride + col] = __float2bfloat16(sg * x2);
      }
    }
  }
}

// ---------------- small 128x128 GEMM (final head only) ----------------
template <int MODE>
__global__ __launch_bounds__(256) void mgemm_kernel(
    const __hip_bfloat16* __restrict__ A,
    const __hip_bfloat16* __restrict__ Wt,
    const float* __restrict__ bias,
    void* __restrict__ Cout,
    int K, int Nh, int Cstride) {
  __shared__ ushort_t As[4 * 128 * 8];
  __shared__ ushort_t Bs[4 * 128 * 8];
  __shared__ ushort_t Bs2[(MODE == 2) ? 4 * 128 * 8 : 8];
  int t = threadIdx.x;
  int w = t >> 6, lane = t & 63;
  int wr = w >> 1, wc = w & 1;
  size_t m0 = (size_t)blockIdx.y * 128;
  size_t n0 = (size_t)blockIdx.x * 128;
  int cell0 = w * 64 + lane;
  int cell1 = 256 + w * 64 + lane;
  int kg0 = cell0 >> 7, rw0 = cell0 & 127;
  int kg1 = cell1 >> 7, rw1 = cell1 & 127;
  const ushort_t* gA = (const ushort_t*)A;
  const ushort_t* gB = (const ushort_t*)Wt;
  const ushort_t* gB2 = (const ushort_t*)(Wt + (size_t)Nh * K);
  size_t a0 = (m0 + rw0) * (size_t)K + kg0 * 8;
  size_t a1 = (m0 + rw1) * (size_t)K + kg1 * 8;
  size_t b0 = (n0 + rw0) * (size_t)K + kg0 * 8;
  size_t b1 = (n0 + rw1) * (size_t)K + kg1 * 8;
  int ldso0 = w * 1024;
  int ldso1 = 4096 + w * 1024;
  f32x4 acc[4][4];
  f32x4 acc2[4][4];
#pragma unroll
  for (int i = 0; i < 4; ++i)
#pragma unroll
    for (int j = 0; j < 4; ++j) {
      acc[i][j] = (f32x4){0.f, 0.f, 0.f, 0.f};
      acc2[i][j] = (f32x4){0.f, 0.f, 0.f, 0.f};
    }
  int fr = lane & 15, kg = lane >> 4;
  int abase = (kg * 128 + wr * 64 + fr) * 16;
  int bbase = (kg * 128 + wc * 64 + fr) * 16;
  for (int k0 = 0; k0 < K; k0 += 32) {
    __syncthreads();
    GLD16(gA + a0 + k0, (char*)As + ldso0);
    GLD16(gA + a1 + k0, (char*)As + ldso1);
    GLD16(gB + b0 + k0, (char*)Bs + ldso0);
    GLD16(gB + b1 + k0, (char*)Bs + ldso1);
    if constexpr (MODE == 2) {
      GLD16(gB2 + b0 + k0, (char*)Bs2 + ldso0);
      GLD16(gB2 + b1 + k0, (char*)Bs2 + ldso1);
    }
    __syncthreads();
    short8v a[4], b[4];
#pragma unroll
    for (int mi = 0; mi < 4; ++mi)
      a[mi] = *(const short8v*)((const char*)As + abase + mi * 256);
#pragma unroll
    for (int ni = 0; ni < 4; ++ni)
      b[ni] = *(const short8v*)((const char*)Bs + bbase + ni * 256);
#pragma unroll
    for (int mi = 0; mi < 4; ++mi)
#pragma unroll
      for (int ni = 0; ni < 4; ++ni)
        acc[mi][ni] = __builtin_amdgcn_mfma_f32_16x16x32_bf16(a[mi], b[ni], acc[mi][ni], 0, 0, 0);
    if constexpr (MODE == 2) {
#pragma unroll
      for (int ni = 0; ni < 4; ++ni)
        b[ni] = *(const short8v*)((const char*)Bs2 + bbase + ni * 256);
#pragma unroll
      for (int mi = 0; mi < 4; ++mi)
#pragma unroll
        for (int ni = 0; ni < 4; ++ni)
          acc2[mi][ni] = __builtin_amdgcn_mfma_f32_16x16x32_bf16(a[mi], b[ni], acc2[mi][ni], 0, 0, 0);
    }
  }
  int er = wr * 64 + (lane >> 4) * 4;
  int ec = wc * 64 + fr;
#pragma unroll
  for (int mi = 0; mi < 4; ++mi) {
#pragma unroll
    for (int ni = 0; ni < 4; ++ni) {
      int col = (int)n0 + ec + ni * 16;
      float bs1 = bias[col];
#pragma unroll
      for (int j = 0; j < 4; ++j) {
        size_t row = m0 + er + mi * 16 + j;
        size_t cidx = row * (size_t)Cstride + col;
        float x = acc[mi][ni][j] + bs1;
        if constexpr (MODE == 3) {
          ((float*)Cout)[cidx] = x;
        } else {
          float x2 = acc2[mi][ni][j] + bias[Nh + col];
          float sig = 1.f / (1.f + expf(-x));
          ((__hip_bfloat16*)Cout)[cidx] = __float2bfloat16(x * sig * x2);
        }
      }
    }
  }
}

// ---------------- attention layer-0: gather q/k/v from qkv65 via edges map ----
__global__ __launch_bounds__(256) void attn_g_kernel(const __hip_bfloat16* __restrict__ qkv65,
                                                     const int* __restrict__ edges,
                                                     const float* __restrict__ dist,
                                                     const float* __restrict__ ds_l,
                                                     __hip_bfloat16* __restrict__ o) {
  int nq = blockIdx.x >> 2;
  int h0 = (blockIdx.x & 3) * (NHEAD / HSPLIT);
  int t = threadIdx.x;
  __shared__ float qs[16][65], ks[16][65], vs[16][65];
  __shared__ float sc[16][17], dl[16][17];
  __shared__ float sps_s[NHEAD];
  __shared__ int map_s[16];
  dl[t >> 4][t & 15] = dist[(size_t)nq * 256 + t];
  if (t < NHEAD) sps_s[t] = log1pf(expf(ds_l[t]));
  if (t < 16) {
    int diff = edges[nq * 16 + t] - edges[nq * 16];
    map_s[t] = min(max(diff, -POSCLIP), POSCLIP) + POSCLIP;
  }
  __syncthreads();
  int e = t >> 4, c4 = (t & 15) * 4;
  const ushort_t* qp = (const ushort_t*)qkv65;
  size_t ebase = (size_t)map_s[e] * 3072;
  for (int h = h0; h < h0 + NHEAD / HSPLIT; ++h) {
    const ushort_t* p = qp + ebase + h * 64 + c4;
    ushort4 qv = *(const ushort4*)p;
    ushort4 kv = *(const ushort4*)(p + 1024);
    ushort4 vv = *(const ushort4*)(p + 2048);
    qs[e][c4] = b2f(qv.x); qs[e][c4 + 1] = b2f(qv.y); qs[e][c4 + 2] = b2f(qv.z); qs[e][c4 + 3] = b2f(qv.w);
    ks[e][c4] = b2f(kv.x); ks[e][c4 + 1] = b2f(kv.y); ks[e][c4 + 2] = b2f(kv.z); ks[e][c4 + 3] = b2f(kv.w);
    vs[e][c4] = b2f(vv.x); vs[e][c4 + 1] = b2f(vv.y); vs[e][c4 + 2] = b2f(vv.z); vs[e][c4 + 3] = b2f(vv.w);
    __syncthreads();
    int ee = t >> 4, ff = t & 15;
    float s = 0.f;
#pragma unroll
    for (int d = 0; d < 64; ++d) s = fmaf(qs[ee][d], ks[ff][d], s);
    sc[ee][ff] = s * 0.125f - sps_s[h] * dl[ee][ff];
    __syncthreads();
    if (t < 16) {
      float m = -1e30f;
      for (int f = 0; f < 16; ++f) m = fmaxf(m, sc[t][f]);
      float sum = 0.f;
      for (int f = 0; f < 16; ++f) { float pe = expf(sc[t][f] - m); sc[t][f] = pe; sum += pe; }
      float inv = 1.f / sum;
      for (int f = 0; f < 16; ++f) sc[t][f] *= inv;
    }
    __syncthreads();
#pragma unroll
    for (int r = 0; r < 4; ++r) {
      int idx = t + 256 * r;
      int oe = idx >> 6, od = idx & 63;
      float acc = 0.f;
#pragma unroll
      for (int f = 0; f < 16; ++f) acc = fmaf(sc[oe][f], vs[f][od], acc);
      o[(size_t)(nq * 16 + oe) * 1024 + h * 64 + od] = __float2bfloat16(acc);
    }
    __syncthreads();
  }
}

// ---------------- attention layer-2: token-0 output only ----------------
__global__ __launch_bounds__(256) void attn2_kernel(const __hip_bfloat16* __restrict__ qkv,
                                                    const float* __restrict__ dist,
                                                    const float* __restrict__ ds_l,
                                                    __hip_bfloat16* __restrict__ o) {
  int nq = blockIdx.x;
  int t = threadIdx.x;
  __shared__ ushort_t ks[16 * 1032];
  __shared__ ushort_t vs[16 * 1032];
  __shared__ float qsf[1024];
  __shared__ float sc[16][17];
  __shared__ float pm[16], pi[16], sps_s[16], dl[16];
  const ushort_t* qp = (const ushort_t*)qkv;
  size_t base = (size_t)nq * 16 * 3072;
#pragma unroll
  for (int i = 0; i < 8; ++i) {
    int flat8 = (i * 256 + t) * 8;
    int e = flat8 >> 10, cc = flat8 & 1023;
    *(short8v*)(ks + e * 1032 + cc) = *(const short8v*)(qp + base + (size_t)e * 3072 + 1024 + cc);
    *(short8v*)(vs + e * 1032 + cc) = *(const short8v*)(qp + base + (size_t)e * 3072 + 2048 + cc);
  }
  {
    ushort4 qv = *(const ushort4*)(qp + base + t * 4);
    qsf[t * 4 + 0] = b2f(qv.x); qsf[t * 4 + 1] = b2f(qv.y);
    qsf[t * 4 + 2] = b2f(qv.z); qsf[t * 4 + 3] = b2f(qv.w);
  }
  if (t < 16) {
    sps_s[t] = log1pf(expf(ds_l[t]));
    dl[t] = dist[(size_t)nq * 256 + t];
  }
  __syncthreads();
  int h = t >> 4, f = t & 15;
  float s = 0.f;
#pragma unroll
  for (int dc = 0; dc < 8; ++dc) {
    short8v k8 = *(const short8v*)(ks + f * 1032 + h * 64 + dc * 8);
#pragma unroll
    for (int j = 0; j < 8; ++j)
      s = fmaf(qsf[h * 64 + dc * 8 + j], b2f((ushort_t)k8[j]), s);
  }
  sc[h][f] = s * 0.125f - sps_s[h] * dl[f];
  __syncthreads();
  if (t < 16) {
    float m = -1e30f;
    for (int ff = 0; ff < 16; ++ff) m = fmaxf(m, sc[t][ff]);
    float sum = 0.f;
    for (int ff = 0; ff < 16; ++ff) sum += expf(sc[t][ff] - m);
    pm[t] = m; pi[t] = 1.f / sum;
  }
  __syncthreads();
  float p = expf(sc[h][f] - pm[h]) * pi[h];
  __syncthreads();
  sc[h][f] = p;
  __syncthreads();
#pragma unroll
  for (int r = 0; r < 4; ++r) {
    int idx = t + 256 * r;
    int oh = idx >> 6, od = idx & 63;
    float acc = 0.f;
#pragma unroll
    for (int f2 = 0; f2 < 16; ++f2)
      acc = fmaf(sc[oh][f2], b2f(vs[f2 * 1032 + oh * 64 + od]), acc);
    o[(size_t)nq * 1024 + idx] = __float2bfloat16(acc);
  }
}

// ---------------- z0 gather: token-0 rows -> compact fp32 ----------------
__global__ __launch_bounds__(256) void z0copy_kernel(const float* __restrict__ z,
                                                     float* __restrict__ z0) {
  ((float4*)(z0 + (size_t)blockIdx.x * 1024))[threadIdx.x] =
      ((const float4*)(z + (size_t)blockIdx.x * 16384))[threadIdx.x];
}

// ---------------- final VAE head elementwise ----------------
__global__ __launch_bounds__(64) void final_kernel(const float* __restrict__ tmp,
                                                   const float* __restrict__ eps,
                                                   float* __restrict__ out) {
  int r = blockIdx.x; int j = threadIdx.x;
  float mu = tmp[r * 128 + j];
  float lv = fminf(tmp[r * 128 + 64 + j], 5.0f);
  float zs = mu + eps[r * 64 + j] * expf(0.5f * lv);
  out[r * 64 + j] = zs;
  out[262144 + r * 64 + j] = mu;
  out[524288 + r * 64 + j] = lv;
}

extern "C" void kernel_launch(void* const* d_in, const int* in_sizes, int n_in,
                              void* d_out, int out_size, void* d_ws, size_t ws_size,
                              hipStream_t stream) {
  (void)in_sizes; (void)n_in; (void)out_size;
  const float* coords = (const float*)d_in[0];
  const float* eps    = (const float*)d_in[1];
  const float* emb    = (const float*)d_in[2];
  const float* ln1_g  = (const float*)d_in[3];
  const float* ln1_b  = (const float*)d_in[4];
  const float* Wqkv   = (const float*)d_in[5];
  const float* bqkv   = (const float*)d_in[6];
  const float* dist_scale = (const float*)d_in[7];
  const float* Wo     = (const float*)d_in[8];
  const float* bo     = (const float*)d_in[9];
  const float* ln2_g  = (const float*)d_in[10];
  const float* ln2_b  = (const float*)d_in[11];
  const float* Wf1    = (const float*)d_in[12];
  const float* bf1    = (const float*)d_in[13];
  const float* Wf2    = (const float*)d_in[14];
  const float* bf2    = (const float*)d_in[15];
  const float* lnf_g  = (const float*)d_in[16];
  const float* lnf_b  = (const float*)d_in[17];
  const float* We1    = (const float*)d_in[18];
  const float* be1    = (const float*)d_in[19];
  const float* We2    = (const float*)d_in[20];
  const float* be2    = (const float*)d_in[21];

  char* ws = (char*)d_ws;
  int*   edges = (int*)ws;                                        // 256 KB
  float* dist  = (float*)(ws + (4ull << 20));                     // 4 MB
  __hip_bfloat16* hfinal = (__hip_bfloat16*)(ws + (8ull << 20));  // 8 MB
  __hip_bfloat16* gated  = (__hip_bfloat16*)(ws + (16ull << 20)); // 4 MB
  float* tmp   = (float*)(ws + (20ull << 20));                    // 2 MB
  __hip_bfloat16* o_all  = (__hip_bfloat16*)(ws + (22ull << 20)); // 8 MB
  float* z0_all = (float*)(ws + (30ull << 20));                   // 16 MB
  __hip_bfloat16* wbase = (__hip_bfloat16*)(ws + (46ull << 20));  // ~69.9 MB
  size_t woff = 0;
  __hip_bfloat16* wqkvT = wbase + woff; woff += 2ull * 3072 * 1024;
  __hip_bfloat16* woT   = wbase + woff; woff += 2ull * 1024 * 1024;
  __hip_bfloat16* wf1T  = wbase + woff; woff += 2ull * 8192 * 1024;
  __hip_bfloat16* wf2T  = wbase + woff; woff += 2ull * 1024 * 4096;
  __hip_bfloat16* we1T  = wbase + woff; woff += 1024ull * 1024;
  __hip_bfloat16* we2T  = wbase + woff; woff += 128ull * 512;
  __hip_bfloat16* h65   = wbase + woff; woff += 65ull * 1024;
  __hip_bfloat16* qkv65 = wbase + woff; woff += 65ull * 3072;

  const size_t FIXED = 116ull << 20;
  int CQ = 4096;
  while (CQ > 256 && FIXED + (size_t)CQ * 16 * 14336ull > ws_size) CQ >>= 1;
  if (FIXED + (size_t)CQ * 16 * 14336ull > ws_size) return;  // ws too small: leave poison
  size_t CT = (size_t)CQ * KNNK;
  char* creg = ws + FIXED;
  float* zbuf = (float*)creg;                                    // CT x 1024 fp32
  __hip_bfloat16* hbuf = (__hip_bfloat16*)(creg + CT * 4096);    // CT x 1024 bf16
  __hip_bfloat16* sh8  = (__hip_bfloat16*)(creg + CT * 6144);    // CT x 4096 bf16
  __hip_bfloat16* h2        = hbuf;   // post-loop alias
  __hip_bfloat16* gated_all = sh8;    // post-loop alias

  knn_kernel<<<NQ, 64, 0, stream>>>(coords, edges);
  dist_kernel<<<NQ, 256, 0, stream>>>(coords, edges, dist);
  for (int l = 0; l < NLAYER; ++l) {
    wconv_kernel<<<dim3(96, 32), 256, 0, stream>>>(Wqkv + (size_t)l * 1024 * 3072,
                                                   wqkvT + (size_t)l * 3072 * 1024, 1024, 3072);
    wconv_kernel<<<dim3(32, 32), 256, 0, stream>>>(Wo + (size_t)l * 1024 * 1024,
                                                   woT + (size_t)l * 1024 * 1024, 1024, 1024);
    wconv_kernel<<<dim3(256, 32), 256, 0, stream>>>(Wf1 + (size_t)l * 1024 * 8192,
                                                    wf1T + (size_t)l * 8192 * 1024, 1024, 8192);
    wconv_kernel<<<dim3(32, 128), 256, 0, stream>>>(Wf2 + (size_t)l * 4096 * 1024,
                                                    wf2T + (size_t)l * 1024 * 4096, 4096, 1024);
  }
  wconv_kernel<<<dim3(32, 32), 256, 0, stream>>>(We1, we1T, 1024, 1024);
  wconv_kernel<<<dim3(4, 16), 256, 0, stream>>>(We2, we2T, 512, 128);

  // layer-0 ln1+qkv collapse to the 65 distinct embedding rows
  ln_kernel<<<65, 256, 0, stream>>>(emb, DIM, ln1_g, ln1_b, h65);
  qkv65_kernel<<<65, 256, 0, stream>>>(h65, wqkvT, bqkv, qkv65);

  int NCH = NQ / CQ;
  int MT128 = (int)(CT / 128);
  for (int c = 0; c < NCH; ++c) {
    zinit_kernel<<<(int)CT, 256, 0, stream>>>(edges, emb, zbuf, (int)(c * CT));
    // ---- layer 0: attn directly from qkv65 (gathered), then wo/ln2/ff ----
    attn_g_kernel<<<CQ * HSPLIT, 256, 0, stream>>>(qkv65, edges + (size_t)c * CQ * 16,
                                                   dist + (size_t)c * CQ * 256,
                                                   dist_scale, hbuf);
    gemmT128_kernel<1><<<MT128 * 8, 256, 0, stream>>>(
        (const ushort_t*)hbuf, (const ushort_t*)woT, bo, zbuf, 1024, MT128, 1024, 8, 2);
    ln_kernel<<<(int)CT, 256, 0, stream>>>(zbuf, DIM, ln2_g, ln2_b, hbuf);
    gemmGW_kernel<<<MT128 * 32, 256, 0, stream>>>(
        (const ushort_t*)hbuf, (const ushort_t*)wf1T, bf1, sh8, 1024, MT128, 4096, 4096, 32, 4);
    gemmT128_kernel<1><<<MT128 * 8, 256, 0, stream>>>(
        (const ushort_t*)sh8, (const ushort_t*)wf2T, bf2, zbuf, 4096, MT128, 1024, 8, 2);
    // ---- layer 1 front: full ln1+qkv (K/V need all tokens); token-0 attn ----
    ln_kernel<<<(int)CT, 256, 0, stream>>>(zbuf, DIM, ln1_g + DIM, ln1_b + DIM, hbuf);
    gemmT128_kernel<0><<<MT128 * 24, 256, 0, stream>>>(
        (const ushort_t*)hbuf, (const ushort_t*)(wqkvT + 3072ull * 1024),
        bqkv + 3072, sh8, 1024, MT128, 3072, 24, 4);
    attn2_kernel<<<CQ, 256, 0, stream>>>(sh8, dist + (size_t)c * CQ * 256,
                                         dist_scale + NHEAD, o_all + (size_t)c * CQ * 1024);
    z0copy_kernel<<<CQ, 256, 0, stream>>>(zbuf, z0_all + (size_t)c * CQ * 1024);
  }

  // ---- layer 1 tail on compact token-0 rows: M = NQ = 4096 ----
  int MTQ = NQ / 128;  // 32
  gemmT128_kernel<1><<<MTQ * 8, 256, 0, stream>>>(
      (const ushort_t*)o_all, (const ushort_t*)(woT + 1024ull * 1024),
      bo + DIM, z0_all, 1024, MTQ, 1024, 8, 2);
  ln_kernel<<<NQ, 256, 0, stream>>>(z0_all, DIM, ln2_g + DIM, ln2_b + DIM, h2);
  gemmGW_kernel<<<MTQ * 32, 256, 0, stream>>>(
      (const ushort_t*)h2, (const ushort_t*)(wf1T + 8192ull * 1024),
      bf1 + 2 * DFFN, gated_all, 1024, MTQ, 4096, 4096, 32, 4);
  gemmT128_kernel<1><<<MTQ * 8, 256, 0, stream>>>(
      (const ushort_t*)gated_all, (const ushort_t*)(wf2T + 1024ull * 4096),
      bf2 + DIM, z0_all, 4096, MTQ, 1024, 8, 2);
  ln_kernel<<<NQ, 256, 0, stream>>>(z0_all, DIM, lnf_g, lnf_b, hfinal);

  mgemm_kernel<2><<<dim3(4, 32), 256, 0, stream>>>(hfinal, we1T, be1, gated, 1024, 512, 512);
  mgemm_kernel<3><<<dim3(1, 32), 256, 0, stream>>>(gated, we2T, be2, tmp, 512, 0, 128);
  final_kernel<<<NQ, 64, 0, stream>>>(tmp, eps, (float*)d_out);
}

// Round 14
// 3536.297 us; speedup vs baseline: 1.8456x; 1.0540x over previous
//
#include <hip/hip_runtime.h>
#include <hip/hip_bf16.h>
#include <math.h>

#define LLEN 512
#define KNNK 16
#define DIM 1024
#define NHEAD 16
#define NLAYER 2
#define DFFN 4096
#define POSCLIP 32
#define NQ 4096
#define NTOK 65536
#define HSPLIT 4

typedef __attribute__((ext_vector_type(8))) short short8v;
typedef __attribute__((ext_vector_type(4))) float f32x4;
typedef unsigned short ushort_t;

__device__ __forceinline__ float b2f(ushort_t u) {
  union { unsigned u; float f; } x; x.u = ((unsigned)u) << 16; return x.f;
}

// 2D XCD-blocked tile mapping: B-slice L2-resident, A fetched ~once/XCD.
__device__ __forceinline__ void xcd_map(int bid, int Mtiles, int Ntiles, int XN,
                                        int& mt, int& nt) {
  int nt_per = Ntiles / XN;
  int mt_per = (Mtiles * XN) >> 3;
  int xcd = bid & 7, i = bid >> 3;
  int xn = xcd % XN, xm = xcd / XN;
  int ntl = i % nt_per, mtl = i / nt_per;
  mt = xm * mt_per + mtl;
  nt = xn * nt_per + ntl;
}

#define GLD16(gp, lp)                                                          \
  __builtin_amdgcn_global_load_lds(                                            \
      (const __attribute__((address_space(1))) void*)(gp),                     \
      (__attribute__((address_space(3))) void*)(lp), 16, 0, 0)

// ---------------- KNN: one wave per query ----------------
__global__ __launch_bounds__(64) void knn_kernel(const float* __restrict__ coords,
                                                 int* __restrict__ edges) {
  int n = blockIdx.x;
  int b = n / LLEN, i = n % LLEN;
  int lane = threadIdx.x;
  const float* cb = coords + (size_t)b * LLEN * 9;
  float xi = cb[i * 9 + 3], yi = cb[i * 9 + 4], zi = cb[i * 9 + 5];
  float d[8];
#pragma unroll
  for (int r = 0; r < 8; ++r) {
    int j = r * 64 + lane;
    float dx = xi - cb[j * 9 + 3];
    float dy = yi - cb[j * 9 + 4];
    float dz = zi - cb[j * 9 + 5];
    d[r] = dx * dx + dy * dy + dz * dz;
  }
  for (int s = 0; s < KNNK; ++s) {
    float bv = INFINITY; int bi = 1 << 30;
#pragma unroll
    for (int r = 0; r < 8; ++r) {
      int j = r * 64 + lane;
      if (d[r] < bv || (d[r] == bv && j < bi)) { bv = d[r]; bi = j; }
    }
#pragma unroll
    for (int off = 32; off > 0; off >>= 1) {
      float ov = __shfl_xor(bv, off);
      int   oi = __shfl_xor(bi, off);
      if (ov < bv || (ov == bv && oi < bi)) { bv = ov; bi = oi; }
    }
    if (lane == 0) edges[n * KNNK + s] = bi;
    if ((bi & 63) == lane) d[bi >> 6] = INFINITY;
  }
}

// ---------------- dist: 16x16 per query ----------------
__global__ __launch_bounds__(256) void dist_kernel(const float* __restrict__ coords,
                                                   const int* __restrict__ edges,
                                                   float* __restrict__ dist) {
  int n = blockIdx.x; int b = n / LLEN;
  __shared__ float tx[16], ty[16], tz[16];
  int t = threadIdx.x;
  const float* cb = coords + (size_t)b * LLEN * 9;
  if (t < 16) {
    int j = edges[n * KNNK + t];
    tx[t] = cb[j * 9 + 3]; ty[t] = cb[j * 9 + 4]; tz[t] = cb[j * 9 + 5];
  }
  __syncthreads();
  int e = t >> 4, f = t & 15;
  float dx = tx[e] - tx[f], dy = ty[e] - ty[f], dz = tz[e] - tz[f];
  dist[(size_t)n * 256 + t] = sqrtf(dx * dx + dy * dy + dz * dz + 1e-8f);
}

// ---------------- z init (chunked) ----------------
__global__ __launch_bounds__(256) void zinit_kernel(const int* __restrict__ edges,
                                                    const float* __restrict__ emb,
                                                    float* __restrict__ zbuf, int tok0) {
  int tl = blockIdx.x;
  int tok = tok0 + tl;
  int n = tok >> 4;
  int diff = edges[tok] - edges[n << 4];
  int idx = min(max(diff, -POSCLIP), POSCLIP) + POSCLIP;
  ((float4*)(zbuf + (size_t)tl * DIM))[threadIdx.x] =
      ((const float4*)(emb + (size_t)idx * DIM))[threadIdx.x];
}

// ---------------- LayerNorm fp32 in -> bf16 out ----------------
__global__ __launch_bounds__(256) void ln_kernel(const float* __restrict__ X, int stride,
                                                 const float* __restrict__ g,
                                                 const float* __restrict__ bta,
                                                 __hip_bfloat16* __restrict__ Y) {
  int row = blockIdx.x; int t = threadIdx.x;
  const float4* xr = (const float4*)(X + (size_t)row * stride);
  float4 v = xr[t];
  float s = v.x + v.y + v.z + v.w;
  __shared__ float red[8];
  for (int off = 32; off; off >>= 1) s += __shfl_down(s, off);
  int wid = t >> 6;
  if ((t & 63) == 0) red[wid] = s;
  __syncthreads();
  if (t == 0) red[4] = (red[0] + red[1] + red[2] + red[3]) * (1.0f / DIM);
  __syncthreads();
  float mean = red[4];
  float d0 = v.x - mean, d1 = v.y - mean, d2 = v.z - mean, d3 = v.w - mean;
  float s2 = d0 * d0 + d1 * d1 + d2 * d2 + d3 * d3;
  for (int off = 32; off; off >>= 1) s2 += __shfl_down(s2, off);
  if ((t & 63) == 0) red[wid] = s2;
  __syncthreads();
  if (t == 0) red[5] = rsqrtf((red[0] + red[1] + red[2] + red[3]) * (1.0f / DIM) + 1e-5f);
  __syncthreads();
  float rstd = red[5];
  float4 gv = ((const float4*)g)[t], bv = ((const float4*)bta)[t];
  size_t o = (size_t)row * DIM + t * 4;
  Y[o + 0] = __float2bfloat16(d0 * rstd * gv.x + bv.x);
  Y[o + 1] = __float2bfloat16(d1 * rstd * gv.y + bv.y);
  Y[o + 2] = __float2bfloat16(d2 * rstd * gv.z + bv.z);
  Y[o + 3] = __float2bfloat16(d3 * rstd * gv.w + bv.w);
}

// ---------------- weight fp32 K x N -> bf16 N x K ----------------
__global__ __launch_bounds__(256) void wconv_kernel(const float* __restrict__ W,
                                                    __hip_bfloat16* __restrict__ Wt,
                                                    int K, int N) {
  __shared__ float tile[32][33];
  int n0 = blockIdx.x * 32, k0 = blockIdx.y * 32;
  int c = threadIdx.x & 31, r = threadIdx.x >> 5;
#pragma unroll
  for (int i = 0; i < 4; ++i)
    tile[r + i * 8][c] = W[(size_t)(k0 + r + i * 8) * N + n0 + c];
  __syncthreads();
#pragma unroll
  for (int i = 0; i < 4; ++i)
    Wt[(size_t)(n0 + r + i * 8) * K + k0 + c] = __float2bfloat16(tile[c][r + i * 8]);
}

// BK=32 swizzle: LDS chunk c holds global k-chunk c ^ ((row>>1)&3);
// reads use kg ^ ((fr>>1)&3). <=2-way (free).

// ============ gemmT128: BM=128, BN=128, BK=32, 256 thr (4 waves 2x2),
// 3-slot ring (48KB LDS). MODE 0: bf16 C = x  MODE 1: fp32 C += x
template <int MODE>
__global__ __launch_bounds__(256, 3) void gemmT128_kernel(
    const ushort_t* __restrict__ A,
    const ushort_t* __restrict__ Wt,
    const float* __restrict__ bias,
    void* __restrict__ Cout,
    int K, int Mtiles, int Cstride, int Ntiles, int XN) {
  __shared__ ushort_t Alds[3][4096];
  __shared__ ushort_t Blds[3][4096];
  int t = threadIdx.x;
  int w = t >> 6, lane = t & 63;
  int wr = w >> 1, wc = w & 1;
  int fr = lane & 15, kg = lane >> 4;

  int mt, nt;
  xcd_map(blockIdx.x, Mtiles, Ntiles, XN, mt, nt);
  size_t m0 = (size_t)mt * 128, n0 = (size_t)nt * 128;

  int stg_r = w * 16 + (lane >> 2);
  int stg_c = (((lane & 3) ^ ((lane >> 3) & 3)) << 3);
  const ushort_t* gAl = A + (m0 + stg_r) * (size_t)K + stg_c;
  const ushort_t* gBl = Wt + (n0 + stg_r) * (size_t)K + stg_c;
  int lds_w = w * 512;

#define SAt(slot, kcol, j) GLD16(gAl + (size_t)(j) * 64 * K + (kcol), Alds[slot] + (j) * 2048 + lds_w)
#define SBt(slot, kcol, j) GLD16(gBl + (size_t)(j) * 64 * K + (kcol), Blds[slot] + (j) * 2048 + lds_w)

  f32x4 acc[4][4];
#pragma unroll
  for (int i = 0; i < 4; ++i)
#pragma unroll
    for (int j = 0; j < 4; ++j) acc[i][j] = (f32x4){0.f, 0.f, 0.f, 0.f};

  int usw = ((kg ^ ((fr >> 1) & 3)) << 3);

  SAt(0, 0, 0); SAt(0, 0, 1); SBt(0, 0, 0); SBt(0, 0, 1);
  SAt(1, 32, 0); SAt(1, 32, 1); SBt(1, 32, 0); SBt(1, 32, 1);
  asm volatile("s_waitcnt vmcnt(4)" ::: "memory");
  __builtin_amdgcn_s_barrier();

  short8v af[4], bf[4];
  int NT = K >> 5;
  int sl = 0, st = 2;
  for (int ti = 0; ti < NT; ++ti) {
    int kS = (ti + 2) << 5;
    int stg = (ti + 2) < NT;
    const ushort_t* sA = Alds[sl];
    const ushort_t* sB = Blds[sl];
#pragma unroll
    for (int mi = 0; mi < 4; ++mi)
      af[mi] = *(const short8v*)(sA + (wr * 64 + mi * 16 + fr) * 32 + usw);
#pragma unroll
    for (int ni = 0; ni < 4; ++ni)
      bf[ni] = *(const short8v*)(sB + (wc * 64 + ni * 16 + fr) * 32 + usw);
    if (stg) { SAt(st, kS, 0); SAt(st, kS, 1); SBt(st, kS, 0); SBt(st, kS, 1); }
    asm volatile("s_waitcnt lgkmcnt(0)" ::: "memory");
    __builtin_amdgcn_sched_barrier(0);
    __builtin_amdgcn_s_setprio(1);
#pragma unroll
    for (int mi = 0; mi < 4; ++mi)
#pragma unroll
      for (int ni = 0; ni < 4; ++ni)
        acc[mi][ni] = __builtin_amdgcn_mfma_f32_16x16x32_bf16(af[mi], bf[ni], acc[mi][ni], 0, 0, 0);
    __builtin_amdgcn_s_setprio(0);
    if (stg) { asm volatile("s_waitcnt vmcnt(4)" ::: "memory"); }
    else if (ti + 1 < NT) { asm volatile("s_waitcnt vmcnt(0)" ::: "memory"); }
    __builtin_amdgcn_s_barrier();
    sl = (sl == 2) ? 0 : sl + 1;
    st = (st == 2) ? 0 : st + 1;
  }
#undef SAt
#undef SBt

  int er = wr * 64 + (lane >> 4) * 4;
  int ec = wc * 64 + fr;
#pragma unroll
  for (int mi = 0; mi < 4; ++mi) {
#pragma unroll
    for (int ni = 0; ni < 4; ++ni) {
      int col = (int)n0 + ec + ni * 16;
      float bs = bias[col];
#pragma unroll
      for (int j = 0; j < 4; ++j) {
        size_t row = m0 + er + mi * 16 + j;
        size_t cidx = row * (size_t)Cstride + col;
        float x = acc[mi][ni][j] + bs;
        if constexpr (MODE == 0) {
          ((__hip_bfloat16*)Cout)[cidx] = __float2bfloat16(x);
        } else {
          ((float*)Cout)[cidx] += x;
        }
      }
    }
  }
}

// ============ gemmGW: fused gated ff1, 4 waves (2Mx2N), per-wave 64x64 of
// BOTH gated outputs. BM=128, BN=128 dual, BK=32, 3-slot ring 72KB, 2 blk/CU.
__global__ __launch_bounds__(256, 2) void gemmGW_kernel(
    const ushort_t* __restrict__ A,
    const ushort_t* __restrict__ Wt,
    const float* __restrict__ bias,
    __hip_bfloat16* __restrict__ Cout,
    int K, int Mtiles, int Cstride, int NhRows, int Ntiles, int XN) {
  __shared__ ushort_t Alds[3][4096];
  __shared__ ushort_t B1lds[3][4096];
  __shared__ ushort_t B2lds[3][4096];
  int t = threadIdx.x;
  int w = t >> 6, lane = t & 63;
  int wr = w >> 1, wc = w & 1;
  int fr = lane & 15, kg = lane >> 4;

  int mt, nt;
  xcd_map(blockIdx.x, Mtiles, Ntiles, XN, mt, nt);
  size_t m0 = (size_t)mt * 128, n0 = (size_t)nt * 128;

  int stg_r = w * 16 + (lane >> 2);
  int stg_c = (((lane & 3) ^ ((lane >> 3) & 3)) << 3);
  const ushort_t* gAl = A + (m0 + stg_r) * (size_t)K + stg_c;
  const ushort_t* gB1 = Wt + (n0 + stg_r) * (size_t)K + stg_c;
  const ushort_t* gB2 = Wt + ((size_t)NhRows + n0 + stg_r) * (size_t)K + stg_c;
  int lds_w = w * 512;

#define SAg(slot, kcol, j) GLD16(gAl + (size_t)(j) * 64 * K + (kcol), Alds[slot] + (j) * 2048 + lds_w)
#define SB1g(slot, kcol, j) GLD16(gB1 + (size_t)(j) * 64 * K + (kcol), B1lds[slot] + (j) * 2048 + lds_w)
#define SB2g(slot, kcol, j) GLD16(gB2 + (size_t)(j) * 64 * K + (kcol), B2lds[slot] + (j) * 2048 + lds_w)

  f32x4 acc1[4][4], acc2[4][4];
#pragma unroll
  for (int i = 0; i < 4; ++i)
#pragma unroll
    for (int j = 0; j < 4; ++j) {
      acc1[i][j] = (f32x4){0.f, 0.f, 0.f, 0.f};
      acc2[i][j] = (f32x4){0.f, 0.f, 0.f, 0.f};
    }

  int usw = ((kg ^ ((fr >> 1) & 3)) << 3);

  SAg(0, 0, 0); SAg(0, 0, 1); SB1g(0, 0, 0); SB1g(0, 0, 1); SB2g(0, 0, 0); SB2g(0, 0, 1);
  SAg(1, 32, 0); SAg(1, 32, 1); SB1g(1, 32, 0); SB1g(1, 32, 1); SB2g(1, 32, 0); SB2g(1, 32, 1);
  asm volatile("s_waitcnt vmcnt(6)" ::: "memory");
  __builtin_amdgcn_s_barrier();

  short8v af[4], bf1[4], bf2[4];
  int NT = K >> 5;
  int sl = 0, st = 2;
  for (int ti = 0; ti < NT; ++ti) {
    int kS = (ti + 2) << 5;
    int stg = (ti + 2) < NT;
    const ushort_t* sA = Alds[sl];
    const ushort_t* sB1 = B1lds[sl];
    const ushort_t* sB2 = B2lds[sl];
#pragma unroll
    for (int mi = 0; mi < 4; ++mi)
      af[mi] = *(const short8v*)(sA + (wr * 64 + mi * 16 + fr) * 32 + usw);
#pragma unroll
    for (int ni = 0; ni < 4; ++ni) {
      bf1[ni] = *(const short8v*)(sB1 + (wc * 64 + ni * 16 + fr) * 32 + usw);
      bf2[ni] = *(const short8v*)(sB2 + (wc * 64 + ni * 16 + fr) * 32 + usw);
    }
    if (stg) {
      SAg(st, kS, 0); SAg(st, kS, 1);
      SB1g(st, kS, 0); SB1g(st, kS, 1);
      SB2g(st, kS, 0); SB2g(st, kS, 1);
    }
    asm volatile("s_waitcnt lgkmcnt(0)" ::: "memory");
    __builtin_amdgcn_sched_barrier(0);
    __builtin_amdgcn_s_setprio(1);
#pragma unroll
    for (int mi = 0; mi < 4; ++mi)
#pragma unroll
      for (int ni = 0; ni < 4; ++ni) {
        acc1[mi][ni] = __builtin_amdgcn_mfma_f32_16x16x32_bf16(af[mi], bf1[ni], acc1[mi][ni], 0, 0, 0);
        acc2[mi][ni] = __builtin_amdgcn_mfma_f32_16x16x32_bf16(af[mi], bf2[ni], acc2[mi][ni], 0, 0, 0);
      }
    __builtin_amdgcn_s_setprio(0);
    if (stg) { asm volatile("s_waitcnt vmcnt(6)" ::: "memory"); }
    else if (ti + 1 < NT) { asm volatile("s_waitcnt vmcnt(0)" ::: "memory"); }
    __builtin_amdgcn_s_barrier();
    sl = (sl == 2) ? 0 : sl + 1;
    st = (st == 2) ? 0 : st + 1;
  }
#undef SAg
#undef SB1g
#undef SB2g

  int er = wr * 64 + (lane >> 4) * 4;
  int ec = wc * 64 + fr;
#pragma unroll
  for (int mi = 0; mi < 4; ++mi) {
#pragma unroll
    for (int ni = 0; ni < 4; ++ni) {
      int col = (int)n0 + ec + ni * 16;
      float b1v = bias[col];
      float b2v = bias[NhRows + col];
#pragma unroll
      for (int j = 0; j < 4; ++j) {
        size_t row = m0 + er + mi * 16 + j;
        float x1 = acc1[mi][ni][j] + b1v;
        float x2 = acc2[mi][ni][j] + b2v;
        float sg = x1 / (1.f + expf(-x1));
        Cout[row * (size_t)Cstride + col] = __float2bfloat16(sg * x2);
      }
    }
  }
}

// ---------------- small 128x128 GEMM (final head only) ----------------
template <int MODE>
__global__ __launch_bounds__(256) void mgemm_kernel(
    const __hip_bfloat16* __restrict__ A,
    const __hip_bfloat16* __restrict__ Wt,
    const float* __restrict__ bias,
    void* __restrict__ Cout,
    int K, int Nh, int Cstride) {
  __shared__ ushort_t As[4 * 128 * 8];
  __shared__ ushort_t Bs[4 * 128 * 8];
  __shared__ ushort_t Bs2[(MODE == 2) ? 4 * 128 * 8 : 8];
  int t = threadIdx.x;
  int w = t >> 6, lane = t & 63;
  int wr = w >> 1, wc = w & 1;
  size_t m0 = (size_t)blockIdx.y * 128;
  size_t n0 = (size_t)blockIdx.x * 128;
  int cell0 = w * 64 + lane;
  int cell1 = 256 + w * 64 + lane;
  int kg0 = cell0 >> 7, rw0 = cell0 & 127;
  int kg1 = cell1 >> 7, rw1 = cell1 & 127;
  const ushort_t* gA = (const ushort_t*)A;
  const ushort_t* gB = (const ushort_t*)Wt;
  const ushort_t* gB2 = (const ushort_t*)(Wt + (size_t)Nh * K);
  size_t a0 = (m0 + rw0) * (size_t)K + kg0 * 8;
  size_t a1 = (m0 + rw1) * (size_t)K + kg1 * 8;
  size_t b0 = (n0 + rw0) * (size_t)K + kg0 * 8;
  size_t b1 = (n0 + rw1) * (size_t)K + kg1 * 8;
  int ldso0 = w * 1024;
  int ldso1 = 4096 + w * 1024;
  f32x4 acc[4][4];
  f32x4 acc2[4][4];
#pragma unroll
  for (int i = 0; i < 4; ++i)
#pragma unroll
    for (int j = 0; j < 4; ++j) {
      acc[i][j] = (f32x4){0.f, 0.f, 0.f, 0.f};
      acc2[i][j] = (f32x4){0.f, 0.f, 0.f, 0.f};
    }
  int fr = lane & 15, kg = lane >> 4;
  int abase = (kg * 128 + wr * 64 + fr) * 16;
  int bbase = (kg * 128 + wc * 64 + fr) * 16;
  for (int k0 = 0; k0 < K; k0 += 32) {
    __syncthreads();
    GLD16(gA + a0 + k0, (char*)As + ldso0);
    GLD16(gA + a1 + k0, (char*)As + ldso1);
    GLD16(gB + b0 + k0, (char*)Bs + ldso0);
    GLD16(gB + b1 + k0, (char*)Bs + ldso1);
    if constexpr (MODE == 2) {
      GLD16(gB2 + b0 + k0, (char*)Bs2 + ldso0);
      GLD16(gB2 + b1 + k0, (char*)Bs2 + ldso1);
    }
    __syncthreads();
    short8v a[4], b[4];
#pragma unroll
    for (int mi = 0; mi < 4; ++mi)
      a[mi] = *(const short8v*)((const char*)As + abase + mi * 256);
#pragma unroll
    for (int ni = 0; ni < 4; ++ni)
      b[ni] = *(const short8v*)((const char*)Bs + bbase + ni * 256);
#pragma unroll
    for (int mi = 0; mi < 4; ++mi)
#pragma unroll
      for (int ni = 0; ni < 4; ++ni)
        acc[mi][ni] = __builtin_amdgcn_mfma_f32_16x16x32_bf16(a[mi], b[ni], acc[mi][ni], 0, 0, 0);
    if constexpr (MODE == 2) {
#pragma unroll
      for (int ni = 0; ni < 4; ++ni)
        b[ni] = *(const short8v*)((const char*)Bs2 + bbase + ni * 256);
#pragma unroll
      for (int mi = 0; mi < 4; ++mi)
#pragma unroll
        for (int ni = 0; ni < 4; ++ni)
          acc2[mi][ni] = __builtin_amdgcn_mfma_f32_16x16x32_bf16(a[mi], b[ni], acc2[mi][ni], 0, 0, 0);
    }
  }
  int er = wr * 64 + (lane >> 4) * 4;
  int ec = wc * 64 + fr;
#pragma unroll
  for (int mi = 0; mi < 4; ++mi) {
#pragma unroll
    for (int ni = 0; ni < 4; ++ni) {
      int col = (int)n0 + ec + ni * 16;
      float bs1 = bias[col];
#pragma unroll
      for (int j = 0; j < 4; ++j) {
        size_t row = m0 + er + mi * 16 + j;
        size_t cidx = row * (size_t)Cstride + col;
        float x = acc[mi][ni][j] + bs1;
        if constexpr (MODE == 3) {
          ((float*)Cout)[cidx] = x;
        } else {
          float x2 = acc2[mi][ni][j] + bias[Nh + col];
          float sig = 1.f / (1.f + expf(-x));
          ((__hip_bfloat16*)Cout)[cidx] = __float2bfloat16(x * sig * x2);
        }
      }
    }
  }
}

// ---------------- attention layer-0: gather q/k/v from qkv65 via edges map ----
__global__ __launch_bounds__(256) void attn_g_kernel(const __hip_bfloat16* __restrict__ qkv65,
                                                     const int* __restrict__ edges,
                                                     const float* __restrict__ dist,
                                                     const float* __restrict__ ds_l,
                                                     __hip_bfloat16* __restrict__ o) {
  int nq = blockIdx.x >> 2;
  int h0 = (blockIdx.x & 3) * (NHEAD / HSPLIT);
  int t = threadIdx.x;
  __shared__ float qs[16][65], ks[16][65], vs[16][65];
  __shared__ float sc[16][17], dl[16][17];
  __shared__ float sps_s[NHEAD];
  __shared__ int map_s[16];
  dl[t >> 4][t & 15] = dist[(size_t)nq * 256 + t];
  if (t < NHEAD) sps_s[t] = log1pf(expf(ds_l[t]));
  if (t < 16) {
    int diff = edges[nq * 16 + t] - edges[nq * 16];
    map_s[t] = min(max(diff, -POSCLIP), POSCLIP) + POSCLIP;
  }
  __syncthreads();
  int e = t >> 4, c4 = (t & 15) * 4;
  const ushort_t* qp = (const ushort_t*)qkv65;
  size_t ebase = (size_t)map_s[e] * 3072;
  for (int h = h0; h < h0 + NHEAD / HSPLIT; ++h) {
    const ushort_t* p = qp + ebase + h * 64 + c4;
    ushort4 qv = *(const ushort4*)p;
    ushort4 kv = *(const ushort4*)(p + 1024);
    ushort4 vv = *(const ushort4*)(p + 2048);
    qs[e][c4] = b2f(qv.x); qs[e][c4 + 1] = b2f(qv.y); qs[e][c4 + 2] = b2f(qv.z); qs[e][c4 + 3] = b2f(qv.w);
    ks[e][c4] = b2f(kv.x); ks[e][c4 + 1] = b2f(kv.y); ks[e][c4 + 2] = b2f(kv.z); ks[e][c4 + 3] = b2f(kv.w);
    vs[e][c4] = b2f(vv.x); vs[e][c4 + 1] = b2f(vv.y); vs[e][c4 + 2] = b2f(vv.z); vs[e][c4 + 3] = b2f(vv.w);
    __syncthreads();
    int ee = t >> 4, ff = t & 15;
    float s = 0.f;
#pragma unroll
    for (int d = 0; d < 64; ++d) s = fmaf(qs[ee][d], ks[ff][d], s);
    sc[ee][ff] = s * 0.125f - sps_s[h] * dl[ee][ff];
    __syncthreads();
    if (t < 16) {
      float m = -1e30f;
      for (int f = 0; f < 16; ++f) m = fmaxf(m, sc[t][f]);
      float sum = 0.f;
      for (int f = 0; f < 16; ++f) { float pe = expf(sc[t][f] - m); sc[t][f] = pe; sum += pe; }
      float inv = 1.f / sum;
      for (int f = 0; f < 16; ++f) sc[t][f] *= inv;
    }
    __syncthreads();
#pragma unroll
    for (int r = 0; r < 4; ++r) {
      int idx = t + 256 * r;
      int oe = idx >> 6, od = idx & 63;
      float acc = 0.f;
#pragma unroll
      for (int f = 0; f < 16; ++f) acc = fmaf(sc[oe][f], vs[f][od], acc);
      o[(size_t)(nq * 16 + oe) * 1024 + h * 64 + od] = __float2bfloat16(acc);
    }
    __syncthreads();
  }
}

// ---------------- attention layer-2: token-0 output only ----------------
__global__ __launch_bounds__(256) void attn2_kernel(const __hip_bfloat16* __restrict__ qkv,
                                                    const float* __restrict__ dist,
                                                    const float* __restrict__ ds_l,
                                                    __hip_bfloat16* __restrict__ o) {
  int nq = blockIdx.x;
  int t = threadIdx.x;
  __shared__ ushort_t ks[16 * 1032];
  __shared__ ushort_t vs[16 * 1032];
  __shared__ float qsf[1024];
  __shared__ float sc[16][17];
  __shared__ float pm[16], pi[16], sps_s[16], dl[16];
  const ushort_t* qp = (const ushort_t*)qkv;
  size_t base = (size_t)nq * 16 * 3072;
#pragma unroll
  for (int i = 0; i < 8; ++i) {
    int flat8 = (i * 256 + t) * 8;
    int e = flat8 >> 10, cc = flat8 & 1023;
    *(short8v*)(ks + e * 1032 + cc) = *(const short8v*)(qp + base + (size_t)e * 3072 + 1024 + cc);
    *(short8v*)(vs + e * 1032 + cc) = *(const short8v*)(qp + base + (size_t)e * 3072 + 2048 + cc);
  }
  {
    ushort4 qv = *(const ushort4*)(qp + base + t * 4);
    qsf[t * 4 + 0] = b2f(qv.x); qsf[t * 4 + 1] = b2f(qv.y);
    qsf[t * 4 + 2] = b2f(qv.z); qsf[t * 4 + 3] = b2f(qv.w);
  }
  if (t < 16) {
    sps_s[t] = log1pf(expf(ds_l[t]));
    dl[t] = dist[(size_t)nq * 256 + t];
  }
  __syncthreads();
  int h = t >> 4, f = t & 15;
  float s = 0.f;
#pragma unroll
  for (int dc = 0; dc < 8; ++dc) {
    short8v k8 = *(const short8v*)(ks + f * 1032 + h * 64 + dc * 8);
#pragma unroll
    for (int j = 0; j < 8; ++j)
      s = fmaf(qsf[h * 64 + dc * 8 + j], b2f((ushort_t)k8[j]), s);
  }
  sc[h][f] = s * 0.125f - sps_s[h] * dl[f];
  __syncthreads();
  if (t < 16) {
    float m = -1e30f;
    for (int ff = 0; ff < 16; ++ff) m = fmaxf(m, sc[t][ff]);
    float sum = 0.f;
    for (int ff = 0; ff < 16; ++ff) sum += expf(sc[t][ff] - m);
    pm[t] = m; pi[t] = 1.f / sum;
  }
  __syncthreads();
  float p = expf(sc[h][f] - pm[h]) * pi[h];
  __syncthreads();
  sc[h][f] = p;
  __syncthreads();
#pragma unroll
  for (int r = 0; r < 4; ++r) {
    int idx = t + 256 * r;
    int oh = idx >> 6, od = idx & 63;
    float acc = 0.f;
#pragma unroll
    for (int f2 = 0; f2 < 16; ++f2)
      acc = fmaf(sc[oh][f2], b2f(vs[f2 * 1032 + oh * 64 + od]), acc);
    o[(size_t)nq * 1024 + idx] = __float2bfloat16(acc);
  }
}

// ---------------- z0 gather: token-0 rows -> compact fp32 ----------------
__global__ __launch_bounds__(256) void z0copy_kernel(const float* __restrict__ z,
                                                     float* __restrict__ z0) {
  ((float4*)(z0 + (size_t)blockIdx.x * 1024))[threadIdx.x] =
      ((const float4*)(z + (size_t)blockIdx.x * 16384))[threadIdx.x];
}

// ---------------- final VAE head elementwise ----------------
__global__ __launch_bounds__(64) void final_kernel(const float* __restrict__ tmp,
                                                   const float* __restrict__ eps,
                                                   float* __restrict__ out) {
  int r = blockIdx.x; int j = threadIdx.x;
  float mu = tmp[r * 128 + j];
  float lv = fminf(tmp[r * 128 + 64 + j], 5.0f);
  float zs = mu + eps[r * 64 + j] * expf(0.5f * lv);
  out[r * 64 + j] = zs;
  out[262144 + r * 64 + j] = mu;
  out[524288 + r * 64 + j] = lv;
}

extern "C" void kernel_launch(void* const* d_in, const int* in_sizes, int n_in,
                              void* d_out, int out_size, void* d_ws, size_t ws_size,
                              hipStream_t stream) {
  (void)in_sizes; (void)n_in; (void)out_size;
  const float* coords = (const float*)d_in[0];
  const float* eps    = (const float*)d_in[1];
  const float* emb    = (const float*)d_in[2];
  const float* ln1_g  = (const float*)d_in[3];
  const float* ln1_b  = (const float*)d_in[4];
  const float* Wqkv   = (const float*)d_in[5];
  const float* bqkv   = (const float*)d_in[6];
  const float* dist_scale = (const float*)d_in[7];
  const float* Wo     = (const float*)d_in[8];
  const float* bo     = (const float*)d_in[9];
  const float* ln2_g  = (const float*)d_in[10];
  const float* ln2_b  = (const float*)d_in[11];
  const float* Wf1    = (const float*)d_in[12];
  const float* bf1    = (const float*)d_in[13];
  const float* Wf2    = (const float*)d_in[14];
  const float* bf2    = (const float*)d_in[15];
  const float* lnf_g  = (const float*)d_in[16];
  const float* lnf_b  = (const float*)d_in[17];
  const float* We1    = (const float*)d_in[18];
  const float* be1    = (const float*)d_in[19];
  const float* We2    = (const float*)d_in[20];
  const float* be2    = (const float*)d_in[21];

  char* ws = (char*)d_ws;
  int*   edges = (int*)ws;                                        // 256 KB
  float* dist  = (float*)(ws + (4ull << 20));                     // 4 MB
  __hip_bfloat16* hfinal = (__hip_bfloat16*)(ws + (8ull << 20));  // 8 MB
  __hip_bfloat16* gated  = (__hip_bfloat16*)(ws + (16ull << 20)); // 4 MB
  float* tmp   = (float*)(ws + (20ull << 20));                    // 2 MB
  __hip_bfloat16* o_all  = (__hip_bfloat16*)(ws + (22ull << 20)); // 8 MB
  float* z0_all = (float*)(ws + (30ull << 20));                   // 16 MB
  __hip_bfloat16* wbase = (__hip_bfloat16*)(ws + (46ull << 20));  // ~70 MB
  size_t woff = 0;
  __hip_bfloat16* wqkvT = wbase + woff; woff += 2ull * 3072 * 1024;
  __hip_bfloat16* woT   = wbase + woff; woff += 2ull * 1024 * 1024;
  __hip_bfloat16* wf1T  = wbase + woff; woff += 2ull * 8192 * 1024;
  __hip_bfloat16* wf2T  = wbase + woff; woff += 2ull * 1024 * 4096;
  __hip_bfloat16* we1T  = wbase + woff; woff += 1024ull * 1024;
  __hip_bfloat16* we2T  = wbase + woff; woff += 128ull * 512;
  __hip_bfloat16* h65   = wbase + woff; woff += 128ull * 1024;   // padded to 128 rows
  __hip_bfloat16* qkv65 = wbase + woff; woff += 128ull * 3072;   // padded to 128 rows

  const size_t FIXED = 116ull << 20;
  int CQ = 4096;
  while (CQ > 256 && FIXED + (size_t)CQ * 16 * 14336ull > ws_size) CQ >>= 1;
  if (FIXED + (size_t)CQ * 16 * 14336ull > ws_size) return;  // ws too small: leave poison
  size_t CT = (size_t)CQ * KNNK;
  char* creg = ws + FIXED;
  float* zbuf = (float*)creg;                                    // CT x 1024 fp32
  __hip_bfloat16* hbuf = (__hip_bfloat16*)(creg + CT * 4096);    // CT x 1024 bf16
  __hip_bfloat16* sh8  = (__hip_bfloat16*)(creg + CT * 6144);    // CT x 4096 bf16
  __hip_bfloat16* h2        = hbuf;   // post-loop alias
  __hip_bfloat16* gated_all = sh8;    // post-loop alias

  knn_kernel<<<NQ, 64, 0, stream>>>(coords, edges);
  dist_kernel<<<NQ, 256, 0, stream>>>(coords, edges, dist);
  for (int l = 0; l < NLAYER; ++l) {
    wconv_kernel<<<dim3(96, 32), 256, 0, stream>>>(Wqkv + (size_t)l * 1024 * 3072,
                                                   wqkvT + (size_t)l * 3072 * 1024, 1024, 3072);
    wconv_kernel<<<dim3(32, 32), 256, 0, stream>>>(Wo + (size_t)l * 1024 * 1024,
                                                   woT + (size_t)l * 1024 * 1024, 1024, 1024);
    wconv_kernel<<<dim3(256, 32), 256, 0, stream>>>(Wf1 + (size_t)l * 1024 * 8192,
                                                    wf1T + (size_t)l * 8192 * 1024, 1024, 8192);
    wconv_kernel<<<dim3(32, 128), 256, 0, stream>>>(Wf2 + (size_t)l * 4096 * 1024,
                                                    wf2T + (size_t)l * 1024 * 4096, 4096, 1024);
  }
  wconv_kernel<<<dim3(32, 32), 256, 0, stream>>>(We1, we1T, 1024, 1024);
  wconv_kernel<<<dim3(4, 16), 256, 0, stream>>>(We2, we2T, 512, 128);

  // layer-0 ln1+qkv collapse to the 65 distinct embedding rows (padded to 128;
  // rows 65..127 read stale ws, influence only unread output rows).
  ln_kernel<<<65, 256, 0, stream>>>(emb, DIM, ln1_g, ln1_b, h65);
  gemmT128_kernel<0><<<24, 256, 0, stream>>>(
      (const ushort_t*)h65, (const ushort_t*)wqkvT, bqkv, qkv65, 1024, 1, 3072, 24, 8);

  int NCH = NQ / CQ;
  int MT128 = (int)(CT / 128);
  for (int c = 0; c < NCH; ++c) {
    zinit_kernel<<<(int)CT, 256, 0, stream>>>(edges, emb, zbuf, (int)(c * CT));
    // ---- layer 0: attn directly from qkv65 (gathered), then wo/ln2/ff ----
    attn_g_kernel<<<CQ * HSPLIT, 256, 0, stream>>>(qkv65, edges + (size_t)c * CQ * 16,
                                                   dist + (size_t)c * CQ * 256,
                                                   dist_scale, hbuf);
    gemmT128_kernel<1><<<MT128 * 8, 256, 0, stream>>>(
        (const ushort_t*)hbuf, (const ushort_t*)woT, bo, zbuf, 1024, MT128, 1024, 8, 2);
    ln_kernel<<<(int)CT, 256, 0, stream>>>(zbuf, DIM, ln2_g, ln2_b, hbuf);
    gemmGW_kernel<<<MT128 * 32, 256, 0, stream>>>(
        (const ushort_t*)hbuf, (const ushort_t*)wf1T, bf1, sh8, 1024, MT128, 4096, 4096, 32, 4);
    gemmT128_kernel<1><<<MT128 * 8, 256, 0, stream>>>(
        (const ushort_t*)sh8, (const ushort_t*)wf2T, bf2, zbuf, 4096, MT128, 1024, 8, 2);
    // ---- layer 1 front: full ln1+qkv (K/V need all tokens); token-0 attn ----
    ln_kernel<<<(int)CT, 256, 0, stream>>>(zbuf, DIM, ln1_g + DIM, ln1_b + DIM, hbuf);
    gemmT128_kernel<0><<<MT128 * 24, 256, 0, stream>>>(
        (const ushort_t*)hbuf, (const ushort_t*)(wqkvT + 3072ull * 1024),
        bqkv + 3072, sh8, 1024, MT128, 3072, 24, 4);
    attn2_kernel<<<CQ, 256, 0, stream>>>(sh8, dist + (size_t)c * CQ * 256,
                                         dist_scale + NHEAD, o_all + (size_t)c * CQ * 1024);
    z0copy_kernel<<<CQ, 256, 0, stream>>>(zbuf, z0_all + (size_t)c * CQ * 1024);
  }

  // ---- layer 1 tail on compact token-0 rows: M = NQ = 4096 ----
  int MTQ = NQ / 128;  // 32
  gemmT128_kernel<1><<<MTQ * 8, 256, 0, stream>>>(
      (const ushort_t*)o_all, (const ushort_t*)(woT + 1024ull * 1024),
      bo + DIM, z0_all, 1024, MTQ, 1024, 8, 2);
  ln_kernel<<<NQ, 256, 0, stream>>>(z0_all, DIM, ln2_g + DIM, ln2_b + DIM, h2);
  gemmGW_kernel<<<MTQ * 32, 256, 0, stream>>>(
      (const ushort_t*)h2, (const ushort_t*)(wf1T + 8192ull * 1024),
      bf1 + 2 * DFFN, gated_all, 1024, MTQ, 4096, 4096, 32, 4);
  gemmT128_kernel<1><<<MTQ * 8, 256, 0, stream>>>(
      (const ushort_t*)gated_all, (const ushort_t*)(wf2T + 1024ull * 4096),
      bf2 + DIM, z0_all, 4096, MTQ, 1024, 8, 2);
  ln_kernel<<<NQ, 256, 0, stream>>>(z0_all, DIM, lnf_g, lnf_b, hfinal);

  mgemm_kernel<2><<<dim3(4, 32), 256, 0, stream>>>(hfinal, we1T, be1, gated, 1024, 512, 512);
  mgemm_kernel<3><<<dim3(1, 32), 256, 0, stream>>>(gated, we2T, be2, tmp, 512, 0, 128);
  final_kernel<<<NQ, 64, 0, stream>>>(tmp, eps, (float*)d_out);
}

// Round 15
// 3403.688 us; speedup vs baseline: 1.9175x; 1.0390x over previous
//
#include <hip/hip_runtime.h>
#include <hip/hip_bf16.h>
#include <math.h>

#define LLEN 512
#define KNNK 16
#define DIM 1024
#define NHEAD 16
#define NLAYER 2
#define DFFN 4096
#define POSCLIP 32
#define NQ 4096
#define NTOK 65536
#define HSPLIT 4

typedef __attribute__((ext_vector_type(8))) short short8v;
typedef __attribute__((ext_vector_type(4))) float f32x4;
typedef unsigned short ushort_t;

__device__ __forceinline__ float b2f(ushort_t u) {
  union { unsigned u; float f; } x; x.u = ((unsigned)u) << 16; return x.f;
}

// 2D XCD-blocked tile mapping: B-slice L2-resident, A fetched ~once/XCD.
__device__ __forceinline__ void xcd_map(int bid, int Mtiles, int Ntiles, int XN,
                                        int& mt, int& nt) {
  int nt_per = Ntiles / XN;
  int mt_per = (Mtiles * XN) >> 3;
  int xcd = bid & 7, i = bid >> 3;
  int xn = xcd % XN, xm = xcd / XN;
  int ntl = i % nt_per, mtl = i / nt_per;
  mt = xm * mt_per + mtl;
  nt = xn * nt_per + ntl;
}

#define GLD16(gp, lp)                                                          \
  __builtin_amdgcn_global_load_lds(                                            \
      (const __attribute__((address_space(1))) void*)(gp),                     \
      (__attribute__((address_space(3))) void*)(lp), 16, 0, 0)

// ---------------- KNN: one wave per query ----------------
__global__ __launch_bounds__(64) void knn_kernel(const float* __restrict__ coords,
                                                 int* __restrict__ edges) {
  int n = blockIdx.x;
  int b = n / LLEN, i = n % LLEN;
  int lane = threadIdx.x;
  const float* cb = coords + (size_t)b * LLEN * 9;
  float xi = cb[i * 9 + 3], yi = cb[i * 9 + 4], zi = cb[i * 9 + 5];
  float d[8];
#pragma unroll
  for (int r = 0; r < 8; ++r) {
    int j = r * 64 + lane;
    float dx = xi - cb[j * 9 + 3];
    float dy = yi - cb[j * 9 + 4];
    float dz = zi - cb[j * 9 + 5];
    d[r] = dx * dx + dy * dy + dz * dz;
  }
  for (int s = 0; s < KNNK; ++s) {
    float bv = INFINITY; int bi = 1 << 30;
#pragma unroll
    for (int r = 0; r < 8; ++r) {
      int j = r * 64 + lane;
      if (d[r] < bv || (d[r] == bv && j < bi)) { bv = d[r]; bi = j; }
    }
#pragma unroll
    for (int off = 32; off > 0; off >>= 1) {
      float ov = __shfl_xor(bv, off);
      int   oi = __shfl_xor(bi, off);
      if (ov < bv || (ov == bv && oi < bi)) { bv = ov; bi = oi; }
    }
    if (lane == 0) edges[n * KNNK + s] = bi;
    if ((bi & 63) == lane) d[bi >> 6] = INFINITY;
  }
}

// ---------------- dist: 16x16 per query ----------------
__global__ __launch_bounds__(256) void dist_kernel(const float* __restrict__ coords,
                                                   const int* __restrict__ edges,
                                                   float* __restrict__ dist) {
  int n = blockIdx.x; int b = n / LLEN;
  __shared__ float tx[16], ty[16], tz[16];
  int t = threadIdx.x;
  const float* cb = coords + (size_t)b * LLEN * 9;
  if (t < 16) {
    int j = edges[n * KNNK + t];
    tx[t] = cb[j * 9 + 3]; ty[t] = cb[j * 9 + 4]; tz[t] = cb[j * 9 + 5];
  }
  __syncthreads();
  int e = t >> 4, f = t & 15;
  float dx = tx[e] - tx[f], dy = ty[e] - ty[f], dz = tz[e] - tz[f];
  dist[(size_t)n * 256 + t] = sqrtf(dx * dx + dy * dy + dz * dz + 1e-8f);
}

// ---------------- LayerNorm fp32 in -> bf16 out ----------------
__global__ __launch_bounds__(256) void ln_kernel(const float* __restrict__ X, int stride,
                                                 const float* __restrict__ g,
                                                 const float* __restrict__ bta,
                                                 __hip_bfloat16* __restrict__ Y) {
  int row = blockIdx.x; int t = threadIdx.x;
  const float4* xr = (const float4*)(X + (size_t)row * stride);
  float4 v = xr[t];
  float s = v.x + v.y + v.z + v.w;
  __shared__ float red[8];
  for (int off = 32; off; off >>= 1) s += __shfl_down(s, off);
  int wid = t >> 6;
  if ((t & 63) == 0) red[wid] = s;
  __syncthreads();
  if (t == 0) red[4] = (red[0] + red[1] + red[2] + red[3]) * (1.0f / DIM);
  __syncthreads();
  float mean = red[4];
  float d0 = v.x - mean, d1 = v.y - mean, d2 = v.z - mean, d3 = v.w - mean;
  float s2 = d0 * d0 + d1 * d1 + d2 * d2 + d3 * d3;
  for (int off = 32; off; off >>= 1) s2 += __shfl_down(s2, off);
  if ((t & 63) == 0) red[wid] = s2;
  __syncthreads();
  if (t == 0) red[5] = rsqrtf((red[0] + red[1] + red[2] + red[3]) * (1.0f / DIM) + 1e-5f);
  __syncthreads();
  float rstd = red[5];
  float4 gv = ((const float4*)g)[t], bv = ((const float4*)bta)[t];
  size_t o = (size_t)row * DIM + t * 4;
  Y[o + 0] = __float2bfloat16(d0 * rstd * gv.x + bv.x);
  Y[o + 1] = __float2bfloat16(d1 * rstd * gv.y + bv.y);
  Y[o + 2] = __float2bfloat16(d2 * rstd * gv.z + bv.z);
  Y[o + 3] = __float2bfloat16(d3 * rstd * gv.w + bv.w);
}

// ---------------- weight fp32 K x N -> bf16 N x K ----------------
__global__ __launch_bounds__(256) void wconv_kernel(const float* __restrict__ W,
                                                    __hip_bfloat16* __restrict__ Wt,
                                                    int K, int N) {
  __shared__ float tile[32][33];
  int n0 = blockIdx.x * 32, k0 = blockIdx.y * 32;
  int c = threadIdx.x & 31, r = threadIdx.x >> 5;
#pragma unroll
  for (int i = 0; i < 4; ++i)
    tile[r + i * 8][c] = W[(size_t)(k0 + r + i * 8) * N + n0 + c];
  __syncthreads();
#pragma unroll
  for (int i = 0; i < 4; ++i)
    Wt[(size_t)(n0 + r + i * 8) * K + k0 + c] = __float2bfloat16(tile[c][r + i * 8]);
}

// BK=32 swizzle: LDS chunk c holds global k-chunk c ^ ((row>>1)&3);
// reads use kg ^ ((fr>>1)&3). <=2-way (free).

// ============ gemmT128: BM=128, BN=128, BK=32, 256 thr (4 waves 2x2),
// 3-slot ring (48KB LDS). MODE 0: bf16 C = x   MODE 1: fp32 C += x
// MODE 4: fp32 C = emb[gather(edges)] + x   (fused z-init + residual)
template <int MODE>
__global__ __launch_bounds__(256, 3) void gemmT128_kernel(
    const ushort_t* __restrict__ A,
    const ushort_t* __restrict__ Wt,
    const float* __restrict__ bias,
    void* __restrict__ Cout,
    int K, int Mtiles, int Cstride, int Ntiles, int XN,
    const int* __restrict__ eg, const float* __restrict__ embg, int tok0) {
  __shared__ ushort_t Alds[3][4096];
  __shared__ ushort_t Blds[3][4096];
  int t = threadIdx.x;
  int w = t >> 6, lane = t & 63;
  int wr = w >> 1, wc = w & 1;
  int fr = lane & 15, kg = lane >> 4;

  int mt, nt;
  xcd_map(blockIdx.x, Mtiles, Ntiles, XN, mt, nt);
  size_t m0 = (size_t)mt * 128, n0 = (size_t)nt * 128;

  int stg_r = w * 16 + (lane >> 2);
  int stg_c = (((lane & 3) ^ ((lane >> 3) & 3)) << 3);
  const ushort_t* gAl = A + (m0 + stg_r) * (size_t)K + stg_c;
  const ushort_t* gBl = Wt + (n0 + stg_r) * (size_t)K + stg_c;
  int lds_w = w * 512;

#define SAt(slot, kcol, j) GLD16(gAl + (size_t)(j) * 64 * K + (kcol), Alds[slot] + (j) * 2048 + lds_w)
#define SBt(slot, kcol, j) GLD16(gBl + (size_t)(j) * 64 * K + (kcol), Blds[slot] + (j) * 2048 + lds_w)

  f32x4 acc[4][4];
#pragma unroll
  for (int i = 0; i < 4; ++i)
#pragma unroll
    for (int j = 0; j < 4; ++j) acc[i][j] = (f32x4){0.f, 0.f, 0.f, 0.f};

  int usw = ((kg ^ ((fr >> 1) & 3)) << 3);

  SAt(0, 0, 0); SAt(0, 0, 1); SBt(0, 0, 0); SBt(0, 0, 1);
  SAt(1, 32, 0); SAt(1, 32, 1); SBt(1, 32, 0); SBt(1, 32, 1);
  asm volatile("s_waitcnt vmcnt(4)" ::: "memory");
  __builtin_amdgcn_s_barrier();

  short8v af[4], bf[4];
  int NT = K >> 5;
  int sl = 0, st = 2;
  for (int ti = 0; ti < NT; ++ti) {
    int kS = (ti + 2) << 5;
    int stg = (ti + 2) < NT;
    const ushort_t* sA = Alds[sl];
    const ushort_t* sB = Blds[sl];
#pragma unroll
    for (int mi = 0; mi < 4; ++mi)
      af[mi] = *(const short8v*)(sA + (wr * 64 + mi * 16 + fr) * 32 + usw);
#pragma unroll
    for (int ni = 0; ni < 4; ++ni)
      bf[ni] = *(const short8v*)(sB + (wc * 64 + ni * 16 + fr) * 32 + usw);
    if (stg) { SAt(st, kS, 0); SAt(st, kS, 1); SBt(st, kS, 0); SBt(st, kS, 1); }
    asm volatile("s_waitcnt lgkmcnt(0)" ::: "memory");
    __builtin_amdgcn_sched_barrier(0);
    __builtin_amdgcn_s_setprio(1);
#pragma unroll
    for (int mi = 0; mi < 4; ++mi)
#pragma unroll
      for (int ni = 0; ni < 4; ++ni)
        acc[mi][ni] = __builtin_amdgcn_mfma_f32_16x16x32_bf16(af[mi], bf[ni], acc[mi][ni], 0, 0, 0);
    __builtin_amdgcn_s_setprio(0);
    if (stg) { asm volatile("s_waitcnt vmcnt(4)" ::: "memory"); }
    else if (ti + 1 < NT) { asm volatile("s_waitcnt vmcnt(0)" ::: "memory"); }
    __builtin_amdgcn_s_barrier();
    sl = (sl == 2) ? 0 : sl + 1;
    st = (st == 2) ? 0 : st + 1;
  }
#undef SAt
#undef SBt

  int er = wr * 64 + (lane >> 4) * 4;
  int ec = wc * 64 + fr;
#pragma unroll
  for (int mi = 0; mi < 4; ++mi) {
#pragma unroll
    for (int ni = 0; ni < 4; ++ni) {
      int col = (int)n0 + ec + ni * 16;
      float bs = bias[col];
#pragma unroll
      for (int j = 0; j < 4; ++j) {
        size_t row = m0 + er + mi * 16 + j;
        size_t cidx = row * (size_t)Cstride + col;
        float x = acc[mi][ni][j] + bs;
        if constexpr (MODE == 0) {
          ((__hip_bfloat16*)Cout)[cidx] = __float2bfloat16(x);
        } else if constexpr (MODE == 1) {
          ((float*)Cout)[cidx] += x;
        } else {  // MODE 4: fused z-init
          int tok = tok0 + (int)row;
          int n = tok >> 4;
          int diff = eg[tok] - eg[n << 4];
          int idx = min(max(diff, -POSCLIP), POSCLIP) + POSCLIP;
          ((float*)Cout)[cidx] = embg[(size_t)idx * DIM + col] + x;
        }
      }
    }
  }
}

// ============ gemmGW: fused gated ff1, 4 waves (2Mx2N), per-wave 64x64 of
// BOTH gated outputs. BM=128, BN=128 dual, BK=32, 3-slot ring 72KB, 2 blk/CU.
__global__ __launch_bounds__(256, 2) void gemmGW_kernel(
    const ushort_t* __restrict__ A,
    const ushort_t* __restrict__ Wt,
    const float* __restrict__ bias,
    __hip_bfloat16* __restrict__ Cout,
    int K, int Mtiles, int Cstride, int NhRows, int Ntiles, int XN) {
  __shared__ ushort_t Alds[3][4096];
  __shared__ ushort_t B1lds[3][4096];
  __shared__ ushort_t B2lds[3][4096];
  int t = threadIdx.x;
  int w = t >> 6, lane = t & 63;
  int wr = w >> 1, wc = w & 1;
  int fr = lane & 15, kg = lane >> 4;

  int mt, nt;
  xcd_map(blockIdx.x, Mtiles, Ntiles, XN, mt, nt);
  size_t m0 = (size_t)mt * 128, n0 = (size_t)nt * 128;

  int stg_r = w * 16 + (lane >> 2);
  int stg_c = (((lane & 3) ^ ((lane >> 3) & 3)) << 3);
  const ushort_t* gAl = A + (m0 + stg_r) * (size_t)K + stg_c;
  const ushort_t* gB1 = Wt + (n0 + stg_r) * (size_t)K + stg_c;
  const ushort_t* gB2 = Wt + ((size_t)NhRows + n0 + stg_r) * (size_t)K + stg_c;
  int lds_w = w * 512;

#define SAg(slot, kcol, j) GLD16(gAl + (size_t)(j) * 64 * K + (kcol), Alds[slot] + (j) * 2048 + lds_w)
#define SB1g(slot, kcol, j) GLD16(gB1 + (size_t)(j) * 64 * K + (kcol), B1lds[slot] + (j) * 2048 + lds_w)
#define SB2g(slot, kcol, j) GLD16(gB2 + (size_t)(j) * 64 * K + (kcol), B2lds[slot] + (j) * 2048 + lds_w)

  f32x4 acc1[4][4], acc2[4][4];
#pragma unroll
  for (int i = 0; i < 4; ++i)
#pragma unroll
    for (int j = 0; j < 4; ++j) {
      acc1[i][j] = (f32x4){0.f, 0.f, 0.f, 0.f};
      acc2[i][j] = (f32x4){0.f, 0.f, 0.f, 0.f};
    }

  int usw = ((kg ^ ((fr >> 1) & 3)) << 3);

  SAg(0, 0, 0); SAg(0, 0, 1); SB1g(0, 0, 0); SB1g(0, 0, 1); SB2g(0, 0, 0); SB2g(0, 0, 1);
  SAg(1, 32, 0); SAg(1, 32, 1); SB1g(1, 32, 0); SB1g(1, 32, 1); SB2g(1, 32, 0); SB2g(1, 32, 1);
  asm volatile("s_waitcnt vmcnt(6)" ::: "memory");
  __builtin_amdgcn_s_barrier();

  short8v af[4], bf1[4], bf2[4];
  int NT = K >> 5;
  int sl = 0, st = 2;
  for (int ti = 0; ti < NT; ++ti) {
    int kS = (ti + 2) << 5;
    int stg = (ti + 2) < NT;
    const ushort_t* sA = Alds[sl];
    const ushort_t* sB1 = B1lds[sl];
    const ushort_t* sB2 = B2lds[sl];
#pragma unroll
    for (int mi = 0; mi < 4; ++mi)
      af[mi] = *(const short8v*)(sA + (wr * 64 + mi * 16 + fr) * 32 + usw);
#pragma unroll
    for (int ni = 0; ni < 4; ++ni) {
      bf1[ni] = *(const short8v*)(sB1 + (wc * 64 + ni * 16 + fr) * 32 + usw);
      bf2[ni] = *(const short8v*)(sB2 + (wc * 64 + ni * 16 + fr) * 32 + usw);
    }
    if (stg) {
      SAg(st, kS, 0); SAg(st, kS, 1);
      SB1g(st, kS, 0); SB1g(st, kS, 1);
      SB2g(st, kS, 0); SB2g(st, kS, 1);
    }
    asm volatile("s_waitcnt lgkmcnt(0)" ::: "memory");
    __builtin_amdgcn_sched_barrier(0);
    __builtin_amdgcn_s_setprio(1);
#pragma unroll
    for (int mi = 0; mi < 4; ++mi)
#pragma unroll
      for (int ni = 0; ni < 4; ++ni) {
        acc1[mi][ni] = __builtin_amdgcn_mfma_f32_16x16x32_bf16(af[mi], bf1[ni], acc1[mi][ni], 0, 0, 0);
        acc2[mi][ni] = __builtin_amdgcn_mfma_f32_16x16x32_bf16(af[mi], bf2[ni], acc2[mi][ni], 0, 0, 0);
      }
    __builtin_amdgcn_s_setprio(0);
    if (stg) { asm volatile("s_waitcnt vmcnt(6)" ::: "memory"); }
    else if (ti + 1 < NT) { asm volatile("s_waitcnt vmcnt(0)" ::: "memory"); }
    __builtin_amdgcn_s_barrier();
    sl = (sl == 2) ? 0 : sl + 1;
    st = (st == 2) ? 0 : st + 1;
  }
#undef SAg
#undef SB1g
#undef SB2g

  int er = wr * 64 + (lane >> 4) * 4;
  int ec = wc * 64 + fr;
#pragma unroll
  for (int mi = 0; mi < 4; ++mi) {
#pragma unroll
    for (int ni = 0; ni < 4; ++ni) {
      int col = (int)n0 + ec + ni * 16;
      float b1v = bias[col];
      float b2v = bias[NhRows + col];
#pragma unroll
      for (int j = 0; j < 4; ++j) {
        size_t row = m0 + er + mi * 16 + j;
        float x1 = acc1[mi][ni][j] + b1v;
        float x2 = acc2[mi][ni][j] + b2v;
        float sg = x1 / (1.f + expf(-x1));
        Cout[row * (size_t)Cstride + col] = __float2bfloat16(sg * x2);
      }
    }
  }
}

// ---------------- small 128x128 GEMM (final head only) ----------------
template <int MODE>
__global__ __launch_bounds__(256) void mgemm_kernel(
    const __hip_bfloat16* __restrict__ A,
    const __hip_bfloat16* __restrict__ Wt,
    const float* __restrict__ bias,
    void* __restrict__ Cout,
    int K, int Nh, int Cstride) {
  __shared__ ushort_t As[4 * 128 * 8];
  __shared__ ushort_t Bs[4 * 128 * 8];
  __shared__ ushort_t Bs2[(MODE == 2) ? 4 * 128 * 8 : 8];
  int t = threadIdx.x;
  int w = t >> 6, lane = t & 63;
  int wr = w >> 1, wc = w & 1;
  size_t m0 = (size_t)blockIdx.y * 128;
  size_t n0 = (size_t)blockIdx.x * 128;
  int cell0 = w * 64 + lane;
  int cell1 = 256 + w * 64 + lane;
  int kg0 = cell0 >> 7, rw0 = cell0 & 127;
  int kg1 = cell1 >> 7, rw1 = cell1 & 127;
  const ushort_t* gA = (const ushort_t*)A;
  const ushort_t* gB = (const ushort_t*)Wt;
  const ushort_t* gB2 = (const ushort_t*)(Wt + (size_t)Nh * K);
  size_t a0 = (m0 + rw0) * (size_t)K + kg0 * 8;
  size_t a1 = (m0 + rw1) * (size_t)K + kg1 * 8;
  size_t b0 = (n0 + rw0) * (size_t)K + kg0 * 8;
  size_t b1 = (n0 + rw1) * (size_t)K + kg1 * 8;
  int ldso0 = w * 1024;
  int ldso1 = 4096 + w * 1024;
  f32x4 acc[4][4];
  f32x4 acc2[4][4];
#pragma unroll
  for (int i = 0; i < 4; ++i)
#pragma unroll
    for (int j = 0; j < 4; ++j) {
      acc[i][j] = (f32x4){0.f, 0.f, 0.f, 0.f};
      acc2[i][j] = (f32x4){0.f, 0.f, 0.f, 0.f};
    }
  int fr = lane & 15, kg = lane >> 4;
  int abase = (kg * 128 + wr * 64 + fr) * 16;
  int bbase = (kg * 128 + wc * 64 + fr) * 16;
  for (int k0 = 0; k0 < K; k0 += 32) {
    __syncthreads();
    GLD16(gA + a0 + k0, (char*)As + ldso0);
    GLD16(gA + a1 + k0, (char*)As + ldso1);
    GLD16(gB + b0 + k0, (char*)Bs + ldso0);
    GLD16(gB + b1 + k0, (char*)Bs + ldso1);
    if constexpr (MODE == 2) {
      GLD16(gB2 + b0 + k0, (char*)Bs2 + ldso0);
      GLD16(gB2 + b1 + k0, (char*)Bs2 + ldso1);
    }
    __syncthreads();
    short8v a[4], b[4];
#pragma unroll
    for (int mi = 0; mi < 4; ++mi)
      a[mi] = *(const short8v*)((const char*)As + abase + mi * 256);
#pragma unroll
    for (int ni = 0; ni < 4; ++ni)
      b[ni] = *(const short8v*)((const char*)Bs + bbase + ni * 256);
#pragma unroll
    for (int mi = 0; mi < 4; ++mi)
#pragma unroll
      for (int ni = 0; ni < 4; ++ni)
        acc[mi][ni] = __builtin_amdgcn_mfma_f32_16x16x32_bf16(a[mi], b[ni], acc[mi][ni], 0, 0, 0);
    if constexpr (MODE == 2) {
#pragma unroll
      for (int ni = 0; ni < 4; ++ni)
        b[ni] = *(const short8v*)((const char*)Bs2 + bbase + ni * 256);
#pragma unroll
      for (int mi = 0; mi < 4; ++mi)
#pragma unroll
        for (int ni = 0; ni < 4; ++ni)
          acc2[mi][ni] = __builtin_amdgcn_mfma_f32_16x16x32_bf16(a[mi], b[ni], acc2[mi][ni], 0, 0, 0);
    }
  }
  int er = wr * 64 + (lane >> 4) * 4;
  int ec = wc * 64 + fr;
#pragma unroll
  for (int mi = 0; mi < 4; ++mi) {
#pragma unroll
    for (int ni = 0; ni < 4; ++ni) {
      int col = (int)n0 + ec + ni * 16;
      float bs1 = bias[col];
#pragma unroll
      for (int j = 0; j < 4; ++j) {
        size_t row = m0 + er + mi * 16 + j;
        size_t cidx = row * (size_t)Cstride + col;
        float x = acc[mi][ni][j] + bs1;
        if constexpr (MODE == 3) {
          ((float*)Cout)[cidx] = x;
        } else {
          float x2 = acc2[mi][ni][j] + bias[Nh + col];
          float sig = 1.f / (1.f + expf(-x));
          ((__hip_bfloat16*)Cout)[cidx] = __float2bfloat16(x * sig * x2);
        }
      }
    }
  }
}

// ---------------- attention layer-0: gather q/k/v from qkv65 via edges map ----
__global__ __launch_bounds__(256) void attn_g_kernel(const __hip_bfloat16* __restrict__ qkv65,
                                                     const int* __restrict__ edges,
                                                     const float* __restrict__ dist,
                                                     const float* __restrict__ ds_l,
                                                     __hip_bfloat16* __restrict__ o) {
  int nq = blockIdx.x >> 2;
  int h0 = (blockIdx.x & 3) * (NHEAD / HSPLIT);
  int t = threadIdx.x;
  __shared__ float qs[16][65], ks[16][65], vs[16][65];
  __shared__ float sc[16][17], dl[16][17];
  __shared__ float sps_s[NHEAD];
  __shared__ int map_s[16];
  dl[t >> 4][t & 15] = dist[(size_t)nq * 256 + t];
  if (t < NHEAD) sps_s[t] = log1pf(expf(ds_l[t]));
  if (t < 16) {
    int diff = edges[nq * 16 + t] - edges[nq * 16];
    map_s[t] = min(max(diff, -POSCLIP), POSCLIP) + POSCLIP;
  }
  __syncthreads();
  int e = t >> 4, c4 = (t & 15) * 4;
  const ushort_t* qp = (const ushort_t*)qkv65;
  size_t ebase = (size_t)map_s[e] * 3072;
  for (int h = h0; h < h0 + NHEAD / HSPLIT; ++h) {
    const ushort_t* p = qp + ebase + h * 64 + c4;
    ushort4 qv = *(const ushort4*)p;
    ushort4 kv = *(const ushort4*)(p + 1024);
    ushort4 vv = *(const ushort4*)(p + 2048);
    qs[e][c4] = b2f(qv.x); qs[e][c4 + 1] = b2f(qv.y); qs[e][c4 + 2] = b2f(qv.z); qs[e][c4 + 3] = b2f(qv.w);
    ks[e][c4] = b2f(kv.x); ks[e][c4 + 1] = b2f(kv.y); ks[e][c4 + 2] = b2f(kv.z); ks[e][c4 + 3] = b2f(kv.w);
    vs[e][c4] = b2f(vv.x); vs[e][c4 + 1] = b2f(vv.y); vs[e][c4 + 2] = b2f(vv.z); vs[e][c4 + 3] = b2f(vv.w);
    __syncthreads();
    int ee = t >> 4, ff = t & 15;
    float s = 0.f;
#pragma unroll
    for (int d = 0; d < 64; ++d) s = fmaf(qs[ee][d], ks[ff][d], s);
    sc[ee][ff] = s * 0.125f - sps_s[h] * dl[ee][ff];
    __syncthreads();
    if (t < 16) {
      float m = -1e30f;
      for (int f = 0; f < 16; ++f) m = fmaxf(m, sc[t][f]);
      float sum = 0.f;
      for (int f = 0; f < 16; ++f) { float pe = expf(sc[t][f] - m); sc[t][f] = pe; sum += pe; }
      float inv = 1.f / sum;
      for (int f = 0; f < 16; ++f) sc[t][f] *= inv;
    }
    __syncthreads();
#pragma unroll
    for (int r = 0; r < 4; ++r) {
      int idx = t + 256 * r;
      int oe = idx >> 6, od = idx & 63;
      float acc = 0.f;
#pragma unroll
      for (int f = 0; f < 16; ++f) acc = fmaf(sc[oe][f], vs[f][od], acc);
      o[(size_t)(nq * 16 + oe) * 1024 + h * 64 + od] = __float2bfloat16(acc);
    }
    __syncthreads();
  }
}

// ---------------- h0 gather: token-0 bf16 h rows -> compact ----------------
__global__ __launch_bounds__(256) void h0copy_kernel(const __hip_bfloat16* __restrict__ h,
                                                     __hip_bfloat16* __restrict__ hq) {
  ((ushort4*)((ushort_t*)hq + (size_t)blockIdx.x * 1024))[threadIdx.x] =
      ((const ushort4*)((const ushort_t*)h + (size_t)blockIdx.x * 16384))[threadIdx.x];
}

// ---------------- attention layer-2: token-0 output only (split q / kv) -----
__global__ __launch_bounds__(256) void attn2_kernel(const __hip_bfloat16* __restrict__ qbuf,
                                                    const __hip_bfloat16* __restrict__ kv,
                                                    const float* __restrict__ dist,
                                                    const float* __restrict__ ds_l,
                                                    __hip_bfloat16* __restrict__ o) {
  int nq = blockIdx.x;
  int t = threadIdx.x;
  __shared__ ushort_t ks[16 * 1032];
  __shared__ ushort_t vs[16 * 1032];
  __shared__ float qsf[1024];
  __shared__ float sc[16][17];
  __shared__ float pm[16], pi[16], sps_s[16], dl[16];
  const ushort_t* kvp = (const ushort_t*)kv;
  size_t kvb = (size_t)nq * 16 * 2048;
#pragma unroll
  for (int i = 0; i < 8; ++i) {
    int flat8 = (i * 256 + t) * 8;
    int e = flat8 >> 10, cc = flat8 & 1023;
    *(short8v*)(ks + e * 1032 + cc) = *(const short8v*)(kvp + kvb + (size_t)e * 2048 + cc);
    *(short8v*)(vs + e * 1032 + cc) = *(const short8v*)(kvp + kvb + (size_t)e * 2048 + 1024 + cc);
  }
  {
    ushort4 qv = *(const ushort4*)((const ushort_t*)qbuf + (size_t)nq * 1024 + t * 4);
    qsf[t * 4 + 0] = b2f(qv.x); qsf[t * 4 + 1] = b2f(qv.y);
    qsf[t * 4 + 2] = b2f(qv.z); qsf[t * 4 + 3] = b2f(qv.w);
  }
  if (t < 16) {
    sps_s[t] = log1pf(expf(ds_l[t]));
    dl[t] = dist[(size_t)nq * 256 + t];
  }
  __syncthreads();
  int h = t >> 4, f = t & 15;
  float s = 0.f;
#pragma unroll
  for (int dc = 0; dc < 8; ++dc) {
    short8v k8 = *(const short8v*)(ks + f * 1032 + h * 64 + dc * 8);
#pragma unroll
    for (int j = 0; j < 8; ++j)
      s = fmaf(qsf[h * 64 + dc * 8 + j], b2f((ushort_t)k8[j]), s);
  }
  sc[h][f] = s * 0.125f - sps_s[h] * dl[f];
  __syncthreads();
  if (t < 16) {
    float m = -1e30f;
    for (int ff = 0; ff < 16; ++ff) m = fmaxf(m, sc[t][ff]);
    float sum = 0.f;
    for (int ff = 0; ff < 16; ++ff) sum += expf(sc[t][ff] - m);
    pm[t] = m; pi[t] = 1.f / sum;
  }
  __syncthreads();
  float p = expf(sc[h][f] - pm[h]) * pi[h];
  __syncthreads();
  sc[h][f] = p;
  __syncthreads();
#pragma unroll
  for (int r = 0; r < 4; ++r) {
    int idx = t + 256 * r;
    int oh = idx >> 6, od = idx & 63;
    float acc = 0.f;
#pragma unroll
    for (int f2 = 0; f2 < 16; ++f2)
      acc = fmaf(sc[oh][f2], b2f(vs[f2 * 1032 + oh * 64 + od]), acc);
    o[(size_t)nq * 1024 + idx] = __float2bfloat16(acc);
  }
}

// ---------------- z0 gather: token-0 rows -> compact fp32 ----------------
__global__ __launch_bounds__(256) void z0copy_kernel(const float* __restrict__ z,
                                                     float* __restrict__ z0) {
  ((float4*)(z0 + (size_t)blockIdx.x * 1024))[threadIdx.x] =
      ((const float4*)(z + (size_t)blockIdx.x * 16384))[threadIdx.x];
}

// ---------------- final VAE head elementwise ----------------
__global__ __launch_bounds__(64) void final_kernel(const float* __restrict__ tmp,
                                                   const float* __restrict__ eps,
                                                   float* __restrict__ out) {
  int r = blockIdx.x; int j = threadIdx.x;
  float mu = tmp[r * 128 + j];
  float lv = fminf(tmp[r * 128 + 64 + j], 5.0f);
  float zs = mu + eps[r * 64 + j] * expf(0.5f * lv);
  out[r * 64 + j] = zs;
  out[262144 + r * 64 + j] = mu;
  out[524288 + r * 64 + j] = lv;
}

extern "C" void kernel_launch(void* const* d_in, const int* in_sizes, int n_in,
                              void* d_out, int out_size, void* d_ws, size_t ws_size,
                              hipStream_t stream) {
  (void)in_sizes; (void)n_in; (void)out_size;
  const float* coords = (const float*)d_in[0];
  const float* eps    = (const float*)d_in[1];
  const float* emb    = (const float*)d_in[2];
  const float* ln1_g  = (const float*)d_in[3];
  const float* ln1_b  = (const float*)d_in[4];
  const float* Wqkv   = (const float*)d_in[5];
  const float* bqkv   = (const float*)d_in[6];
  const float* dist_scale = (const float*)d_in[7];
  const float* Wo     = (const float*)d_in[8];
  const float* bo     = (const float*)d_in[9];
  const float* ln2_g  = (const float*)d_in[10];
  const float* ln2_b  = (const float*)d_in[11];
  const float* Wf1    = (const float*)d_in[12];
  const float* bf1    = (const float*)d_in[13];
  const float* Wf2    = (const float*)d_in[14];
  const float* bf2    = (const float*)d_in[15];
  const float* lnf_g  = (const float*)d_in[16];
  const float* lnf_b  = (const float*)d_in[17];
  const float* We1    = (const float*)d_in[18];
  const float* be1    = (const float*)d_in[19];
  const float* We2    = (const float*)d_in[20];
  const float* be2    = (const float*)d_in[21];

  char* ws = (char*)d_ws;
  int*   edges = (int*)ws;                                        // 256 KB
  float* dist  = (float*)(ws + (4ull << 20));                     // 4 MB
  __hip_bfloat16* hfinal = (__hip_bfloat16*)(ws + (8ull << 20));  // 8 MB
  __hip_bfloat16* gated  = (__hip_bfloat16*)(ws + (16ull << 20)); // 4 MB
  float* tmp   = (float*)(ws + (20ull << 20));                    // 2 MB
  __hip_bfloat16* o_all  = (__hip_bfloat16*)(ws + (22ull << 20)); // 8 MB
  float* z0_all = (float*)(ws + (30ull << 20));                   // 16 MB
  __hip_bfloat16* wbase = (__hip_bfloat16*)(ws + (46ull << 20));  // ~70 MB
  size_t woff = 0;
  __hip_bfloat16* wqkvT = wbase + woff; woff += 2ull * 3072 * 1024;
  __hip_bfloat16* woT   = wbase + woff; woff += 2ull * 1024 * 1024;
  __hip_bfloat16* wf1T  = wbase + woff; woff += 2ull * 8192 * 1024;
  __hip_bfloat16* wf2T  = wbase + woff; woff += 2ull * 1024 * 4096;
  __hip_bfloat16* we1T  = wbase + woff; woff += 1024ull * 1024;
  __hip_bfloat16* we2T  = wbase + woff; woff += 128ull * 512;
  __hip_bfloat16* h65   = wbase + woff; woff += 128ull * 1024;   // padded to 128 rows
  __hip_bfloat16* qkv65 = wbase + woff; woff += 128ull * 3072;   // padded to 128 rows

  const size_t FIXED = 116ull << 20;
  int CQ = 4096;
  while (CQ > 256 && FIXED + (size_t)CQ * 16 * 14336ull > ws_size) CQ >>= 1;
  if (FIXED + (size_t)CQ * 16 * 14336ull > ws_size) return;  // ws too small: leave poison
  size_t CT = (size_t)CQ * KNNK;
  char* creg = ws + FIXED;
  float* zbuf = (float*)creg;                                    // CT x 1024 fp32
  __hip_bfloat16* hbuf = (__hip_bfloat16*)(creg + CT * 4096);    // CT x 1024 bf16
  __hip_bfloat16* sh8  = (__hip_bfloat16*)(creg + CT * 6144);    // CT x 4096 bf16
  __hip_bfloat16* hq   = sh8 + (size_t)CT * 2048;                // CQ x 1024 bf16 (upper half of sh8)
  __hip_bfloat16* qbuf = hq + (size_t)CQ * 1024;                 // CQ x 1024 bf16
  __hip_bfloat16* h2        = hbuf;   // post-loop alias
  __hip_bfloat16* gated_all = sh8;    // post-loop alias

  knn_kernel<<<NQ, 64, 0, stream>>>(coords, edges);
  dist_kernel<<<NQ, 256, 0, stream>>>(coords, edges, dist);
  for (int l = 0; l < NLAYER; ++l) {
    wconv_kernel<<<dim3(96, 32), 256, 0, stream>>>(Wqkv + (size_t)l * 1024 * 3072,
                                                   wqkvT + (size_t)l * 3072 * 1024, 1024, 3072);
    wconv_kernel<<<dim3(32, 32), 256, 0, stream>>>(Wo + (size_t)l * 1024 * 1024,
                                                   woT + (size_t)l * 1024 * 1024, 1024, 1024);
    wconv_kernel<<<dim3(256, 32), 256, 0, stream>>>(Wf1 + (size_t)l * 1024 * 8192,
                                                    wf1T + (size_t)l * 8192 * 1024, 1024, 8192);
    wconv_kernel<<<dim3(32, 128), 256, 0, stream>>>(Wf2 + (size_t)l * 4096 * 1024,
                                                    wf2T + (size_t)l * 1024 * 4096, 4096, 1024);
  }
  wconv_kernel<<<dim3(32, 32), 256, 0, stream>>>(We1, we1T, 1024, 1024);
  wconv_kernel<<<dim3(4, 16), 256, 0, stream>>>(We2, we2T, 512, 128);

  // layer-0 ln1+qkv collapse to the 65 distinct embedding rows (padded to 128)
  ln_kernel<<<65, 256, 0, stream>>>(emb, DIM, ln1_g, ln1_b, h65);
  gemmT128_kernel<0><<<24, 256, 0, stream>>>(
      (const ushort_t*)h65, (const ushort_t*)wqkvT, bqkv, qkv65, 1024, 1, 3072, 24, 8,
      nullptr, nullptr, 0);

  int NCH = NQ / CQ;
  int MT128 = (int)(CT / 128);
  int MTQc = CQ / 128;
  int XNq = (MTQc >= 8) ? 1 : (8 / MTQc);
  for (int c = 0; c < NCH; ++c) {
    // ---- layer 0: attn from qkv65 (gathered); wo fused with z-init ----
    attn_g_kernel<<<CQ * HSPLIT, 256, 0, stream>>>(qkv65, edges + (size_t)c * CQ * 16,
                                                   dist + (size_t)c * CQ * 256,
                                                   dist_scale, hbuf);
    gemmT128_kernel<4><<<MT128 * 8, 256, 0, stream>>>(
        (const ushort_t*)hbuf, (const ushort_t*)woT, bo, zbuf, 1024, MT128, 1024, 8, 2,
        edges, emb, (int)(c * CT));
    ln_kernel<<<(int)CT, 256, 0, stream>>>(zbuf, DIM, ln2_g, ln2_b, hbuf);
    gemmGW_kernel<<<MT128 * 32, 256, 0, stream>>>(
        (const ushort_t*)hbuf, (const ushort_t*)wf1T, bf1, sh8, 1024, MT128, 4096, 4096, 32, 4);
    gemmT128_kernel<1><<<MT128 * 8, 256, 0, stream>>>(
        (const ushort_t*)sh8, (const ushort_t*)wf2T, bf2, zbuf, 4096, MT128, 1024, 8, 2,
        nullptr, nullptr, 0);
    // ---- layer 1 front: ln1 full; KV for all tokens; Q only for token-0 ----
    ln_kernel<<<(int)CT, 256, 0, stream>>>(zbuf, DIM, ln1_g + DIM, ln1_b + DIM, hbuf);
    gemmT128_kernel<0><<<MT128 * 16, 256, 0, stream>>>(
        (const ushort_t*)hbuf, (const ushort_t*)(wqkvT + 3072ull * 1024 + 1024ull * 1024),
        bqkv + 3072 + 1024, sh8, 1024, MT128, 2048, 16, 4, nullptr, nullptr, 0);
    h0copy_kernel<<<CQ, 256, 0, stream>>>(hbuf, hq);
    gemmT128_kernel<0><<<MTQc * 8, 256, 0, stream>>>(
        (const ushort_t*)hq, (const ushort_t*)(wqkvT + 3072ull * 1024),
        bqkv + 3072, qbuf, 1024, MTQc, 1024, 8, XNq, nullptr, nullptr, 0);
    attn2_kernel<<<CQ, 256, 0, stream>>>(qbuf, sh8, dist + (size_t)c * CQ * 256,
                                         dist_scale + NHEAD, o_all + (size_t)c * CQ * 1024);
    z0copy_kernel<<<CQ, 256, 0, stream>>>(zbuf, z0_all + (size_t)c * CQ * 1024);
  }

  // ---- layer 1 tail on compact token-0 rows: M = NQ = 4096 ----
  int MTQ = NQ / 128;  // 32
  gemmT128_kernel<1><<<MTQ * 8, 256, 0, stream>>>(
      (const ushort_t*)o_all, (const ushort_t*)(woT + 1024ull * 1024),
      bo + DIM, z0_all, 1024, MTQ, 1024, 8, 2, nullptr, nullptr, 0);
  ln_kernel<<<NQ, 256, 0, stream>>>(z0_all, DIM, ln2_g + DIM, ln2_b + DIM, h2);
  gemmGW_kernel<<<MTQ * 32, 256, 0, stream>>>(
      (const ushort_t*)h2, (const ushort_t*)(wf1T + 8192ull * 1024),
      bf1 + 2 * DFFN, gated_all, 1024, MTQ, 4096, 4096, 32, 4);
  gemmT128_kernel<1><<<MTQ * 8, 256, 0, stream>>>(
      (const ushort_t*)gated_all, (const ushort_t*)(wf2T + 1024ull * 4096),
      bf2 + DIM, z0_all, 4096, MTQ, 1024, 8, 2, nullptr, nullptr, 0);
  ln_kernel<<<NQ, 256, 0, stream>>>(z0_all, DIM, lnf_g, lnf_b, hfinal);

  mgemm_kernel<2><<<dim3(4, 32), 256, 0, stream>>>(hfinal, we1T, be1, gated, 1024, 512, 512);
  mgemm_kernel<3><<<dim3(1, 32), 256, 0, stream>>>(gated, we2T, be2, tmp, 512, 0, 128);
  final_kernel<<<NQ, 64, 0, stream>>>(tmp, eps, (float*)d_out);
}